// Round 3
// baseline (467.112 us; speedup 1.0000x reference)
//
#include <hip/hip_runtime.h>
#include <hip/hip_bf16.h>
#include <math.h>

typedef __bf16 bf16x8 __attribute__((ext_vector_type(8)));
typedef float f32x4 __attribute__((ext_vector_type(4)));

#define MFMA16(a, b, c) __builtin_amdgcn_mfma_f32_16x16x32_bf16((a), (b), (c), 0, 0, 0)
#define KAP(r) ((((r) + ((r) >> 2))) & 3)

__device__ __forceinline__ void gload16(const void* g, void* l) {
  __builtin_amdgcn_global_load_lds((const __attribute__((address_space(1))) void*)g,
                                   (__attribute__((address_space(3))) void*)l, 16, 0, 0);
}

// ---------------------------------------------------------------------------
// Weight transpose + fp32 -> bf16:  in[K][N] -> out[N][K]
// ---------------------------------------------------------------------------
__global__ __launch_bounds__(256) void transpose_bf16(const float* __restrict__ in,
                                                      __bf16* __restrict__ out,
                                                      int K, int Nn) {
  __shared__ float tile[32][33];
  int n0 = blockIdx.x * 32, k0 = blockIdx.y * 32;
  int tx = threadIdx.x & 31, ty = threadIdx.x >> 5;
#pragma unroll
  for (int r = 0; r < 32; r += 8)
    tile[ty + r][tx] = in[(size_t)(k0 + ty + r) * Nn + n0 + tx];
  __syncthreads();
#pragma unroll
  for (int r = 0; r < 32; r += 8)
    out[(size_t)(n0 + ty + r) * K + k0 + tx] = (__bf16)tile[tx][ty + r];
}

// QKV transpose with output-column permutation: orig col n -> n' = which*1024 + h*64 + hd
__global__ __launch_bounds__(256) void transpose_qkv_perm(const float* __restrict__ in,
                                                          __bf16* __restrict__ out) {
  __shared__ float tile[32][33];
  int n0 = blockIdx.x * 32, k0 = blockIdx.y * 32;
  int tx = threadIdx.x & 31, ty = threadIdx.x >> 5;
#pragma unroll
  for (int r = 0; r < 32; r += 8)
    tile[ty + r][tx] = in[(size_t)(k0 + ty + r) * 3072 + n0 + tx];
  __syncthreads();
#pragma unroll
  for (int r = 0; r < 32; r += 8) {
    int n = n0 + ty + r;
    int h = n / 192, rem = n % 192, hd = rem / 3, which = rem % 3;
    int np = which * 1024 + h * 64 + hd;
    out[(size_t)np * 1024 + k0 + tx] = (__bf16)tile[tx][ty + r];
  }
}

__global__ __launch_bounds__(256) void bias_perm(const float* __restrict__ b,
                                                 float* __restrict__ bp) {
  int n = blockIdx.x * 256 + threadIdx.x;
  if (n < 3072) {
    int h = n / 192, rem = n % 192, hd = rem / 3, which = rem % 3;
    bp[which * 1024 + h * 64 + hd] = b[n];
  }
}

// plain fp32 -> bf16 convert (contiguous)
__global__ __launch_bounds__(256) void convert_plain(const float* __restrict__ in,
                                                     __bf16* __restrict__ out) {
  int id = blockIdx.x * 256 + threadIdx.x;
  const float* src = in + (size_t)id * 8;
  __bf16 tmp[8];
#pragma unroll
  for (int e = 0; e < 8; ++e) tmp[e] = (__bf16)src[e];
  *(uint4*)(out + (size_t)id * 8) = *(uint4*)tmp;
}

// x (fp32 [8192][1024]) -> left half of h_in (bf16 [8192][2048])
__global__ __launch_bounds__(256) void convert_x(const float* __restrict__ x,
                                                 __bf16* __restrict__ h) {
  int id = blockIdx.x * 256 + threadIdx.x;
  int row = id >> 7, cc = id & 127;
  const float* src = x + (size_t)row * 1024 + cc * 8;
  __bf16 tmp[8];
#pragma unroll
  for (int e = 0; e < 8; ++e) tmp[e] = (__bf16)src[e];
  *(uint4*)(h + (size_t)row * 2048 + cc * 8) = *(uint4*)tmp;
}

// copy W'T (2048x1024) into wT_ffn0 cols [1024:2048)
__global__ __launch_bounds__(256) void copy_cols(const __bf16* __restrict__ src,
                                                 __bf16* __restrict__ dst) {
  int id = blockIdx.x * 256 + threadIdx.x;  // 2048*128
  int row = id >> 7, c = id & 127;
  *(uint4*)(dst + (size_t)row * 2048 + 1024 + c * 8) =
      *(const uint4*)(src + (size_t)row * 1024 + c * 8);
}

// b'[n] = bffn0[n] + sum_e bout[e] * W0[1024+e][n]
__global__ __launch_bounds__(256) void fuse_bias(const float* __restrict__ bout,
                                                 const float* __restrict__ w0,
                                                 const float* __restrict__ b0,
                                                 float* __restrict__ bf) {
  int n = blockIdx.x * 256 + threadIdx.x;  // 2048
  float s = b0[n];
  for (int e = 0; e < 1024; ++e) s += bout[e] * w0[(size_t)(1024 + e) * 2048 + n];
  bf[n] = s;
}

// ---------------------------------------------------------------------------
// 128x128 GEMM (round-2 verified structure) for small-N GEMMs / precompute.
// ---------------------------------------------------------------------------
template <typename OutT, bool HAS_RES, bool HAS_BIAS>
__global__ __launch_bounds__(256) void gemm_kernel(
    const __bf16* __restrict__ A, int lda,
    const __bf16* __restrict__ Bt,            // N x K row-major
    const float* __restrict__ bias,
    OutT* __restrict__ C, int ldc,
    const float* __restrict__ res,
    int M, int Nn, int K) {
  __shared__ __attribute__((aligned(16))) __bf16 As[128 * 64];
  __shared__ __attribute__((aligned(16))) __bf16 Bs[128 * 64];

  const int t = threadIdx.x;
  const int row0A = blockIdx.x * 128;
  const int row0B = blockIdx.y * 128;
  const int wave = t >> 6, lane = t & 63;
  const int wm = wave >> 1, wn = wave & 1;
  const int g = lane >> 4, lr = lane & 15;

  f32x4 acc[4][4] = {};

  for (int k0 = 0; k0 < K; k0 += 64) {
#pragma unroll
    for (int p = 0; p < 4; ++p) {
      int cbase = (wave * 4 + p) * 64;
      int ci = cbase + lane;
      int r = ci >> 3, cp = ci & 7, cl = cp ^ (r & 7);
      gload16(A + (size_t)(row0A + r) * lda + k0 + cl * 8, &As[cbase * 8]);
      gload16(Bt + (size_t)(row0B + r) * K + k0 + cl * 8, &Bs[cbase * 8]);
    }
    __syncthreads();
#pragma unroll
    for (int kk = 0; kk < 2; ++kk) {
      bf16x8 af[4], bfr[4];
#pragma unroll
      for (int mt = 0; mt < 4; ++mt) {
        int r = wm * 64 + mt * 16 + lr, c = kk * 4 + g;
        af[mt] = *(const bf16x8*)((char*)As + r * 128 + ((c ^ (r & 7)) * 16));
      }
#pragma unroll
      for (int nt = 0; nt < 4; ++nt) {
        int r = wn * 64 + nt * 16 + lr, c = kk * 4 + g;
        bfr[nt] = *(const bf16x8*)((char*)Bs + r * 128 + ((c ^ (r & 7)) * 16));
      }
#pragma unroll
      for (int mt = 0; mt < 4; ++mt)
#pragma unroll
        for (int nt = 0; nt < 4; ++nt)
          acc[mt][nt] = MFMA16(af[mt], bfr[nt], acc[mt][nt]);
    }
    __syncthreads();
  }

  float bias_v[4];
#pragma unroll
  for (int nt = 0; nt < 4; ++nt)
    bias_v[nt] = HAS_BIAS ? bias[row0B + wn * 64 + nt * 16 + lr] : 0.f;
#pragma unroll
  for (int mt = 0; mt < 4; ++mt) {
    int grow_base = row0A + wm * 64 + mt * 16 + g * 4;
#pragma unroll
    for (int nt = 0; nt < 4; ++nt) {
      int gcol = row0B + wn * 64 + nt * 16 + lr;
#pragma unroll
      for (int j = 0; j < 4; ++j) {
        int grow = grow_base + j;
        float v = acc[mt][nt][j] + bias_v[nt];
        if (HAS_RES) v += res[(size_t)grow * ldc + gcol];
        C[(size_t)grow * ldc + gcol] = (OutT)v;
      }
    }
  }
}

// ---------------------------------------------------------------------------
// 256x256 8-phase GEMM (T2+T3+T4+T5). BK=32 slot ring of 4 (128 KiB LDS),
// stage-3-ahead global_load_lds(16B) w/ pre-swizzled source, counted vmcnt(8)
// at slot boundaries (never 0 in main loop), raw s_barrier pairs, setprio
// around 16-MFMA clusters. 8 waves (2m x 4n), per-wave 128x64 out.
// ---------------------------------------------------------------------------
template <typename OutT>
__global__ __launch_bounds__(512, 2) void gemm256(
    const __bf16* __restrict__ A, int lda,
    const __bf16* __restrict__ Bt, int ldb,
    const float* __restrict__ bias,
    OutT* __restrict__ C, int ldc, int K) {
  __shared__ __attribute__((aligned(16))) __bf16 lds[65536];  // 128 KiB
  __bf16* Asl = lds;            // 4 slots x [256][32]
  __bf16* Bsl = lds + 32768;    // 4 slots x [256][32]

  const int t = threadIdx.x;
  const int wave = t >> 6, lane = t & 63;
  const int wm = wave >> 2, wn = wave & 3;
  const int g = lane >> 4, lr = lane & 15;
  const int row0A = blockIdx.x * 256, row0B = blockIdx.y * 256;

  f32x4 acc[8][4] = {};
  const int L = K >> 5;

#define STAGE_A(s)                                                           \
  {                                                                          \
    int ssl = (s) & 3;                                                       \
    _Pragma("unroll") for (int l = 0; l < 2; ++l) {                          \
      int cbase = (wave * 2 + l) * 64;                                       \
      int ci = cbase + lane, r = ci >> 2, c = (ci & 3) ^ KAP(r);             \
      gload16(A + (size_t)(row0A + r) * lda + (s) * 32 + c * 8,              \
              (void*)(Asl + ssl * 8192 + cbase * 8));                        \
    }                                                                        \
  }
#define STAGE_B(s)                                                           \
  {                                                                          \
    int ssl = (s) & 3;                                                       \
    _Pragma("unroll") for (int l = 0; l < 2; ++l) {                          \
      int cbase = (wave * 2 + l) * 64;                                       \
      int ci = cbase + lane, r = ci >> 2, c = (ci & 3) ^ KAP(r);             \
      gload16(Bt + (size_t)(row0B + r) * ldb + (s) * 32 + c * 8,             \
              (void*)(Bsl + ssl * 8192 + cbase * 8));                        \
    }                                                                        \
  }

#define SLOT_BODY(s, DO_STAGE, VMSTR)                                        \
  {                                                                          \
    const __bf16* Ab = Asl + ((s) & 3) * 8192;                               \
    const __bf16* Bb = Bsl + ((s) & 3) * 8192;                               \
    bf16x8 bfrag[4], afrag[4];                                               \
    _Pragma("unroll") for (int ni = 0; ni < 4; ++ni) {                       \
      int rr = wn * 64 + ni * 16 + lr;                                       \
      bfrag[ni] = *(const bf16x8*)(Bb + rr * 32 + ((g ^ KAP(rr)) * 8));      \
    }                                                                        \
    _Pragma("unroll") for (int mi = 0; mi < 4; ++mi) {                       \
      int rr = wm * 128 + mi * 16 + lr;                                      \
      afrag[mi] = *(const bf16x8*)(Ab + rr * 32 + ((g ^ KAP(rr)) * 8));      \
    }                                                                        \
    if (DO_STAGE) STAGE_A((s) + 3);                                          \
    __builtin_amdgcn_s_barrier();                                            \
    __builtin_amdgcn_s_setprio(1);                                           \
    _Pragma("unroll") for (int mi = 0; mi < 4; ++mi)                         \
      _Pragma("unroll") for (int ni = 0; ni < 4; ++ni)                       \
        acc[mi][ni] = MFMA16(afrag[mi], bfrag[ni], acc[mi][ni]);             \
    __builtin_amdgcn_s_setprio(0);                                           \
    __builtin_amdgcn_s_barrier();                                            \
    _Pragma("unroll") for (int mi = 0; mi < 4; ++mi) {                       \
      int rr = wm * 128 + 64 + mi * 16 + lr;                                 \
      afrag[mi] = *(const bf16x8*)(Ab + rr * 32 + ((g ^ KAP(rr)) * 8));      \
    }                                                                        \
    if (DO_STAGE) STAGE_B((s) + 3);                                          \
    asm volatile("s_waitcnt " VMSTR ::: "memory");                           \
    __builtin_amdgcn_s_barrier();                                            \
    __builtin_amdgcn_s_setprio(1);                                           \
    _Pragma("unroll") for (int mi = 0; mi < 4; ++mi)                         \
      _Pragma("unroll") for (int ni = 0; ni < 4; ++ni)                       \
        acc[4 + mi][ni] = MFMA16(afrag[mi], bfrag[ni], acc[4 + mi][ni]);     \
    __builtin_amdgcn_s_setprio(0);                                           \
    __builtin_amdgcn_s_barrier();                                            \
  }

  // prologue: stage slots 0,1,2; drain slot 0 (12 outstanding -> 8)
#pragma unroll
  for (int ss = 0; ss < 3; ++ss) {
    STAGE_A(ss);
    STAGE_B(ss);
  }
  asm volatile("s_waitcnt vmcnt(8)" ::: "memory");
  __builtin_amdgcn_s_barrier();

  for (int s = 0; s + 3 < L; ++s) SLOT_BODY(s, true, "vmcnt(8)");
  SLOT_BODY(L - 3, false, "vmcnt(4)");
  SLOT_BODY(L - 2, false, "vmcnt(0)");
  SLOT_BODY(L - 1, false, "vmcnt(0)");

#undef SLOT_BODY
#undef STAGE_A
#undef STAGE_B

  // epilogue
  float bias_v[4];
#pragma unroll
  for (int ni = 0; ni < 4; ++ni) bias_v[ni] = bias[row0B + wn * 64 + ni * 16 + lr];
#pragma unroll
  for (int mi = 0; mi < 8; ++mi) {
    int grow_base = row0A + wm * 128 + mi * 16 + g * 4;
#pragma unroll
    for (int ni = 0; ni < 4; ++ni) {
      int gcol = row0B + wn * 64 + ni * 16 + lr;
#pragma unroll
      for (int j = 0; j < 4; ++j)
        C[(size_t)(grow_base + j) * ldc + gcol] = (OutT)(acc[mi][ni][j] + bias_v[ni]);
    }
  }
}

// ---------------------------------------------------------------------------
// RoPE + scatter (qkv column-permuted: [Q|K|V] each (token, h*64+hd)).
// q pre-scaled 1/8; v packed to (bh, hd, n) with kv-permutation for PV frags.
// ---------------------------------------------------------------------------
__global__ __launch_bounds__(256) void rope_scatter(
    const __bf16* __restrict__ qkv, const float* __restrict__ enc,
    __bf16* __restrict__ q, __bf16* __restrict__ kk, __bf16* __restrict__ vt) {
  int bh = blockIdx.y;
  int b = bh >> 4, h = bh & 15;
  int n0 = blockIdx.x * 64;
  int t = threadIdx.x;
#pragma unroll
  for (int i = 0; i < 2; ++i) {
    int id = t + i * 256;
    int nl = id >> 3, cc = id & 7;
    int n = n0 + nl;
    size_t row = (size_t)(b * 2048 + n) * 3072;
    bf16x8 qv = *(const bf16x8*)(qkv + row + h * 64 + cc * 8);
    bf16x8 kv = *(const bf16x8*)(qkv + row + 1024 + h * 64 + cc * 8);
    const float* e0 = enc + (size_t)n * 64 + cc * 8;
    const float* e1 = e0 + 131072;
    __bf16 qo[8], ko[8];
#pragma unroll
    for (int e = 0; e < 8; e += 2) {
      float q0 = (float)qv[e], q1 = (float)qv[e + 1];
      float k0 = (float)kv[e], k1 = (float)kv[e + 1];
      float f00 = e0[e], f01 = e0[e + 1], f10 = e1[e], f11 = e1[e + 1];
      qo[e] = (__bf16)((q0 * f00 - q1 * f10) * 0.125f);
      qo[e + 1] = (__bf16)((q1 * f01 + q0 * f11) * 0.125f);
      ko[e] = (__bf16)(k0 * f00 - k1 * f10);
      ko[e + 1] = (__bf16)(k1 * f01 + k0 * f11);
    }
    size_t qb = ((size_t)bh * 2048 + n) * 64 + cc * 8;
    *(uint4*)(q + qb) = *(uint4*)qo;
    *(uint4*)(kk + qb) = *(uint4*)ko;
  }
#pragma unroll
  for (int i = 0; i < 2; ++i) {
    int id = t + i * 256;
    int hd = id >> 3, c = id & 7;
    __bf16 tmp[8];
#pragma unroll
    for (int e = 0; e < 8; ++e) {
      int kv = (c >> 2) * 32 + (e >> 2) * 16 + (c & 3) * 4 + (e & 3);
      int n = n0 + kv;
      tmp[e] = qkv[(size_t)(b * 2048 + n) * 3072 + 2048 + h * 64 + hd];
    }
    *(uint4*)(vt + ((size_t)bh * 64 + hd) * 2048 + n0 + c * 8) = *(uint4*)tmp;
  }
}

// ---------------------------------------------------------------------------
// Flash attention (swapped QK^T, lane-local softmax, no max-tracking, P from
// registers, dbuf gload_lds staging, setprio around MFMA clusters).
// ctx written into h_in right half (ld 2048).
// ---------------------------------------------------------------------------
__global__ __launch_bounds__(256) void attn_kernel(
    const __bf16* __restrict__ q, const __bf16* __restrict__ k,
    const __bf16* __restrict__ vt, __bf16* __restrict__ ctx) {
  __shared__ __attribute__((aligned(16))) __bf16 Ks[2][64 * 64];
  __shared__ __attribute__((aligned(16))) __bf16 Vs[2][64 * 64];

  const int bh = blockIdx.y, b = bh >> 4, h = bh & 15;
  const int q0 = blockIdx.x * 64;
  const int t = threadIdx.x, wave = t >> 6, lane = t & 63;
  const int g = lane >> 4, lr = lane & 15;
  const int qrow = q0 + wave * 16;

  const __bf16* kbase = k + (size_t)bh * 2048 * 64;
  const __bf16* vbase = vt + (size_t)bh * 64 * 2048;

  bf16x8 qf[2];
#pragma unroll
  for (int kc = 0; kc < 2; ++kc)
    qf[kc] = *(const bf16x8*)(q + ((size_t)bh * 2048 + qrow + lr) * 64 + kc * 32 + g * 8);

  f32x4 o[4] = {};
  float lsum = 0.f;

#define STAGE_ATTN(buf, kv0)                                                    \
  {                                                                             \
    _Pragma("unroll") for (int p = 0; p < 2; ++p) {                             \
      int cbase = wave * 128 + p * 64;                                          \
      int ci = cbase + lane;                                                    \
      int r = ci >> 3, cp = ci & 7, cl = cp ^ (r & 7);                          \
      gload16(kbase + (size_t)((kv0) + r) * 64 + cl * 8, &Ks[buf][cbase * 8]);  \
      gload16(vbase + (size_t)r * 2048 + (kv0) + cl * 8, &Vs[buf][cbase * 8]);  \
    }                                                                           \
  }

  STAGE_ATTN(0, 0);
  __syncthreads();
  int buf = 0;

  for (int kv0 = 0; kv0 < 2048; kv0 += 64) {
    if (kv0 + 64 < 2048) STAGE_ATTN(buf ^ 1, kv0 + 64);

    f32x4 s[4];
    __builtin_amdgcn_s_setprio(1);
#pragma unroll
    for (int nt = 0; nt < 4; ++nt) {
      int r = nt * 16 + lr;
      bf16x8 kf0 = *(const bf16x8*)((char*)Ks[buf] + r * 128 + ((g ^ (r & 7)) * 16));
      bf16x8 kf1 = *(const bf16x8*)((char*)Ks[buf] + r * 128 + (((4 + g) ^ (r & 7)) * 16));
      f32x4 a = {};
      a = MFMA16(kf0, qf[0], a);
      a = MFMA16(kf1, qf[1], a);
      s[nt] = a;
    }
    __builtin_amdgcn_s_setprio(0);

    float pvv[4][4];
#pragma unroll
    for (int nt = 0; nt < 4; ++nt)
#pragma unroll
      for (int j = 0; j < 4; ++j) {
        float e = __expf(s[nt][j]);
        pvv[nt][j] = e;
        lsum += e;
      }

    __builtin_amdgcn_s_setprio(1);
#pragma unroll
    for (int t2 = 0; t2 < 2; ++t2) {
      bf16x8 pf;
#pragma unroll
      for (int e = 0; e < 8; ++e) pf[e] = (__bf16)pvv[2 * t2 + (e >> 2)][e & 3];
#pragma unroll
      for (int nt = 0; nt < 4; ++nt) {
        int r = nt * 16 + lr;
        bf16x8 vf = *(const bf16x8*)((char*)Vs[buf] + r * 128 + (((t2 * 4 + g) ^ (r & 7)) * 16));
        o[nt] = MFMA16(vf, pf, o[nt]);
      }
    }
    __builtin_amdgcn_s_setprio(0);
    __syncthreads();
    buf ^= 1;
  }

  lsum += __shfl_xor(lsum, 16, 64);
  lsum += __shfl_xor(lsum, 32, 64);
  float inv = 1.f / lsum;

  size_t obase = ((size_t)(b * 2048 + qrow + lr)) * 2048 + 1024 + h * 64;
#pragma unroll
  for (int nt = 0; nt < 4; ++nt) {
    __bf16 w4[4];
#pragma unroll
    for (int j = 0; j < 4; ++j) w4[j] = (__bf16)(o[nt][j] * inv);
    *(uint2*)(ctx + obase + nt * 16 + g * 4) = *(uint2*)w4;
  }
#undef STAGE_ATTN
}

// ---------------------------------------------------------------------------
// LayerNorm + exact GELU over rows of 2048
// ---------------------------------------------------------------------------
__global__ __launch_bounds__(256) void ln_gelu(const __bf16* __restrict__ hin,
                                               const float* __restrict__ lns,
                                               const float* __restrict__ lnb,
                                               __bf16* __restrict__ hout) {
  int row = blockIdx.x;
  const __bf16* rp = hin + (size_t)row * 2048;
  int t = threadIdx.x;
  __bf16 tmp[8];
  *(uint4*)tmp = *(const uint4*)(rp + t * 8);
  float vals[8], s = 0.f, s2 = 0.f;
#pragma unroll
  for (int e = 0; e < 8; ++e) {
    float x = (float)tmp[e];
    vals[e] = x;
    s += x;
    s2 += x * x;
  }
#pragma unroll
  for (int m = 1; m < 64; m <<= 1) {
    s += __shfl_xor(s, m, 64);
    s2 += __shfl_xor(s2, m, 64);
  }
  __shared__ float red[8];
  int wave = t >> 6, lane = t & 63;
  if (lane == 0) { red[wave] = s; red[4 + wave] = s2; }
  __syncthreads();
  s = red[0] + red[1] + red[2] + red[3];
  s2 = red[4] + red[5] + red[6] + red[7];
  float mu = s * (1.f / 2048.f);
  float var = s2 * (1.f / 2048.f) - mu * mu;
  float rstd = rsqrtf(var + 1e-5f);
  __bf16 outv[8];
#pragma unroll
  for (int e = 0; e < 8; ++e) {
    int c = t * 8 + e;
    float xh = (vals[e] - mu) * rstd * lns[c] + lnb[c];
    float gg = 0.5f * xh * (1.f + erff(xh * 0.70710678118f));
    outv[e] = (__bf16)gg;
  }
  *(uint4*)(hout + (size_t)row * 2048 + t * 8) = *(uint4*)outv;
}

// ---------------------------------------------------------------------------
// Launch
// ---------------------------------------------------------------------------
extern "C" void kernel_launch(void* const* d_in, const int* in_sizes, int n_in,
                              void* d_out, int out_size, void* d_ws, size_t ws_size,
                              hipStream_t stream) {
  const float* x = (const float*)d_in[0];
  const float* enc = (const float*)d_in[1];
  const float* wqkv = (const float*)d_in[2];
  const float* bqkv = (const float*)d_in[3];
  const float* wout = (const float*)d_in[4];
  const float* bout = (const float*)d_in[5];
  const float* wffn0 = (const float*)d_in[6];
  const float* bffn0 = (const float*)d_in[7];
  const float* lns = (const float*)d_in[8];
  const float* lnb = (const float*)d_in[9];
  const float* wffn3 = (const float*)d_in[10];
  const float* bffn3 = (const float*)d_in[11];
  float* out = (float*)d_out;
  char* ws = (char*)d_ws;

  __bf16* wT_qkv = (__bf16*)(ws + 0);              //  6291456
  __bf16* wT_ffn0 = (__bf16*)(ws + 6291456);       //  8388608
  __bf16* wT_ffn3 = (__bf16*)(ws + 14680064);      //  4194304
  __bf16* wout_bf = (__bf16*)(ws + 18874368);      //  2097152
  __bf16* wpT_tmp = (__bf16*)(ws + 20971520);      //  4194304
  float* bqkv_p = (float*)(ws + 25165824);         //    12288
  float* bffn0_f = (float*)(ws + 25178112);        //     8192
  __bf16* h_in = (__bf16*)(ws + 25186304);         // 33554432  [x | ctx]
  __bf16* qkv = (__bf16*)(ws + 58740736);          // 50331648
  __bf16* ffn0o = qkv;                             // alias (qkv dead after rope)
  __bf16* qb = (__bf16*)(ws + 109072384);          // 16777216
  __bf16* h2 = qb;                                 // alias q,k (dead after attn)
  __bf16* kb = (__bf16*)(ws + 125849600);          // 16777216
  __bf16* vtb = (__bf16*)(ws + 142626816);         // 16777216

  dim3 blk(256);
  // weight prep
  transpose_qkv_perm<<<dim3(96, 32), blk, 0, stream>>>(wqkv, wT_qkv);
  bias_perm<<<12, blk, 0, stream>>>(bqkv, bqkv_p);
  transpose_bf16<<<dim3(64, 64), blk, 0, stream>>>(wffn0, wT_ffn0, 2048, 2048);
  transpose_bf16<<<dim3(32, 64), blk, 0, stream>>>(wffn3, wT_ffn3, 2048, 1024);
  convert_plain<<<512, blk, 0, stream>>>(wout, wout_bf);
  // W'T = W0b^T * Wout^T  (2048 x 1024), then splice into wT_ffn0 cols 1024:
  gemm_kernel<__bf16, false, false><<<dim3(16, 8), blk, 0, stream>>>(
      wT_ffn0 + 1024, 2048, wout_bf, nullptr, wpT_tmp, 1024, nullptr, 2048, 1024, 1024);
  copy_cols<<<1024, blk, 0, stream>>>(wpT_tmp, wT_ffn0);
  fuse_bias<<<8, blk, 0, stream>>>(bout, wffn0, bffn0, bffn0_f);
  convert_x<<<4096, blk, 0, stream>>>(x, h_in);

  // QKV projection (8-phase 256^2): [8192,1024] x [1024,3072]
  gemm256<__bf16><<<dim3(32, 12), dim3(512), 0, stream>>>(
      h_in, 2048, wT_qkv, 1024, bqkv_p, qkv, 3072, 1024);

  rope_scatter<<<dim3(32, 64), blk, 0, stream>>>(qkv, enc, qb, kb, vtb);
  attn_kernel<<<dim3(32, 64), blk, 0, stream>>>(qb, kb, vtb, h_in);

  // FFN0 (8-phase 256^2): [8192,2048] x [2048,2048] (with fused out-proj)
  gemm256<__bf16><<<dim3(32, 8), dim3(512), 0, stream>>>(
      h_in, 2048, wT_ffn0, 2048, bffn0_f, ffn0o, 2048, 2048);

  ln_gelu<<<8192, blk, 0, stream>>>(ffn0o, lns, lnb, h2);

  // FFN3 + bias + residual -> out (fp32)
  gemm_kernel<float, true, true><<<dim3(64, 8), blk, 0, stream>>>(
      h2, 2048, wT_ffn3, bffn3, out, 1024, x, 8192, 1024, 2048);
}

// Round 4
// 444.578 us; speedup vs baseline: 1.0507x; 1.0507x over previous
//
#include <hip/hip_runtime.h>
#include <hip/hip_bf16.h>
#include <math.h>

typedef __bf16 bf16x8 __attribute__((ext_vector_type(8)));
typedef float f32x4 __attribute__((ext_vector_type(4)));

#define MFMA16(a, b, c) __builtin_amdgcn_mfma_f32_16x16x32_bf16((a), (b), (c), 0, 0, 0)

__device__ __forceinline__ void gload16(const void* g, void* l) {
  __builtin_amdgcn_global_load_lds((const __attribute__((address_space(1))) void*)g,
                                   (__attribute__((address_space(3))) void*)l, 16, 0, 0);
}

// ---------------------------------------------------------------------------
// Weight transpose + fp32 -> bf16:  in[K][N] -> out[N][K]
// ---------------------------------------------------------------------------
__global__ __launch_bounds__(256) void transpose_bf16(const float* __restrict__ in,
                                                      __bf16* __restrict__ out,
                                                      int K, int Nn) {
  __shared__ float tile[32][33];
  int n0 = blockIdx.x * 32, k0 = blockIdx.y * 32;
  int tx = threadIdx.x & 31, ty = threadIdx.x >> 5;
#pragma unroll
  for (int r = 0; r < 32; r += 8)
    tile[ty + r][tx] = in[(size_t)(k0 + ty + r) * Nn + n0 + tx];
  __syncthreads();
#pragma unroll
  for (int r = 0; r < 32; r += 8)
    out[(size_t)(n0 + ty + r) * K + k0 + tx] = (__bf16)tile[tx][ty + r];
}

// QKV transpose with output-column permutation: orig col n -> n' = which*1024 + h*64 + hd
__global__ __launch_bounds__(256) void transpose_qkv_perm(const float* __restrict__ in,
                                                          __bf16* __restrict__ out) {
  __shared__ float tile[32][33];
  int n0 = blockIdx.x * 32, k0 = blockIdx.y * 32;
  int tx = threadIdx.x & 31, ty = threadIdx.x >> 5;
#pragma unroll
  for (int r = 0; r < 32; r += 8)
    tile[ty + r][tx] = in[(size_t)(k0 + ty + r) * 3072 + n0 + tx];
  __syncthreads();
#pragma unroll
  for (int r = 0; r < 32; r += 8) {
    int n = n0 + ty + r;
    int h = n / 192, rem = n % 192, hd = rem / 3, which = rem % 3;
    int np = which * 1024 + h * 64 + hd;
    out[(size_t)np * 1024 + k0 + tx] = (__bf16)tile[tx][ty + r];
  }
}

__global__ __launch_bounds__(256) void bias_perm(const float* __restrict__ b,
                                                 float* __restrict__ bp) {
  int n = blockIdx.x * 256 + threadIdx.x;
  if (n < 3072) {
    int h = n / 192, rem = n % 192, hd = rem / 3, which = rem % 3;
    bp[which * 1024 + h * 64 + hd] = b[n];
  }
}

// plain fp32 -> bf16 convert (contiguous)
__global__ __launch_bounds__(256) void convert_plain(const float* __restrict__ in,
                                                     __bf16* __restrict__ out) {
  int id = blockIdx.x * 256 + threadIdx.x;
  const float* src = in + (size_t)id * 8;
  __bf16 tmp[8];
#pragma unroll
  for (int e = 0; e < 8; ++e) tmp[e] = (__bf16)src[e];
  *(uint4*)(out + (size_t)id * 8) = *(uint4*)tmp;
}

// x (fp32 [8192][1024]) -> left half of h_in (bf16 [8192][2048])
__global__ __launch_bounds__(256) void convert_x(const float* __restrict__ x,
                                                 __bf16* __restrict__ h) {
  int id = blockIdx.x * 256 + threadIdx.x;
  int row = id >> 7, cc = id & 127;
  const float* src = x + (size_t)row * 1024 + cc * 8;
  __bf16 tmp[8];
#pragma unroll
  for (int e = 0; e < 8; ++e) tmp[e] = (__bf16)src[e];
  *(uint4*)(h + (size_t)row * 2048 + cc * 8) = *(uint4*)tmp;
}

// copy W'T (2048x1024) into wT_ffn0 cols [1024:2048)
__global__ __launch_bounds__(256) void copy_cols(const __bf16* __restrict__ src,
                                                 __bf16* __restrict__ dst) {
  int id = blockIdx.x * 256 + threadIdx.x;  // 2048*128
  int row = id >> 7, c = id & 127;
  *(uint4*)(dst + (size_t)row * 2048 + 1024 + c * 8) =
      *(const uint4*)(src + (size_t)row * 1024 + c * 8);
}

// b'[n] = bffn0[n] + sum_e bout[e] * W0[1024+e][n]  -- deterministic 2-stage
__global__ __launch_bounds__(256) void fuse_bias_part(const float* __restrict__ bout,
                                                      const float* __restrict__ w0,
                                                      float* __restrict__ part) {
  int n = blockIdx.x * 256 + threadIdx.x;  // grid (8,16)
  int e0 = blockIdx.y * 64;
  float s = 0.f;
#pragma unroll 4
  for (int e = 0; e < 64; ++e)
    s += bout[e0 + e] * w0[(size_t)(1024 + e0 + e) * 2048 + n];
  part[(size_t)blockIdx.y * 2048 + n] = s;
}

__global__ __launch_bounds__(256) void fuse_bias_red(const float* __restrict__ part,
                                                     const float* __restrict__ b0,
                                                     float* __restrict__ bf) {
  int n = blockIdx.x * 256 + threadIdx.x;  // grid 8
  float s = b0[n];
#pragma unroll
  for (int y = 0; y < 16; ++y) s += part[(size_t)y * 2048 + n];
  bf[n] = s;
}

// ---------------------------------------------------------------------------
// 128x128 GEMM (round-2 verified structure) + XCD-chunk swizzle (T1).
// global_load_lds(16B) staging, pre-swizzled source col, linear LDS dest,
// XOR-swizzled reads. 2 barriers per K-step.
// ---------------------------------------------------------------------------
template <typename OutT, bool HAS_RES, bool HAS_BIAS>
__global__ __launch_bounds__(256) void gemm_kernel(
    const __bf16* __restrict__ A, int lda,
    const __bf16* __restrict__ Bt,            // N x K row-major
    const float* __restrict__ bias,
    OutT* __restrict__ C, int ldc,
    const float* __restrict__ res,
    int M, int Nn, int K) {
  __shared__ __attribute__((aligned(16))) __bf16 As[128 * 64];
  __shared__ __attribute__((aligned(16))) __bf16 Bs[128 * 64];

  const int t = threadIdx.x;
  // XCD-chunk swizzle (bijective; all grids are multiples of 8 blocks)
  int nwg = gridDim.x * gridDim.y;
  int bid0 = blockIdx.y * gridDim.x + blockIdx.x;
  int bid = (bid0 & 7) * (nwg >> 3) + (bid0 >> 3);
  const int row0A = (bid % gridDim.x) * 128;
  const int row0B = (bid / gridDim.x) * 128;
  const int wave = t >> 6, lane = t & 63;
  const int wm = wave >> 1, wn = wave & 1;
  const int g = lane >> 4, lr = lane & 15;

  f32x4 acc[4][4] = {};

  for (int k0 = 0; k0 < K; k0 += 64) {
#pragma unroll
    for (int p = 0; p < 4; ++p) {
      int cbase = (wave * 4 + p) * 64;
      int ci = cbase + lane;
      int r = ci >> 3, cp = ci & 7, cl = cp ^ (r & 7);
      gload16(A + (size_t)(row0A + r) * lda + k0 + cl * 8, &As[cbase * 8]);
      gload16(Bt + (size_t)(row0B + r) * K + k0 + cl * 8, &Bs[cbase * 8]);
    }
    __syncthreads();
#pragma unroll
    for (int kk = 0; kk < 2; ++kk) {
      bf16x8 af[4], bfr[4];
#pragma unroll
      for (int mt = 0; mt < 4; ++mt) {
        int r = wm * 64 + mt * 16 + lr, c = kk * 4 + g;
        af[mt] = *(const bf16x8*)((char*)As + r * 128 + ((c ^ (r & 7)) * 16));
      }
#pragma unroll
      for (int nt = 0; nt < 4; ++nt) {
        int r = wn * 64 + nt * 16 + lr, c = kk * 4 + g;
        bfr[nt] = *(const bf16x8*)((char*)Bs + r * 128 + ((c ^ (r & 7)) * 16));
      }
#pragma unroll
      for (int mt = 0; mt < 4; ++mt)
#pragma unroll
        for (int nt = 0; nt < 4; ++nt)
          acc[mt][nt] = MFMA16(af[mt], bfr[nt], acc[mt][nt]);
    }
    __syncthreads();
  }

  float bias_v[4];
#pragma unroll
  for (int nt = 0; nt < 4; ++nt)
    bias_v[nt] = HAS_BIAS ? bias[row0B + wn * 64 + nt * 16 + lr] : 0.f;
#pragma unroll
  for (int mt = 0; mt < 4; ++mt) {
    int grow_base = row0A + wm * 64 + mt * 16 + g * 4;
#pragma unroll
    for (int nt = 0; nt < 4; ++nt) {
      int gcol = row0B + wn * 64 + nt * 16 + lr;
#pragma unroll
      for (int j = 0; j < 4; ++j) {
        int grow = grow_base + j;
        float v = acc[mt][nt][j] + bias_v[nt];
        if (HAS_RES) v += res[(size_t)grow * ldc + gcol];
        C[(size_t)grow * ldc + gcol] = (OutT)v;
      }
    }
  }
}

// ---------------------------------------------------------------------------
// RoPE + scatter (qkv column-permuted: [Q|K|V] each (token, h*64+hd)).
// q pre-scaled by 0.125*log2(e) so attn uses native exp2. v packed to
// (bh, hd, n) with kv-permutation matching the PV register fragment.
// ---------------------------------------------------------------------------
__global__ __launch_bounds__(256) void rope_scatter(
    const __bf16* __restrict__ qkv, const float* __restrict__ enc,
    __bf16* __restrict__ q, __bf16* __restrict__ kk, __bf16* __restrict__ vt) {
  int bh = blockIdx.y;
  int b = bh >> 4, h = bh & 15;
  int n0 = blockIdx.x * 64;
  int t = threadIdx.x;
  const float QSC = 0.125f * 1.44269504088896f;
#pragma unroll
  for (int i = 0; i < 2; ++i) {
    int id = t + i * 256;
    int nl = id >> 3, cc = id & 7;
    int n = n0 + nl;
    size_t row = (size_t)(b * 2048 + n) * 3072;
    bf16x8 qv = *(const bf16x8*)(qkv + row + h * 64 + cc * 8);
    bf16x8 kv = *(const bf16x8*)(qkv + row + 1024 + h * 64 + cc * 8);
    const float* e0 = enc + (size_t)n * 64 + cc * 8;
    const float* e1 = e0 + 131072;
    __bf16 qo[8], ko[8];
#pragma unroll
    for (int e = 0; e < 8; e += 2) {
      float q0 = (float)qv[e], q1 = (float)qv[e + 1];
      float k0 = (float)kv[e], k1 = (float)kv[e + 1];
      float f00 = e0[e], f01 = e0[e + 1], f10 = e1[e], f11 = e1[e + 1];
      qo[e] = (__bf16)((q0 * f00 - q1 * f10) * QSC);
      qo[e + 1] = (__bf16)((q1 * f01 + q0 * f11) * QSC);
      ko[e] = (__bf16)(k0 * f00 - k1 * f10);
      ko[e + 1] = (__bf16)(k1 * f01 + k0 * f11);
    }
    size_t qb = ((size_t)bh * 2048 + n) * 64 + cc * 8;
    *(uint4*)(q + qb) = *(uint4*)qo;
    *(uint4*)(kk + qb) = *(uint4*)ko;
  }
#pragma unroll
  for (int i = 0; i < 2; ++i) {
    int id = t + i * 256;
    int hd = id >> 3, c = id & 7;
    __bf16 tmp[8];
#pragma unroll
    for (int e = 0; e < 8; ++e) {
      int kv = (c >> 2) * 32 + (e >> 2) * 16 + (c & 3) * 4 + (e & 3);
      int n = n0 + kv;
      tmp[e] = qkv[(size_t)(b * 2048 + n) * 3072 + 2048 + h * 64 + hd];
    }
    *(uint4*)(vt + ((size_t)bh * 64 + hd) * 2048 + n0 + c * 8) = *(uint4*)tmp;
  }
}

// ---------------------------------------------------------------------------
// Flash attention: swapped QK^T (lane-local softmax), native exp2, row-sum
// via all-ones MFMA (no shuffles/adds), P fed to PV from registers.
// Double-buffered gload_lds staging; setprio around MFMA clusters; XCD swizzle.
// ctx written into h_in right half (ld 2048).
// ---------------------------------------------------------------------------
__global__ __launch_bounds__(256) void attn_kernel(
    const __bf16* __restrict__ q, const __bf16* __restrict__ k,
    const __bf16* __restrict__ vt, __bf16* __restrict__ ctx) {
  __shared__ __attribute__((aligned(16))) __bf16 Ks[2][64 * 64];
  __shared__ __attribute__((aligned(16))) __bf16 Vs[2][64 * 64];

  int nwg = gridDim.x * gridDim.y;
  int bid0 = blockIdx.y * gridDim.x + blockIdx.x;
  int bid = (bid0 & 7) * (nwg >> 3) + (bid0 >> 3);
  const int bh = bid / gridDim.x, qblk = bid % gridDim.x;
  const int b = bh >> 4, h = bh & 15;
  const int q0 = qblk * 64;
  const int t = threadIdx.x, wave = t >> 6, lane = t & 63;
  const int g = lane >> 4, lr = lane & 15;
  const int qrow = q0 + wave * 16;

  const __bf16* kbase = k + (size_t)bh * 2048 * 64;
  const __bf16* vbase = vt + (size_t)bh * 64 * 2048;

  bf16x8 qf[2];
#pragma unroll
  for (int kc = 0; kc < 2; ++kc)
    qf[kc] = *(const bf16x8*)(q + ((size_t)bh * 2048 + qrow + lr) * 64 + kc * 32 + g * 8);

  bf16x8 ones;
#pragma unroll
  for (int e = 0; e < 8; ++e) ones[e] = (__bf16)1.0f;

  f32x4 o[4] = {};
  f32x4 lacc = {};  // every element = running row-sum of P for q=lr

#define STAGE_ATTN(buf, kv0)                                                    \
  {                                                                             \
    _Pragma("unroll") for (int p = 0; p < 2; ++p) {                             \
      int cbase = wave * 128 + p * 64;                                          \
      int ci = cbase + lane;                                                    \
      int r = ci >> 3, cp = ci & 7, cl = cp ^ (r & 7);                          \
      gload16(kbase + (size_t)((kv0) + r) * 64 + cl * 8, &Ks[buf][cbase * 8]);  \
      gload16(vbase + (size_t)r * 2048 + (kv0) + cl * 8, &Vs[buf][cbase * 8]);  \
    }                                                                           \
  }

  STAGE_ATTN(0, 0);
  __syncthreads();
  int buf = 0;

  for (int kv0 = 0; kv0 < 2048; kv0 += 64) {
    if (kv0 + 64 < 2048) STAGE_ATTN(buf ^ 1, kv0 + 64);

    f32x4 s[4];
    __builtin_amdgcn_s_setprio(1);
#pragma unroll
    for (int nt = 0; nt < 4; ++nt) {
      int r = nt * 16 + lr;
      bf16x8 kf0 = *(const bf16x8*)((char*)Ks[buf] + r * 128 + ((g ^ (r & 7)) * 16));
      bf16x8 kf1 = *(const bf16x8*)((char*)Ks[buf] + r * 128 + (((4 + g) ^ (r & 7)) * 16));
      f32x4 a = {};
      a = MFMA16(kf0, qf[0], a);
      a = MFMA16(kf1, qf[1], a);
      s[nt] = a;
    }
    __builtin_amdgcn_s_setprio(0);

#pragma unroll
    for (int t2 = 0; t2 < 2; ++t2) {
      bf16x8 pf;
#pragma unroll
      for (int e = 0; e < 8; ++e)
        pf[e] = (__bf16)__builtin_amdgcn_exp2f(s[2 * t2 + (e >> 2)][e & 3]);
      lacc = MFMA16(ones, pf, lacc);
      __builtin_amdgcn_s_setprio(1);
#pragma unroll
      for (int nt = 0; nt < 4; ++nt) {
        int r = nt * 16 + lr;
        bf16x8 vf = *(const bf16x8*)((char*)Vs[buf] + r * 128 + (((t2 * 4 + g) ^ (r & 7)) * 16));
        o[nt] = MFMA16(vf, pf, o[nt]);
      }
      __builtin_amdgcn_s_setprio(0);
    }
    __syncthreads();
    buf ^= 1;
  }

  float inv = 1.f / lacc[0];

  size_t obase = ((size_t)(b * 2048 + qrow + lr)) * 2048 + 1024 + h * 64;
#pragma unroll
  for (int nt = 0; nt < 4; ++nt) {
    __bf16 w4[4];
#pragma unroll
    for (int j = 0; j < 4; ++j) w4[j] = (__bf16)(o[nt][j] * inv);
    *(uint2*)(ctx + obase + nt * 16 + g * 4) = *(uint2*)w4;
  }
#undef STAGE_ATTN
}

// ---------------------------------------------------------------------------
// LayerNorm + exact GELU over rows of 2048
// ---------------------------------------------------------------------------
__global__ __launch_bounds__(256) void ln_gelu(const __bf16* __restrict__ hin,
                                               const float* __restrict__ lns,
                                               const float* __restrict__ lnb,
                                               __bf16* __restrict__ hout) {
  int row = blockIdx.x;
  const __bf16* rp = hin + (size_t)row * 2048;
  int t = threadIdx.x;
  __bf16 tmp[8];
  *(uint4*)tmp = *(const uint4*)(rp + t * 8);
  float vals[8], s = 0.f, s2 = 0.f;
#pragma unroll
  for (int e = 0; e < 8; ++e) {
    float x = (float)tmp[e];
    vals[e] = x;
    s += x;
    s2 += x * x;
  }
#pragma unroll
  for (int m = 1; m < 64; m <<= 1) {
    s += __shfl_xor(s, m, 64);
    s2 += __shfl_xor(s2, m, 64);
  }
  __shared__ float red[8];
  int wave = t >> 6, lane = t & 63;
  if (lane == 0) { red[wave] = s; red[4 + wave] = s2; }
  __syncthreads();
  s = red[0] + red[1] + red[2] + red[3];
  s2 = red[4] + red[5] + red[6] + red[7];
  float mu = s * (1.f / 2048.f);
  float var = s2 * (1.f / 2048.f) - mu * mu;
  float rstd = rsqrtf(var + 1e-5f);
  __bf16 outv[8];
#pragma unroll
  for (int e = 0; e < 8; ++e) {
    int c = t * 8 + e;
    float xh = (vals[e] - mu) * rstd * lns[c] + lnb[c];
    float gg = 0.5f * xh * (1.f + erff(xh * 0.70710678118f));
    outv[e] = (__bf16)gg;
  }
  *(uint4*)(hout + (size_t)row * 2048 + t * 8) = *(uint4*)outv;
}

// ---------------------------------------------------------------------------
// Launch
// ---------------------------------------------------------------------------
extern "C" void kernel_launch(void* const* d_in, const int* in_sizes, int n_in,
                              void* d_out, int out_size, void* d_ws, size_t ws_size,
                              hipStream_t stream) {
  const float* x = (const float*)d_in[0];
  const float* enc = (const float*)d_in[1];
  const float* wqkv = (const float*)d_in[2];
  const float* bqkv = (const float*)d_in[3];
  const float* wout = (const float*)d_in[4];
  const float* bout = (const float*)d_in[5];
  const float* wffn0 = (const float*)d_in[6];
  const float* bffn0 = (const float*)d_in[7];
  const float* lns = (const float*)d_in[8];
  const float* lnb = (const float*)d_in[9];
  const float* wffn3 = (const float*)d_in[10];
  const float* bffn3 = (const float*)d_in[11];
  float* out = (float*)d_out;
  char* ws = (char*)d_ws;

  __bf16* wT_qkv = (__bf16*)(ws + 0);              //  6291456
  __bf16* wT_ffn0 = (__bf16*)(ws + 6291456);       //  8388608
  __bf16* wT_ffn3 = (__bf16*)(ws + 14680064);      //  4194304
  __bf16* wout_bf = (__bf16*)(ws + 18874368);      //  2097152
  __bf16* wpT_tmp = (__bf16*)(ws + 20971520);      //  4194304 (reused: bias part)
  float* bias_part = (float*)(ws + 20971520);      //   131072 (after copy_cols)
  float* bqkv_p = (float*)(ws + 25165824);         //    12288
  float* bffn0_f = (float*)(ws + 25178112);        //     8192
  __bf16* h_in = (__bf16*)(ws + 25186304);         // 33554432  [x | ctx]
  __bf16* qkv = (__bf16*)(ws + 58740736);          // 50331648
  __bf16* ffn0o = qkv;                             // alias (qkv dead after rope)
  __bf16* qb = (__bf16*)(ws + 109072384);          // 16777216
  __bf16* h2 = qb;                                 // alias (q dead after attn)
  __bf16* kb = (__bf16*)(ws + 125849600);          // 16777216
  __bf16* vtb = (__bf16*)(ws + 142626816);         // 16777216

  dim3 blk(256);
  // weight prep
  transpose_qkv_perm<<<dim3(96, 32), blk, 0, stream>>>(wqkv, wT_qkv);
  bias_perm<<<12, blk, 0, stream>>>(bqkv, bqkv_p);
  transpose_bf16<<<dim3(64, 64), blk, 0, stream>>>(wffn0, wT_ffn0, 2048, 2048);
  transpose_bf16<<<dim3(32, 64), blk, 0, stream>>>(wffn3, wT_ffn3, 2048, 1024);
  convert_plain<<<512, blk, 0, stream>>>(wout, wout_bf);
  // W'T = W0b^T * Wout^T (2048x1024), splice into wT_ffn0 cols [1024:2048)
  gemm_kernel<__bf16, false, false><<<dim3(16, 8), blk, 0, stream>>>(
      wT_ffn0 + 1024, 2048, wout_bf, nullptr, wpT_tmp, 1024, nullptr, 2048, 1024, 1024);
  copy_cols<<<1024, blk, 0, stream>>>(wpT_tmp, wT_ffn0);
  fuse_bias_part<<<dim3(8, 16), blk, 0, stream>>>(bout, wffn0, bias_part);
  fuse_bias_red<<<8, blk, 0, stream>>>(bias_part, bffn0, bffn0_f);
  convert_x<<<4096, blk, 0, stream>>>(x, h_in);

  // QKV projection: [8192,1024] x [1024,3072]
  gemm_kernel<__bf16, false, true><<<dim3(64, 24), blk, 0, stream>>>(
      h_in, 2048, wT_qkv, bqkv_p, qkv, 3072, nullptr, 8192, 3072, 1024);

  rope_scatter<<<dim3(32, 64), blk, 0, stream>>>(qkv, enc, qb, kb, vtb);
  attn_kernel<<<dim3(32, 64), blk, 0, stream>>>(qb, kb, vtb, h_in);

  // FFN0 (with fused out-proj): [8192,2048] x [2048,2048]
  gemm_kernel<__bf16, false, true><<<dim3(64, 16), blk, 0, stream>>>(
      h_in, 2048, wT_ffn0, bffn0_f, ffn0o, 2048, nullptr, 8192, 2048, 2048);

  ln_gelu<<<8192, blk, 0, stream>>>(ffn0o, lns, lnb, h2);

  // FFN3 + bias + residual -> out (fp32)
  gemm_kernel<float, true, true><<<dim3(64, 8), blk, 0, stream>>>(
      h2, 2048, wT_ffn3, bffn3, out, 1024, x, 8192, 1024, 2048);
}

// Round 5
// 417.194 us; speedup vs baseline: 1.1197x; 1.0656x over previous
//
#include <hip/hip_runtime.h>
#include <hip/hip_bf16.h>
#include <math.h>

typedef __bf16 bf16x8 __attribute__((ext_vector_type(8)));
typedef float f32x4 __attribute__((ext_vector_type(4)));

#define MFMA16(a, b, c) __builtin_amdgcn_mfma_f32_16x16x32_bf16((a), (b), (c), 0, 0, 0)

__device__ __forceinline__ void gload16(const void* g, void* l) {
  __builtin_amdgcn_global_load_lds((const __attribute__((address_space(1))) void*)g,
                                   (__attribute__((address_space(3))) void*)l, 16, 0, 0);
}

// ---------------------------------------------------------------------------
// Weight transpose + fp32 -> bf16:  out[n][k] = in[k][n], separate strides.
// grid.x covers out-rows (n), grid.y covers in-rows (k), 32x32 tiles.
// ---------------------------------------------------------------------------
__global__ __launch_bounds__(256) void transpose_bf16(const float* __restrict__ in,
                                                      int ldin,
                                                      __bf16* __restrict__ out,
                                                      int ldo) {
  __shared__ float tile[32][33];
  int n0 = blockIdx.x * 32, k0 = blockIdx.y * 32;
  int tx = threadIdx.x & 31, ty = threadIdx.x >> 5;
#pragma unroll
  for (int r = 0; r < 32; r += 8)
    tile[ty + r][tx] = in[(size_t)(k0 + ty + r) * ldin + n0 + tx];
  __syncthreads();
#pragma unroll
  for (int r = 0; r < 32; r += 8)
    out[(size_t)(n0 + ty + r) * ldo + k0 + tx] = (__bf16)tile[tx][ty + r];
}

// QKV transpose with output-column permutation: orig col n -> n' = which*1024 + h*64 + hd
__global__ __launch_bounds__(256) void transpose_qkv_perm(const float* __restrict__ in,
                                                          __bf16* __restrict__ out) {
  __shared__ float tile[32][33];
  int n0 = blockIdx.x * 32, k0 = blockIdx.y * 32;
  int tx = threadIdx.x & 31, ty = threadIdx.x >> 5;
#pragma unroll
  for (int r = 0; r < 32; r += 8)
    tile[ty + r][tx] = in[(size_t)(k0 + ty + r) * 3072 + n0 + tx];
  __syncthreads();
#pragma unroll
  for (int r = 0; r < 32; r += 8) {
    int n = n0 + ty + r;
    int h = n / 192, rem = n % 192, hd = rem / 3, which = rem % 3;
    int np = which * 1024 + h * 64 + hd;
    out[(size_t)np * 1024 + k0 + tx] = (__bf16)tile[tx][ty + r];
  }
}

__global__ __launch_bounds__(256) void bias_perm(const float* __restrict__ b,
                                                 float* __restrict__ bp) {
  int n = blockIdx.x * 256 + threadIdx.x;
  if (n < 3072) {
    int h = n / 192, rem = n % 192, hd = rem / 3, which = rem % 3;
    bp[which * 1024 + h * 64 + hd] = b[n];
  }
}

// plain fp32 -> bf16 convert (contiguous)
__global__ __launch_bounds__(256) void convert_plain(const float* __restrict__ in,
                                                     __bf16* __restrict__ out) {
  int id = blockIdx.x * 256 + threadIdx.x;
  const float* src = in + (size_t)id * 8;
  __bf16 tmp[8];
#pragma unroll
  for (int e = 0; e < 8; ++e) tmp[e] = (__bf16)src[e];
  *(uint4*)(out + (size_t)id * 8) = *(uint4*)tmp;
}

// x (fp32 [8192][1024]) -> left half of h_in (bf16 [8192][2048])
__global__ __launch_bounds__(256) void convert_x(const float* __restrict__ x,
                                                 __bf16* __restrict__ h) {
  int id = blockIdx.x * 256 + threadIdx.x;
  int row = id >> 7, cc = id & 127;
  const float* src = x + (size_t)row * 1024 + cc * 8;
  __bf16 tmp[8];
#pragma unroll
  for (int e = 0; e < 8; ++e) tmp[e] = (__bf16)src[e];
  *(uint4*)(h + (size_t)row * 2048 + cc * 8) = *(uint4*)tmp;
}

// b'[n] = bffn0[n] + sum_e bout[e] * W0[1024+e][n]  -- deterministic 2-stage
__global__ __launch_bounds__(256) void fuse_bias_part(const float* __restrict__ bout,
                                                      const float* __restrict__ w0,
                                                      float* __restrict__ part) {
  int n = blockIdx.x * 256 + threadIdx.x;  // grid (8,16)
  int e0 = blockIdx.y * 64;
  float s = 0.f;
#pragma unroll 4
  for (int e = 0; e < 64; ++e)
    s += bout[e0 + e] * w0[(size_t)(1024 + e0 + e) * 2048 + n];
  part[(size_t)blockIdx.y * 2048 + n] = s;
}

__global__ __launch_bounds__(256) void fuse_bias_red(const float* __restrict__ part,
                                                     const float* __restrict__ b0,
                                                     float* __restrict__ bf) {
  int n = blockIdx.x * 256 + threadIdx.x;  // grid 8
  float s = b0[n];
#pragma unroll
  for (int y = 0; y < 16; ++y) s += part[(size_t)y * 2048 + n];
  bf[n] = s;
}

// ---------------------------------------------------------------------------
// 128x128 GEMM (round-2 verified structure, default block order).
// global_load_lds(16B) staging, pre-swizzled source col, linear LDS dest,
// XOR-swizzled reads. 2 barriers per K-step.
// ---------------------------------------------------------------------------
template <typename OutT, bool HAS_RES, bool HAS_BIAS>
__global__ __launch_bounds__(256) void gemm_kernel(
    const __bf16* __restrict__ A, int lda,
    const __bf16* __restrict__ Bt,            // N x K row-major
    const float* __restrict__ bias,
    OutT* __restrict__ C, int ldc,
    const float* __restrict__ res,
    int M, int Nn, int K) {
  __shared__ __attribute__((aligned(16))) __bf16 As[128 * 64];
  __shared__ __attribute__((aligned(16))) __bf16 Bs[128 * 64];

  const int t = threadIdx.x;
  const int row0A = blockIdx.x * 128;
  const int row0B = blockIdx.y * 128;
  const int wave = t >> 6, lane = t & 63;
  const int wm = wave >> 1, wn = wave & 1;
  const int g = lane >> 4, lr = lane & 15;

  f32x4 acc[4][4] = {};

  for (int k0 = 0; k0 < K; k0 += 64) {
#pragma unroll
    for (int p = 0; p < 4; ++p) {
      int cbase = (wave * 4 + p) * 64;
      int ci = cbase + lane;
      int r = ci >> 3, cp = ci & 7, cl = cp ^ (r & 7);
      gload16(A + (size_t)(row0A + r) * lda + k0 + cl * 8, &As[cbase * 8]);
      gload16(Bt + (size_t)(row0B + r) * K + k0 + cl * 8, &Bs[cbase * 8]);
    }
    __syncthreads();
#pragma unroll
    for (int kk = 0; kk < 2; ++kk) {
      bf16x8 af[4], bfr[4];
#pragma unroll
      for (int mt = 0; mt < 4; ++mt) {
        int r = wm * 64 + mt * 16 + lr, c = kk * 4 + g;
        af[mt] = *(const bf16x8*)((char*)As + r * 128 + ((c ^ (r & 7)) * 16));
      }
#pragma unroll
      for (int nt = 0; nt < 4; ++nt) {
        int r = wn * 64 + nt * 16 + lr, c = kk * 4 + g;
        bfr[nt] = *(const bf16x8*)((char*)Bs + r * 128 + ((c ^ (r & 7)) * 16));
      }
#pragma unroll
      for (int mt = 0; mt < 4; ++mt)
#pragma unroll
        for (int nt = 0; nt < 4; ++nt)
          acc[mt][nt] = MFMA16(af[mt], bfr[nt], acc[mt][nt]);
    }
    __syncthreads();
  }

  float bias_v[4];
#pragma unroll
  for (int nt = 0; nt < 4; ++nt)
    bias_v[nt] = HAS_BIAS ? bias[row0B + wn * 64 + nt * 16 + lr] : 0.f;
#pragma unroll
  for (int mt = 0; mt < 4; ++mt) {
    int grow_base = row0A + wm * 64 + mt * 16 + g * 4;
#pragma unroll
    for (int nt = 0; nt < 4; ++nt) {
      int gcol = row0B + wn * 64 + nt * 16 + lr;
#pragma unroll
      for (int j = 0; j < 4; ++j) {
        int grow = grow_base + j;
        float v = acc[mt][nt][j] + bias_v[nt];
        if (HAS_RES) v += res[(size_t)grow * ldc + gcol];
        C[(size_t)grow * ldc + gcol] = (OutT)v;
      }
    }
  }
}

// ---------------------------------------------------------------------------
// RoPE + scatter (qkv column-permuted: [Q|K|V] each (token, h*64+hd)).
// q pre-scaled by 0.125*log2(e) so attn uses native exp2. v packed to
// (bh, hd, n) with kv-permutation matching the PV register fragment.
// ---------------------------------------------------------------------------
__global__ __launch_bounds__(256) void rope_scatter(
    const __bf16* __restrict__ qkv, const float* __restrict__ enc,
    __bf16* __restrict__ q, __bf16* __restrict__ kk, __bf16* __restrict__ vt) {
  int bh = blockIdx.y;
  int b = bh >> 4, h = bh & 15;
  int n0 = blockIdx.x * 64;
  int t = threadIdx.x;
  const float QSC = 0.125f * 1.44269504088896f;
#pragma unroll
  for (int i = 0; i < 2; ++i) {
    int id = t + i * 256;
    int nl = id >> 3, cc = id & 7;
    int n = n0 + nl;
    size_t row = (size_t)(b * 2048 + n) * 3072;
    bf16x8 qv = *(const bf16x8*)(qkv + row + h * 64 + cc * 8);
    bf16x8 kv = *(const bf16x8*)(qkv + row + 1024 + h * 64 + cc * 8);
    const float* e0 = enc + (size_t)n * 64 + cc * 8;
    const float* e1 = e0 + 131072;
    __bf16 qo[8], ko[8];
#pragma unroll
    for (int e = 0; e < 8; e += 2) {
      float q0 = (float)qv[e], q1 = (float)qv[e + 1];
      float k0 = (float)kv[e], k1 = (float)kv[e + 1];
      float f00 = e0[e], f01 = e0[e + 1], f10 = e1[e], f11 = e1[e + 1];
      qo[e] = (__bf16)((q0 * f00 - q1 * f10) * QSC);
      qo[e + 1] = (__bf16)((q1 * f01 + q0 * f11) * QSC);
      ko[e] = (__bf16)(k0 * f00 - k1 * f10);
      ko[e + 1] = (__bf16)(k1 * f01 + k0 * f11);
    }
    size_t qb = ((size_t)bh * 2048 + n) * 64 + cc * 8;
    *(uint4*)(q + qb) = *(uint4*)qo;
    *(uint4*)(kk + qb) = *(uint4*)ko;
  }
#pragma unroll
  for (int i = 0; i < 2; ++i) {
    int id = t + i * 256;
    int hd = id >> 3, c = id & 7;
    __bf16 tmp[8];
#pragma unroll
    for (int e = 0; e < 8; ++e) {
      int kv = (c >> 2) * 32 + (e >> 2) * 16 + (c & 3) * 4 + (e & 3);
      int n = n0 + kv;
      tmp[e] = qkv[(size_t)(b * 2048 + n) * 3072 + 2048 + h * 64 + hd];
    }
    *(uint4*)(vt + ((size_t)bh * 64 + hd) * 2048 + n0 + c * 8) = *(uint4*)tmp;
  }
}

// ---------------------------------------------------------------------------
// Flash attention: swapped QK^T (lane-local softmax), native exp2, row-sum
// via all-ones MFMA, P fed to PV from registers. Double-buffered gload_lds
// staging; setprio around MFMA clusters; XCD swizzle (8 heads/XCD -> KV L2-fit).
// ctx written into h_in right half (ld 2048).
// ---------------------------------------------------------------------------
__global__ __launch_bounds__(256) void attn_kernel(
    const __bf16* __restrict__ q, const __bf16* __restrict__ k,
    const __bf16* __restrict__ vt, __bf16* __restrict__ ctx) {
  __shared__ __attribute__((aligned(16))) __bf16 Ks[2][64 * 64];
  __shared__ __attribute__((aligned(16))) __bf16 Vs[2][64 * 64];

  int nwg = gridDim.x * gridDim.y;
  int bid0 = blockIdx.y * gridDim.x + blockIdx.x;
  int bid = (bid0 & 7) * (nwg >> 3) + (bid0 >> 3);
  const int bh = bid / gridDim.x, qblk = bid % gridDim.x;
  const int b = bh >> 4, h = bh & 15;
  const int q0 = qblk * 64;
  const int t = threadIdx.x, wave = t >> 6, lane = t & 63;
  const int g = lane >> 4, lr = lane & 15;
  const int qrow = q0 + wave * 16;

  const __bf16* kbase = k + (size_t)bh * 2048 * 64;
  const __bf16* vbase = vt + (size_t)bh * 64 * 2048;

  bf16x8 qf[2];
#pragma unroll
  for (int kc = 0; kc < 2; ++kc)
    qf[kc] = *(const bf16x8*)(q + ((size_t)bh * 2048 + qrow + lr) * 64 + kc * 32 + g * 8);

  bf16x8 ones;
#pragma unroll
  for (int e = 0; e < 8; ++e) ones[e] = (__bf16)1.0f;

  f32x4 o[4] = {};
  f32x4 lacc = {};  // every element = running row-sum of P for q=lr

#define STAGE_ATTN(buf, kv0)                                                    \
  {                                                                             \
    _Pragma("unroll") for (int p = 0; p < 2; ++p) {                             \
      int cbase = wave * 128 + p * 64;                                          \
      int ci = cbase + lane;                                                    \
      int r = ci >> 3, cp = ci & 7, cl = cp ^ (r & 7);                          \
      gload16(kbase + (size_t)((kv0) + r) * 64 + cl * 8, &Ks[buf][cbase * 8]);  \
      gload16(vbase + (size_t)r * 2048 + (kv0) + cl * 8, &Vs[buf][cbase * 8]);  \
    }                                                                           \
  }

  STAGE_ATTN(0, 0);
  __syncthreads();
  int buf = 0;

  for (int kv0 = 0; kv0 < 2048; kv0 += 64) {
    if (kv0 + 64 < 2048) STAGE_ATTN(buf ^ 1, kv0 + 64);

    f32x4 s[4];
    __builtin_amdgcn_s_setprio(1);
#pragma unroll
    for (int nt = 0; nt < 4; ++nt) {
      int r = nt * 16 + lr;
      bf16x8 kf0 = *(const bf16x8*)((char*)Ks[buf] + r * 128 + ((g ^ (r & 7)) * 16));
      bf16x8 kf1 = *(const bf16x8*)((char*)Ks[buf] + r * 128 + (((4 + g) ^ (r & 7)) * 16));
      f32x4 a = {};
      a = MFMA16(kf0, qf[0], a);
      a = MFMA16(kf1, qf[1], a);
      s[nt] = a;
    }
    __builtin_amdgcn_s_setprio(0);

#pragma unroll
    for (int t2 = 0; t2 < 2; ++t2) {
      bf16x8 pf;
#pragma unroll
      for (int e = 0; e < 8; ++e)
        pf[e] = (__bf16)__builtin_amdgcn_exp2f(s[2 * t2 + (e >> 2)][e & 3]);
      lacc = MFMA16(ones, pf, lacc);
      __builtin_amdgcn_s_setprio(1);
#pragma unroll
      for (int nt = 0; nt < 4; ++nt) {
        int r = nt * 16 + lr;
        bf16x8 vf = *(const bf16x8*)((char*)Vs[buf] + r * 128 + (((t2 * 4 + g) ^ (r & 7)) * 16));
        o[nt] = MFMA16(vf, pf, o[nt]);
      }
      __builtin_amdgcn_s_setprio(0);
    }
    __syncthreads();
    buf ^= 1;
  }

  float inv = 1.f / lacc[0];

  size_t obase = ((size_t)(b * 2048 + qrow + lr)) * 2048 + 1024 + h * 64;
#pragma unroll
  for (int nt = 0; nt < 4; ++nt) {
    __bf16 w4[4];
#pragma unroll
    for (int j = 0; j < 4; ++j) w4[j] = (__bf16)(o[nt][j] * inv);
    *(uint2*)(ctx + obase + nt * 16 + g * 4) = *(uint2*)w4;
  }
#undef STAGE_ATTN
}

// ---------------------------------------------------------------------------
// LayerNorm + exact GELU over rows of 2048
// ---------------------------------------------------------------------------
__global__ __launch_bounds__(256) void ln_gelu(const __bf16* __restrict__ hin,
                                               const float* __restrict__ lns,
                                               const float* __restrict__ lnb,
                                               __bf16* __restrict__ hout) {
  int row = blockIdx.x;
  const __bf16* rp = hin + (size_t)row * 2048;
  int t = threadIdx.x;
  __bf16 tmp[8];
  *(uint4*)tmp = *(const uint4*)(rp + t * 8);
  float vals[8], s = 0.f, s2 = 0.f;
#pragma unroll
  for (int e = 0; e < 8; ++e) {
    float x = (float)tmp[e];
    vals[e] = x;
    s += x;
    s2 += x * x;
  }
#pragma unroll
  for (int m = 1; m < 64; m <<= 1) {
    s += __shfl_xor(s, m, 64);
    s2 += __shfl_xor(s2, m, 64);
  }
  __shared__ float red[8];
  int wave = t >> 6, lane = t & 63;
  if (lane == 0) { red[wave] = s; red[4 + wave] = s2; }
  __syncthreads();
  s = red[0] + red[1] + red[2] + red[3];
  s2 = red[4] + red[5] + red[6] + red[7];
  float mu = s * (1.f / 2048.f);
  float var = s2 * (1.f / 2048.f) - mu * mu;
  float rstd = rsqrtf(var + 1e-5f);
  __bf16 outv[8];
#pragma unroll
  for (int e = 0; e < 8; ++e) {
    int c = t * 8 + e;
    float xh = (vals[e] - mu) * rstd * lns[c] + lnb[c];
    float gg = 0.5f * xh * (1.f + erff(xh * 0.70710678118f));
    outv[e] = (__bf16)gg;
  }
  *(uint4*)(hout + (size_t)row * 2048 + t * 8) = *(uint4*)outv;
}

// ---------------------------------------------------------------------------
// Launch
// ---------------------------------------------------------------------------
extern "C" void kernel_launch(void* const* d_in, const int* in_sizes, int n_in,
                              void* d_out, int out_size, void* d_ws, size_t ws_size,
                              hipStream_t stream) {
  const float* x = (const float*)d_in[0];
  const float* enc = (const float*)d_in[1];
  const float* wqkv = (const float*)d_in[2];
  const float* bqkv = (const float*)d_in[3];
  const float* wout = (const float*)d_in[4];
  const float* bout = (const float*)d_in[5];
  const float* wffn0 = (const float*)d_in[6];
  const float* bffn0 = (const float*)d_in[7];
  const float* lns = (const float*)d_in[8];
  const float* lnb = (const float*)d_in[9];
  const float* wffn3 = (const float*)d_in[10];
  const float* bffn3 = (const float*)d_in[11];
  float* out = (float*)d_out;
  char* ws = (char*)d_ws;

  __bf16* wT_qkv = (__bf16*)(ws + 0);              //  6291456
  __bf16* wT_ffn0 = (__bf16*)(ws + 6291456);       //  8388608
  __bf16* wT_ffn3 = (__bf16*)(ws + 14680064);      //  4194304
  __bf16* wout_bf = (__bf16*)(ws + 18874368);      //  2097152
  __bf16* w0bT = (__bf16*)(ws + 20971520);         //  4194304 (reused later: bias part)
  float* bias_part = (float*)(ws + 20971520);      //   131072 (after W'' gemm)
  float* bqkv_p = (float*)(ws + 25165824);         //    12288
  float* bffn0_f = (float*)(ws + 25178112);        //     8192
  __bf16* h_in = (__bf16*)(ws + 25186304);         // 33554432  [x | ctx]
  __bf16* qkv = (__bf16*)(ws + 58740736);          // 50331648
  __bf16* ffn0o = qkv;                             // alias (qkv dead after rope)
  __bf16* qb = (__bf16*)(ws + 109072384);          // 16777216
  __bf16* h2 = qb;                                 // alias (q dead after attn)
  __bf16* kb = (__bf16*)(ws + 125849600);          // 16777216
  __bf16* vtb = (__bf16*)(ws + 142626816);         // 16777216

  dim3 blk(256);
  // weight prep
  transpose_qkv_perm<<<dim3(96, 32), blk, 0, stream>>>(wqkv, wT_qkv);
  bias_perm<<<12, blk, 0, stream>>>(bqkv, bqkv_p);
  // W0 top half (k<1024) -> wT_ffn0 cols [0:1024), row stride 2048
  transpose_bf16<<<dim3(64, 32), blk, 0, stream>>>(wffn0, 2048, wT_ffn0, 2048);
  // W0 bottom half -> separate buffer (A input for the W'' product)
  transpose_bf16<<<dim3(64, 32), blk, 0, stream>>>(wffn0 + (size_t)1024 * 2048, 2048,
                                                   w0bT, 1024);
  transpose_bf16<<<dim3(32, 64), blk, 0, stream>>>(wffn3, 1024, wT_ffn3, 2048);
  convert_plain<<<512, blk, 0, stream>>>(wout, wout_bf);
  // W''T[n][e] = sum_c W0b[c][n] * Wout[e][c] -> directly into wT_ffn0 cols [1024:2048)
  gemm_kernel<__bf16, false, false><<<dim3(16, 8), blk, 0, stream>>>(
      w0bT, 1024, wout_bf, nullptr, wT_ffn0 + 1024, 2048, nullptr, 2048, 1024, 1024);
  fuse_bias_part<<<dim3(8, 16), blk, 0, stream>>>(bout, wffn0, bias_part);
  fuse_bias_red<<<8, blk, 0, stream>>>(bias_part, bffn0, bffn0_f);
  convert_x<<<4096, blk, 0, stream>>>(x, h_in);

  // QKV projection: [8192,1024] x [1024,3072]
  gemm_kernel<__bf16, false, true><<<dim3(64, 24), blk, 0, stream>>>(
      h_in, 2048, wT_qkv, bqkv_p, qkv, 3072, nullptr, 8192, 3072, 1024);

  rope_scatter<<<dim3(32, 64), blk, 0, stream>>>(qkv, enc, qb, kb, vtb);
  attn_kernel<<<dim3(32, 64), blk, 0, stream>>>(qb, kb, vtb, h_in);

  // FFN0 (with fused out-proj): [8192,2048] x [2048,2048]
  gemm_kernel<__bf16, false, true><<<dim3(64, 16), blk, 0, stream>>>(
      h_in, 2048, wT_ffn0, bffn0_f, ffn0o, 2048, nullptr, 8192, 2048, 2048);

  ln_gelu<<<8192, blk, 0, stream>>>(ffn0o, lns, lnb, h2);

  // FFN3 + bias + residual -> out (fp32)
  gemm_kernel<float, true, true><<<dim3(64, 8), blk, 0, stream>>>(
      h2, 2048, wT_ffn3, bffn3, out, 1024, x, 8192, 1024, 2048);
}

// Round 6
// 405.088 us; speedup vs baseline: 1.1531x; 1.0299x over previous
//
#include <hip/hip_runtime.h>
#include <hip/hip_bf16.h>
#include <math.h>

typedef __bf16 bf16x8 __attribute__((ext_vector_type(8)));
typedef float f32x4 __attribute__((ext_vector_type(4)));

#define MFMA16(a, b, c) __builtin_amdgcn_mfma_f32_16x16x32_bf16((a), (b), (c), 0, 0, 0)

__device__ __forceinline__ void gload16(const void* g, void* l) {
  __builtin_amdgcn_global_load_lds((const __attribute__((address_space(1))) void*)g,
                                   (__attribute__((address_space(3))) void*)l, 16, 0, 0);
}

#define BARRIER asm volatile("s_barrier" ::: "memory")

// ---------------------------------------------------------------------------
// Weight transpose + fp32 -> bf16:  out[n][k] = in[k][n], separate strides.
// ---------------------------------------------------------------------------
__global__ __launch_bounds__(256) void transpose_bf16(const float* __restrict__ in,
                                                      int ldin,
                                                      __bf16* __restrict__ out,
                                                      int ldo) {
  __shared__ float tile[32][33];
  int n0 = blockIdx.x * 32, k0 = blockIdx.y * 32;
  int tx = threadIdx.x & 31, ty = threadIdx.x >> 5;
#pragma unroll
  for (int r = 0; r < 32; r += 8)
    tile[ty + r][tx] = in[(size_t)(k0 + ty + r) * ldin + n0 + tx];
  __syncthreads();
#pragma unroll
  for (int r = 0; r < 32; r += 8)
    out[(size_t)(n0 + ty + r) * ldo + k0 + tx] = (__bf16)tile[tx][ty + r];
}

// QKV transpose with output-column permutation: orig col n -> n' = which*1024 + h*64 + hd
__global__ __launch_bounds__(256) void transpose_qkv_perm(const float* __restrict__ in,
                                                          __bf16* __restrict__ out) {
  __shared__ float tile[32][33];
  int n0 = blockIdx.x * 32, k0 = blockIdx.y * 32;
  int tx = threadIdx.x & 31, ty = threadIdx.x >> 5;
#pragma unroll
  for (int r = 0; r < 32; r += 8)
    tile[ty + r][tx] = in[(size_t)(k0 + ty + r) * 3072 + n0 + tx];
  __syncthreads();
#pragma unroll
  for (int r = 0; r < 32; r += 8) {
    int n = n0 + ty + r;
    int h = n / 192, rem = n % 192, hd = rem / 3, which = rem % 3;
    int np = which * 1024 + h * 64 + hd;
    out[(size_t)np * 1024 + k0 + tx] = (__bf16)tile[tx][ty + r];
  }
}

__global__ __launch_bounds__(256) void bias_perm(const float* __restrict__ b,
                                                 float* __restrict__ bp) {
  int n = blockIdx.x * 256 + threadIdx.x;
  if (n < 3072) {
    int h = n / 192, rem = n % 192, hd = rem / 3, which = rem % 3;
    bp[which * 1024 + h * 64 + hd] = b[n];
  }
}

// plain fp32 -> bf16 convert (contiguous)
__global__ __launch_bounds__(256) void convert_plain(const float* __restrict__ in,
                                                     __bf16* __restrict__ out) {
  int id = blockIdx.x * 256 + threadIdx.x;
  const float* src = in + (size_t)id * 8;
  __bf16 tmp[8];
#pragma unroll
  for (int e = 0; e < 8; ++e) tmp[e] = (__bf16)src[e];
  *(uint4*)(out + (size_t)id * 8) = *(uint4*)tmp;
}

// x (fp32 [8192][1024]) -> left half of h_in (bf16 [8192][2048])
__global__ __launch_bounds__(256) void convert_x(const float* __restrict__ x,
                                                 __bf16* __restrict__ h) {
  int id = blockIdx.x * 256 + threadIdx.x;
  int row = id >> 7, cc = id & 127;
  const float* src = x + (size_t)row * 1024 + cc * 8;
  __bf16 tmp[8];
#pragma unroll
  for (int e = 0; e < 8; ++e) tmp[e] = (__bf16)src[e];
  *(uint4*)(h + (size_t)row * 2048 + cc * 8) = *(uint4*)tmp;
}

// b'[n] = bffn0[n] + sum_e bout[e] * W0[1024+e][n]  -- deterministic 2-stage
__global__ __launch_bounds__(256) void fuse_bias_part(const float* __restrict__ bout,
                                                      const float* __restrict__ w0,
                                                      float* __restrict__ part) {
  int n = blockIdx.x * 256 + threadIdx.x;  // grid (8,16)
  int e0 = blockIdx.y * 64;
  float s = 0.f;
#pragma unroll 4
  for (int e = 0; e < 64; ++e)
    s += bout[e0 + e] * w0[(size_t)(1024 + e0 + e) * 2048 + n];
  part[(size_t)blockIdx.y * 2048 + n] = s;
}

__global__ __launch_bounds__(256) void fuse_bias_red(const float* __restrict__ part,
                                                     const float* __restrict__ b0,
                                                     float* __restrict__ bf) {
  int n = blockIdx.x * 256 + threadIdx.x;  // grid 8
  float s = b0[n];
#pragma unroll
  for (int y = 0; y < 16; ++y) s += part[(size_t)y * 2048 + n];
  bf[n] = s;
}

// ---------------------------------------------------------------------------
// 128x128 GEMM (round-2 verified structure) — used for FFN3 and W'' prep.
// ---------------------------------------------------------------------------
template <typename OutT, bool HAS_RES, bool HAS_BIAS>
__global__ __launch_bounds__(256) void gemm_kernel(
    const __bf16* __restrict__ A, int lda,
    const __bf16* __restrict__ Bt,            // N x K row-major
    const float* __restrict__ bias,
    OutT* __restrict__ C, int ldc,
    const float* __restrict__ res,
    int M, int Nn, int K) {
  __shared__ __attribute__((aligned(16))) __bf16 As[128 * 64];
  __shared__ __attribute__((aligned(16))) __bf16 Bs[128 * 64];

  const int t = threadIdx.x;
  const int row0A = blockIdx.x * 128;
  const int row0B = blockIdx.y * 128;
  const int wave = t >> 6, lane = t & 63;
  const int wm = wave >> 1, wn = wave & 1;
  const int g = lane >> 4, lr = lane & 15;

  f32x4 acc[4][4] = {};

  for (int k0 = 0; k0 < K; k0 += 64) {
#pragma unroll
    for (int p = 0; p < 4; ++p) {
      int cbase = (wave * 4 + p) * 64;
      int ci = cbase + lane;
      int r = ci >> 3, cp = ci & 7, cl = cp ^ (r & 7);
      gload16(A + (size_t)(row0A + r) * lda + k0 + cl * 8, &As[cbase * 8]);
      gload16(Bt + (size_t)(row0B + r) * K + k0 + cl * 8, &Bs[cbase * 8]);
    }
    __syncthreads();
#pragma unroll
    for (int kk = 0; kk < 2; ++kk) {
      bf16x8 af[4], bfr[4];
#pragma unroll
      for (int mt = 0; mt < 4; ++mt) {
        int r = wm * 64 + mt * 16 + lr, c = kk * 4 + g;
        af[mt] = *(const bf16x8*)((char*)As + r * 128 + ((c ^ (r & 7)) * 16));
      }
#pragma unroll
      for (int nt = 0; nt < 4; ++nt) {
        int r = wn * 64 + nt * 16 + lr, c = kk * 4 + g;
        bfr[nt] = *(const bf16x8*)((char*)Bs + r * 128 + ((c ^ (r & 7)) * 16));
      }
#pragma unroll
      for (int mt = 0; mt < 4; ++mt)
#pragma unroll
        for (int nt = 0; nt < 4; ++nt)
          acc[mt][nt] = MFMA16(af[mt], bfr[nt], acc[mt][nt]);
    }
    __syncthreads();
  }

  float bias_v[4];
#pragma unroll
  for (int nt = 0; nt < 4; ++nt)
    bias_v[nt] = HAS_BIAS ? bias[row0B + wn * 64 + nt * 16 + lr] : 0.f;
#pragma unroll
  for (int mt = 0; mt < 4; ++mt) {
    int grow_base = row0A + wm * 64 + mt * 16 + g * 4;
#pragma unroll
    for (int nt = 0; nt < 4; ++nt) {
      int gcol = row0B + wn * 64 + nt * 16 + lr;
#pragma unroll
      for (int j = 0; j < 4; ++j) {
        int grow = grow_base + j;
        float v = acc[mt][nt][j] + bias_v[nt];
        if (HAS_RES) v += res[(size_t)grow * ldc + gcol];
        C[(size_t)grow * ldc + gcol] = (OutT)v;
      }
    }
  }
}

// ---------------------------------------------------------------------------
// 256x256 4-phase counted-vmcnt GEMM (T3+T4+T5). BK=64, full K-tile double
// buffer (128 KiB LDS), 512 threads (8 waves 2m x 4n), per-wave 128x64 out.
// Per K-tile t: p1{read aL,bL; stage A(t+1)hi}, p2{read bH; stage B(t+1)lo},
// p3{read aH; stage B(t+1)hi}, p4{reg-only MFMA; stage A(t+2)lo; vmcnt(2)}.
// vmcnt(2) at each tile end retires exactly tile t+1's 8 loads while keeping
// A(t+2)'s 2 in flight (never drains to 0 mid-loop).
// ---------------------------------------------------------------------------
template <typename OutT>
__global__ __launch_bounds__(512, 2) void gemm256p(
    const __bf16* __restrict__ A, int lda,
    const __bf16* __restrict__ Bt, int ldb,
    const float* __restrict__ bias,
    OutT* __restrict__ C, int ldc, int K) {
  __shared__ __attribute__((aligned(16))) __bf16 As[2][256 * 64];
  __shared__ __attribute__((aligned(16))) __bf16 Bs[2][256 * 64];

  const int t = threadIdx.x;
  const int wave = t >> 6, lane = t & 63;
  const int wm = wave >> 2, wn = wave & 3;
  const int g = lane >> 4, lr = lane & 15;
  const int row0A = blockIdx.x * 256, row0B = blockIdx.y * 256;
  const int L = K >> 6;

  f32x4 acc[8][4] = {};

#define STG_A(tile, i)                                                        \
  {                                                                           \
    int cb = ((i) * 8 + wave) * 64;                                           \
    int ci = cb + lane;                                                       \
    int r = ci >> 3, cl = (ci & 7) ^ (r & 7);                                 \
    gload16(A + (size_t)(row0A + r) * lda + (size_t)(tile) * 64 + cl * 8,     \
            &As[(tile) & 1][cb * 8]);                                         \
  }
#define STG_B(tile, i)                                                        \
  {                                                                           \
    int cb = ((i) * 8 + wave) * 64;                                           \
    int ci = cb + lane;                                                       \
    int r = ci >> 3, cl = (ci & 7) ^ (r & 7);                                 \
    gload16(Bt + (size_t)(row0B + r) * ldb + (size_t)(tile) * 64 + cl * 8,    \
            &Bs[(tile) & 1][cb * 8]);                                         \
  }
#define AFRAG(d, mi, ks)                                                      \
  (*(const bf16x8*)((const char*)As[d] + (wm * 128 + (mi) * 16 + lr) * 128 +  \
                    ((((ks) * 4 + g) ^ (lr & 7)) * 16)))
#define BFRAG(d, ni, ks)                                                      \
  (*(const bf16x8*)((const char*)Bs[d] + (wn * 64 + (ni) * 16 + lr) * 128 +   \
                    ((((ks) * 4 + g) ^ (lr & 7)) * 16)))

  // prologue: tile 0 fully + tile 1 low-half of A; retire tile 0 (keep 2)
#pragma unroll
  for (int i = 0; i < 4; ++i) STG_A(0, i);
#pragma unroll
  for (int i = 0; i < 4; ++i) STG_B(0, i);
  STG_A(1, 0);
  STG_A(1, 1);
  asm volatile("s_waitcnt vmcnt(2)" ::: "memory");
  BARRIER;

  for (int tt = 0; tt < L; ++tt) {
    const int d = tt & 1;
    const bool s1 = (tt + 1) < L, s2 = (tt + 2) < L;
    bf16x8 aL[4][2], aH[4][2], bL[2][2], bH[2][2];

    // ---- phase 1: quadrant (mLow, nLow) ----
#pragma unroll
    for (int mi = 0; mi < 4; ++mi) {
      aL[mi][0] = AFRAG(d, mi, 0);
      aL[mi][1] = AFRAG(d, mi, 1);
    }
#pragma unroll
    for (int ni = 0; ni < 2; ++ni) {
      bL[ni][0] = BFRAG(d, ni, 0);
      bL[ni][1] = BFRAG(d, ni, 1);
    }
    if (s1) { STG_A(tt + 1, 2); STG_A(tt + 1, 3); }
    BARRIER;
    __builtin_amdgcn_s_setprio(1);
#pragma unroll
    for (int mi = 0; mi < 4; ++mi)
#pragma unroll
      for (int ni = 0; ni < 2; ++ni) {
        acc[mi][ni] = MFMA16(aL[mi][0], bL[ni][0], acc[mi][ni]);
        acc[mi][ni] = MFMA16(aL[mi][1], bL[ni][1], acc[mi][ni]);
      }
    __builtin_amdgcn_s_setprio(0);
    BARRIER;

    // ---- phase 2: quadrant (mLow, nHigh) ----
#pragma unroll
    for (int ni = 0; ni < 2; ++ni) {
      bH[ni][0] = BFRAG(d, ni + 2, 0);
      bH[ni][1] = BFRAG(d, ni + 2, 1);
    }
    if (s1) { STG_B(tt + 1, 0); STG_B(tt + 1, 1); }
    BARRIER;
    __builtin_amdgcn_s_setprio(1);
#pragma unroll
    for (int mi = 0; mi < 4; ++mi)
#pragma unroll
      for (int ni = 0; ni < 2; ++ni) {
        acc[mi][ni + 2] = MFMA16(aL[mi][0], bH[ni][0], acc[mi][ni + 2]);
        acc[mi][ni + 2] = MFMA16(aL[mi][1], bH[ni][1], acc[mi][ni + 2]);
      }
    __builtin_amdgcn_s_setprio(0);
    BARRIER;

    // ---- phase 3: quadrant (mHigh, nHigh) ----
#pragma unroll
    for (int mi = 0; mi < 4; ++mi) {
      aH[mi][0] = AFRAG(d, mi + 4, 0);
      aH[mi][1] = AFRAG(d, mi + 4, 1);
    }
    if (s1) { STG_B(tt + 1, 2); STG_B(tt + 1, 3); }
    BARRIER;
    __builtin_amdgcn_s_setprio(1);
#pragma unroll
    for (int mi = 0; mi < 4; ++mi)
#pragma unroll
      for (int ni = 0; ni < 2; ++ni) {
        acc[mi + 4][ni + 2] = MFMA16(aH[mi][0], bH[ni][0], acc[mi + 4][ni + 2]);
        acc[mi + 4][ni + 2] = MFMA16(aH[mi][1], bH[ni][1], acc[mi + 4][ni + 2]);
      }
    __builtin_amdgcn_s_setprio(0);
    BARRIER;

    // ---- phase 4: quadrant (mHigh, nLow) — register-only MFMA ----
    if (s2) { STG_A(tt + 2, 0); STG_A(tt + 2, 1); }
    __builtin_amdgcn_s_setprio(1);
#pragma unroll
    for (int mi = 0; mi < 4; ++mi)
#pragma unroll
      for (int ni = 0; ni < 2; ++ni) {
        acc[mi + 4][ni] = MFMA16(aH[mi][0], bL[ni][0], acc[mi + 4][ni]);
        acc[mi + 4][ni] = MFMA16(aH[mi][1], bL[ni][1], acc[mi + 4][ni]);
      }
    __builtin_amdgcn_s_setprio(0);
    if (s2)
      asm volatile("s_waitcnt vmcnt(2)" ::: "memory");
    else
      asm volatile("s_waitcnt vmcnt(0)" ::: "memory");
    BARRIER;
  }
#undef STG_A
#undef STG_B
#undef AFRAG
#undef BFRAG

  float bias_v[4];
#pragma unroll
  for (int ni = 0; ni < 4; ++ni) bias_v[ni] = bias[row0B + wn * 64 + ni * 16 + lr];
#pragma unroll
  for (int mi = 0; mi < 8; ++mi) {
    int grow_base = row0A + wm * 128 + mi * 16 + g * 4;
#pragma unroll
    for (int ni = 0; ni < 4; ++ni) {
      int gcol = row0B + wn * 64 + ni * 16 + lr;
#pragma unroll
      for (int j = 0; j < 4; ++j)
        C[(size_t)(grow_base + j) * ldc + gcol] = (OutT)(acc[mi][ni][j] + bias_v[ni]);
    }
  }
}

// ---------------------------------------------------------------------------
// RoPE + scatter (qkv column-permuted: [Q|K|V] each (token, h*64+hd)).
// q pre-scaled by 0.125*log2(e) so attn uses native exp2. v packed to
// (bh, hd, n) with kv-permutation matching the PV register fragment.
// ---------------------------------------------------------------------------
__global__ __launch_bounds__(256) void rope_scatter(
    const __bf16* __restrict__ qkv, const float* __restrict__ enc,
    __bf16* __restrict__ q, __bf16* __restrict__ kk, __bf16* __restrict__ vt) {
  int bh = blockIdx.y;
  int b = bh >> 4, h = bh & 15;
  int n0 = blockIdx.x * 64;
  int t = threadIdx.x;
  const float QSC = 0.125f * 1.44269504088896f;
#pragma unroll
  for (int i = 0; i < 2; ++i) {
    int id = t + i * 256;
    int nl = id >> 3, cc = id & 7;
    int n = n0 + nl;
    size_t row = (size_t)(b * 2048 + n) * 3072;
    bf16x8 qv = *(const bf16x8*)(qkv + row + h * 64 + cc * 8);
    bf16x8 kv = *(const bf16x8*)(qkv + row + 1024 + h * 64 + cc * 8);
    const float* e0 = enc + (size_t)n * 64 + cc * 8;
    const float* e1 = e0 + 131072;
    __bf16 qo[8], ko[8];
#pragma unroll
    for (int e = 0; e < 8; e += 2) {
      float q0 = (float)qv[e], q1 = (float)qv[e + 1];
      float k0 = (float)kv[e], k1 = (float)kv[e + 1];
      float f00 = e0[e], f01 = e0[e + 1], f10 = e1[e], f11 = e1[e + 1];
      qo[e] = (__bf16)((q0 * f00 - q1 * f10) * QSC);
      qo[e + 1] = (__bf16)((q1 * f01 + q0 * f11) * QSC);
      ko[e] = (__bf16)(k0 * f00 - k1 * f10);
      ko[e + 1] = (__bf16)(k1 * f01 + k0 * f11);
    }
    size_t qb = ((size_t)bh * 2048 + n) * 64 + cc * 8;
    *(uint4*)(q + qb) = *(uint4*)qo;
    *(uint4*)(kk + qb) = *(uint4*)ko;
  }
#pragma unroll
  for (int i = 0; i < 2; ++i) {
    int id = t + i * 256;
    int hd = id >> 3, c = id & 7;
    __bf16 tmp[8];
#pragma unroll
    for (int e = 0; e < 8; ++e) {
      int kv = (c >> 2) * 32 + (e >> 2) * 16 + (c & 3) * 4 + (e & 3);
      int n = n0 + kv;
      tmp[e] = qkv[(size_t)(b * 2048 + n) * 3072 + 2048 + h * 64 + hd];
    }
    *(uint4*)(vt + ((size_t)bh * 64 + hd) * 2048 + n0 + c * 8) = *(uint4*)tmp;
  }
}

// ---------------------------------------------------------------------------
// Flash attention: swapped QK^T (lane-local softmax), native exp2, row-sum
// via all-ones MFMA, P fed to PV from registers. Double-buffered gload_lds
// staging; setprio around MFMA clusters; XCD swizzle (8 heads/XCD -> KV L2-fit).
// ctx written into h_in right half (ld 2048).
// ---------------------------------------------------------------------------
__global__ __launch_bounds__(256) void attn_kernel(
    const __bf16* __restrict__ q, const __bf16* __restrict__ k,
    const __bf16* __restrict__ vt, __bf16* __restrict__ ctx) {
  __shared__ __attribute__((aligned(16))) __bf16 Ks[2][64 * 64];
  __shared__ __attribute__((aligned(16))) __bf16 Vs[2][64 * 64];

  int nwg = gridDim.x * gridDim.y;
  int bid0 = blockIdx.y * gridDim.x + blockIdx.x;
  int bid = (bid0 & 7) * (nwg >> 3) + (bid0 >> 3);
  const int bh = bid / gridDim.x, qblk = bid % gridDim.x;
  const int b = bh >> 4, h = bh & 15;
  const int q0 = qblk * 64;
  const int t = threadIdx.x, wave = t >> 6, lane = t & 63;
  const int g = lane >> 4, lr = lane & 15;
  const int qrow = q0 + wave * 16;

  const __bf16* kbase = k + (size_t)bh * 2048 * 64;
  const __bf16* vbase = vt + (size_t)bh * 64 * 2048;

  bf16x8 qf[2];
#pragma unroll
  for (int kc = 0; kc < 2; ++kc)
    qf[kc] = *(const bf16x8*)(q + ((size_t)bh * 2048 + qrow + lr) * 64 + kc * 32 + g * 8);

  bf16x8 ones;
#pragma unroll
  for (int e = 0; e < 8; ++e) ones[e] = (__bf16)1.0f;

  f32x4 o[4] = {};
  f32x4 lacc = {};  // every element = running row-sum of P for q=lr

#define STAGE_ATTN(buf, kv0)                                                    \
  {                                                                             \
    _Pragma("unroll") for (int p = 0; p < 2; ++p) {                             \
      int cbase = wave * 128 + p * 64;                                          \
      int ci = cbase + lane;                                                    \
      int r = ci >> 3, cp = ci & 7, cl = cp ^ (r & 7);                          \
      gload16(kbase + (size_t)((kv0) + r) * 64 + cl * 8, &Ks[buf][cbase * 8]);  \
      gload16(vbase + (size_t)r * 2048 + (kv0) + cl * 8, &Vs[buf][cbase * 8]);  \
    }                                                                           \
  }

  STAGE_ATTN(0, 0);
  __syncthreads();
  int buf = 0;

  for (int kv0 = 0; kv0 < 2048; kv0 += 64) {
    if (kv0 + 64 < 2048) STAGE_ATTN(buf ^ 1, kv0 + 64);

    f32x4 s[4];
    __builtin_amdgcn_s_setprio(1);
#pragma unroll
    for (int nt = 0; nt < 4; ++nt) {
      int r = nt * 16 + lr;
      bf16x8 kf0 = *(const bf16x8*)((char*)Ks[buf] + r * 128 + ((g ^ (r & 7)) * 16));
      bf16x8 kf1 = *(const bf16x8*)((char*)Ks[buf] + r * 128 + (((4 + g) ^ (r & 7)) * 16));
      f32x4 a = {};
      a = MFMA16(kf0, qf[0], a);
      a = MFMA16(kf1, qf[1], a);
      s[nt] = a;
    }
    __builtin_amdgcn_s_setprio(0);

#pragma unroll
    for (int t2 = 0; t2 < 2; ++t2) {
      bf16x8 pf;
#pragma unroll
      for (int e = 0; e < 8; ++e)
        pf[e] = (__bf16)__builtin_amdgcn_exp2f(s[2 * t2 + (e >> 2)][e & 3]);
      lacc = MFMA16(ones, pf, lacc);
      __builtin_amdgcn_s_setprio(1);
#pragma unroll
      for (int nt = 0; nt < 4; ++nt) {
        int r = nt * 16 + lr;
        bf16x8 vf = *(const bf16x8*)((char*)Vs[buf] + r * 128 + (((t2 * 4 + g) ^ (r & 7)) * 16));
        o[nt] = MFMA16(vf, pf, o[nt]);
      }
      __builtin_amdgcn_s_setprio(0);
    }
    __syncthreads();
    buf ^= 1;
  }

  float inv = 1.f / lacc[0];

  size_t obase = ((size_t)(b * 2048 + qrow + lr)) * 2048 + 1024 + h * 64;
#pragma unroll
  for (int nt = 0; nt < 4; ++nt) {
    __bf16 w4[4];
#pragma unroll
    for (int j = 0; j < 4; ++j) w4[j] = (__bf16)(o[nt][j] * inv);
    *(uint2*)(ctx + obase + nt * 16 + g * 4) = *(uint2*)w4;
  }
#undef STAGE_ATTN
}

// ---------------------------------------------------------------------------
// LayerNorm + exact GELU over rows of 2048
// ---------------------------------------------------------------------------
__global__ __launch_bounds__(256) void ln_gelu(const __bf16* __restrict__ hin,
                                               const float* __restrict__ lns,
                                               const float* __restrict__ lnb,
                                               __bf16* __restrict__ hout) {
  int row = blockIdx.x;
  const __bf16* rp = hin + (size_t)row * 2048;
  int t = threadIdx.x;
  __bf16 tmp[8];
  *(uint4*)tmp = *(const uint4*)(rp + t * 8);
  float vals[8], s = 0.f, s2 = 0.f;
#pragma unroll
  for (int e = 0; e < 8; ++e) {
    float x = (float)tmp[e];
    vals[e] = x;
    s += x;
    s2 += x * x;
  }
#pragma unroll
  for (int m = 1; m < 64; m <<= 1) {
    s += __shfl_xor(s, m, 64);
    s2 += __shfl_xor(s2, m, 64);
  }
  __shared__ float red[8];
  int wave = t >> 6, lane = t & 63;
  if (lane == 0) { red[wave] = s; red[4 + wave] = s2; }
  __syncthreads();
  s = red[0] + red[1] + red[2] + red[3];
  s2 = red[4] + red[5] + red[6] + red[7];
  float mu = s * (1.f / 2048.f);
  float var = s2 * (1.f / 2048.f) - mu * mu;
  float rstd = rsqrtf(var + 1e-5f);
  __bf16 outv[8];
#pragma unroll
  for (int e = 0; e < 8; ++e) {
    int c = t * 8 + e;
    float xh = (vals[e] - mu) * rstd * lns[c] + lnb[c];
    float gg = 0.5f * xh * (1.f + erff(xh * 0.70710678118f));
    outv[e] = (__bf16)gg;
  }
  *(uint4*)(hout + (size_t)row * 2048 + t * 8) = *(uint4*)outv;
}

// ---------------------------------------------------------------------------
// Launch
// ---------------------------------------------------------------------------
extern "C" void kernel_launch(void* const* d_in, const int* in_sizes, int n_in,
                              void* d_out, int out_size, void* d_ws, size_t ws_size,
                              hipStream_t stream) {
  const float* x = (const float*)d_in[0];
  const float* enc = (const float*)d_in[1];
  const float* wqkv = (const float*)d_in[2];
  const float* bqkv = (const float*)d_in[3];
  const float* wout = (const float*)d_in[4];
  const float* bout = (const float*)d_in[5];
  const float* wffn0 = (const float*)d_in[6];
  const float* bffn0 = (const float*)d_in[7];
  const float* lns = (const float*)d_in[8];
  const float* lnb = (const float*)d_in[9];
  const float* wffn3 = (const float*)d_in[10];
  const float* bffn3 = (const float*)d_in[11];
  float* out = (float*)d_out;
  char* ws = (char*)d_ws;

  __bf16* wT_qkv = (__bf16*)(ws + 0);              //  6291456
  __bf16* wT_ffn0 = (__bf16*)(ws + 6291456);       //  8388608
  __bf16* wT_ffn3 = (__bf16*)(ws + 14680064);      //  4194304
  __bf16* wout_bf = (__bf16*)(ws + 18874368);      //  2097152
  __bf16* w0bT = (__bf16*)(ws + 20971520);         //  4194304
  float* bias_part = (float*)(ws + 20971520);      //   131072 (after W'' gemm)
  float* bqkv_p = (float*)(ws + 25165824);         //    12288
  float* bffn0_f = (float*)(ws + 25178112);        //     8192
  __bf16* h_in = (__bf16*)(ws + 25186304);         // 33554432  [x | ctx]
  __bf16* qkv = (__bf16*)(ws + 58740736);          // 50331648
  __bf16* ffn0o = qkv;                             // alias (qkv dead after rope)
  __bf16* qb = (__bf16*)(ws + 109072384);          // 16777216
  __bf16* h2 = qb;                                 // alias (q dead after attn)
  __bf16* kb = (__bf16*)(ws + 125849600);          // 16777216
  __bf16* vtb = (__bf16*)(ws + 142626816);         // 16777216

  dim3 blk(256);
  // weight prep
  transpose_qkv_perm<<<dim3(96, 32), blk, 0, stream>>>(wqkv, wT_qkv);
  bias_perm<<<12, blk, 0, stream>>>(bqkv, bqkv_p);
  transpose_bf16<<<dim3(64, 32), blk, 0, stream>>>(wffn0, 2048, wT_ffn0, 2048);
  transpose_bf16<<<dim3(64, 32), blk, 0, stream>>>(wffn0 + (size_t)1024 * 2048, 2048,
                                                   w0bT, 1024);
  transpose_bf16<<<dim3(32, 64), blk, 0, stream>>>(wffn3, 1024, wT_ffn3, 2048);
  convert_plain<<<512, blk, 0, stream>>>(wout, wout_bf);
  gemm_kernel<__bf16, false, false><<<dim3(16, 8), blk, 0, stream>>>(
      w0bT, 1024, wout_bf, nullptr, wT_ffn0 + 1024, 2048, nullptr, 2048, 1024, 1024);
  fuse_bias_part<<<dim3(8, 16), blk, 0, stream>>>(bout, wffn0, bias_part);
  fuse_bias_red<<<8, blk, 0, stream>>>(bias_part, bffn0, bffn0_f);
  convert_x<<<4096, blk, 0, stream>>>(x, h_in);

  // QKV projection (4-phase 256^2): [8192,1024] x [1024,3072]
  gemm256p<__bf16><<<dim3(32, 12), dim3(512), 0, stream>>>(
      h_in, 2048, wT_qkv, 1024, bqkv_p, qkv, 3072, 1024);

  rope_scatter<<<dim3(32, 64), blk, 0, stream>>>(qkv, enc, qb, kb, vtb);
  attn_kernel<<<dim3(32, 64), blk, 0, stream>>>(qb, kb, vtb, h_in);

  // FFN0 (with fused out-proj, 4-phase 256^2): [8192,2048] x [2048,2048]
  gemm256p<__bf16><<<dim3(32, 8), dim3(512), 0, stream>>>(
      h_in, 2048, wT_ffn0, 2048, bffn0_f, ffn0o, 2048, 2048);

  ln_gelu<<<8192, blk, 0, stream>>>(ffn0o, lns, lnb, h2);

  // FFN3 + bias + residual -> out (fp32)
  gemm_kernel<float, true, true><<<dim3(64, 8), blk, 0, stream>>>(
      h2, 2048, wT_ffn3, bffn3, out, 1024, x, 8192, 1024, 2048);
}

// Round 7
// 393.745 us; speedup vs baseline: 1.1863x; 1.0288x over previous
//
#include <hip/hip_runtime.h>
#include <hip/hip_bf16.h>
#include <math.h>

typedef __bf16 bf16x8 __attribute__((ext_vector_type(8)));
typedef float f32x4 __attribute__((ext_vector_type(4)));

#define MFMA16(a, b, c) __builtin_amdgcn_mfma_f32_16x16x32_bf16((a), (b), (c), 0, 0, 0)

__device__ __forceinline__ void gload16(const void* g, void* l) {
  __builtin_amdgcn_global_load_lds((const __attribute__((address_space(1))) void*)g,
                                   (__attribute__((address_space(3))) void*)l, 16, 0, 0);
}

#define BARRIER asm volatile("s_barrier" ::: "memory")

// ---------------------------------------------------------------------------
// Weight transpose + fp32 -> bf16:  out[n][k] = in[k][n], separate strides.
// ---------------------------------------------------------------------------
__global__ __launch_bounds__(256) void transpose_bf16(const float* __restrict__ in,
                                                      int ldin,
                                                      __bf16* __restrict__ out,
                                                      int ldo) {
  __shared__ float tile[32][33];
  int n0 = blockIdx.x * 32, k0 = blockIdx.y * 32;
  int tx = threadIdx.x & 31, ty = threadIdx.x >> 5;
#pragma unroll
  for (int r = 0; r < 32; r += 8)
    tile[ty + r][tx] = in[(size_t)(k0 + ty + r) * ldin + n0 + tx];
  __syncthreads();
#pragma unroll
  for (int r = 0; r < 32; r += 8)
    out[(size_t)(n0 + ty + r) * ldo + k0 + tx] = (__bf16)tile[tx][ty + r];
}

// QKV transpose with output-column permutation: orig col n -> n' = which*1024 + h*64 + hd
__global__ __launch_bounds__(256) void transpose_qkv_perm(const float* __restrict__ in,
                                                          __bf16* __restrict__ out) {
  __shared__ float tile[32][33];
  int n0 = blockIdx.x * 32, k0 = blockIdx.y * 32;
  int tx = threadIdx.x & 31, ty = threadIdx.x >> 5;
#pragma unroll
  for (int r = 0; r < 32; r += 8)
    tile[ty + r][tx] = in[(size_t)(k0 + ty + r) * 3072 + n0 + tx];
  __syncthreads();
#pragma unroll
  for (int r = 0; r < 32; r += 8) {
    int n = n0 + ty + r;
    int h = n / 192, rem = n % 192, hd = rem / 3, which = rem % 3;
    int np = which * 1024 + h * 64 + hd;
    out[(size_t)np * 1024 + k0 + tx] = (__bf16)tile[tx][ty + r];
  }
}

__global__ __launch_bounds__(256) void bias_perm(const float* __restrict__ b,
                                                 float* __restrict__ bp) {
  int n = blockIdx.x * 256 + threadIdx.x;
  if (n < 3072) {
    int h = n / 192, rem = n % 192, hd = rem / 3, which = rem % 3;
    bp[which * 1024 + h * 64 + hd] = b[n];
  }
}

// plain fp32 -> bf16 convert (contiguous)
__global__ __launch_bounds__(256) void convert_plain(const float* __restrict__ in,
                                                     __bf16* __restrict__ out) {
  int id = blockIdx.x * 256 + threadIdx.x;
  const float* src = in + (size_t)id * 8;
  __bf16 tmp[8];
#pragma unroll
  for (int e = 0; e < 8; ++e) tmp[e] = (__bf16)src[e];
  *(uint4*)(out + (size_t)id * 8) = *(uint4*)tmp;
}

// x (fp32 [8192][1024]) -> left half of h_in (bf16 [8192][2048])
__global__ __launch_bounds__(256) void convert_x(const float* __restrict__ x,
                                                 __bf16* __restrict__ h) {
  int id = blockIdx.x * 256 + threadIdx.x;
  int row = id >> 7, cc = id & 127;
  const float* src = x + (size_t)row * 1024 + cc * 8;
  __bf16 tmp[8];
#pragma unroll
  for (int e = 0; e < 8; ++e) tmp[e] = (__bf16)src[e];
  *(uint4*)(h + (size_t)row * 2048 + cc * 8) = *(uint4*)tmp;
}

// b'[n] = bffn0[n] + sum_e bout[e] * W0[1024+e][n]  -- deterministic 2-stage
__global__ __launch_bounds__(256) void fuse_bias_part(const float* __restrict__ bout,
                                                      const float* __restrict__ w0,
                                                      float* __restrict__ part) {
  int n = blockIdx.x * 256 + threadIdx.x;  // grid (8,16)
  int e0 = blockIdx.y * 64;
  float s = 0.f;
#pragma unroll 4
  for (int e = 0; e < 64; ++e)
    s += bout[e0 + e] * w0[(size_t)(1024 + e0 + e) * 2048 + n];
  part[(size_t)blockIdx.y * 2048 + n] = s;
}

__global__ __launch_bounds__(256) void fuse_bias_red(const float* __restrict__ part,
                                                     const float* __restrict__ b0,
                                                     float* __restrict__ bf) {
  int n = blockIdx.x * 256 + threadIdx.x;  // grid 8
  float s = b0[n];
#pragma unroll
  for (int y = 0; y < 16; ++y) s += part[(size_t)y * 2048 + n];
  bf[n] = s;
}

// ---------------------------------------------------------------------------
// 128x128 GEMM (round-2 verified structure) — used for FFN3 and W'' prep.
// ---------------------------------------------------------------------------
template <typename OutT, bool HAS_RES, bool HAS_BIAS>
__global__ __launch_bounds__(256) void gemm_kernel(
    const __bf16* __restrict__ A, int lda,
    const __bf16* __restrict__ Bt,            // N x K row-major
    const float* __restrict__ bias,
    OutT* __restrict__ C, int ldc,
    const float* __restrict__ res,
    int M, int Nn, int K) {
  __shared__ __attribute__((aligned(16))) __bf16 As[128 * 64];
  __shared__ __attribute__((aligned(16))) __bf16 Bs[128 * 64];

  const int t = threadIdx.x;
  const int row0A = blockIdx.x * 128;
  const int row0B = blockIdx.y * 128;
  const int wave = t >> 6, lane = t & 63;
  const int wm = wave >> 1, wn = wave & 1;
  const int g = lane >> 4, lr = lane & 15;

  f32x4 acc[4][4] = {};

  for (int k0 = 0; k0 < K; k0 += 64) {
#pragma unroll
    for (int p = 0; p < 4; ++p) {
      int cbase = (wave * 4 + p) * 64;
      int ci = cbase + lane;
      int r = ci >> 3, cp = ci & 7, cl = cp ^ (r & 7);
      gload16(A + (size_t)(row0A + r) * lda + k0 + cl * 8, &As[cbase * 8]);
      gload16(Bt + (size_t)(row0B + r) * K + k0 + cl * 8, &Bs[cbase * 8]);
    }
    __syncthreads();
#pragma unroll
    for (int kk = 0; kk < 2; ++kk) {
      bf16x8 af[4], bfr[4];
#pragma unroll
      for (int mt = 0; mt < 4; ++mt) {
        int r = wm * 64 + mt * 16 + lr, c = kk * 4 + g;
        af[mt] = *(const bf16x8*)((char*)As + r * 128 + ((c ^ (r & 7)) * 16));
      }
#pragma unroll
      for (int nt = 0; nt < 4; ++nt) {
        int r = wn * 64 + nt * 16 + lr, c = kk * 4 + g;
        bfr[nt] = *(const bf16x8*)((char*)Bs + r * 128 + ((c ^ (r & 7)) * 16));
      }
#pragma unroll
      for (int mt = 0; mt < 4; ++mt)
#pragma unroll
        for (int nt = 0; nt < 4; ++nt)
          acc[mt][nt] = MFMA16(af[mt], bfr[nt], acc[mt][nt]);
    }
    __syncthreads();
  }

  float bias_v[4];
#pragma unroll
  for (int nt = 0; nt < 4; ++nt)
    bias_v[nt] = HAS_BIAS ? bias[row0B + wn * 64 + nt * 16 + lr] : 0.f;
#pragma unroll
  for (int mt = 0; mt < 4; ++mt) {
    int grow_base = row0A + wm * 64 + mt * 16 + g * 4;
#pragma unroll
    for (int nt = 0; nt < 4; ++nt) {
      int gcol = row0B + wn * 64 + nt * 16 + lr;
#pragma unroll
      for (int j = 0; j < 4; ++j) {
        int grow = grow_base + j;
        float v = acc[mt][nt][j] + bias_v[nt];
        if (HAS_RES) v += res[(size_t)grow * ldc + gcol];
        C[(size_t)grow * ldc + gcol] = (OutT)v;
      }
    }
  }
}

// ---------------------------------------------------------------------------
// 256x256 4-phase counted-vmcnt GEMM (T3+T4+T5) — verified in round 6.
// ---------------------------------------------------------------------------
template <typename OutT>
__global__ __launch_bounds__(512, 2) void gemm256p(
    const __bf16* __restrict__ A, int lda,
    const __bf16* __restrict__ Bt, int ldb,
    const float* __restrict__ bias,
    OutT* __restrict__ C, int ldc, int K) {
  __shared__ __attribute__((aligned(16))) __bf16 As[2][256 * 64];
  __shared__ __attribute__((aligned(16))) __bf16 Bs[2][256 * 64];

  const int t = threadIdx.x;
  const int wave = t >> 6, lane = t & 63;
  const int wm = wave >> 2, wn = wave & 3;
  const int g = lane >> 4, lr = lane & 15;
  const int row0A = blockIdx.x * 256, row0B = blockIdx.y * 256;
  const int L = K >> 6;

  f32x4 acc[8][4] = {};

#define STG_A(tile, i)                                                        \
  {                                                                           \
    int cb = ((i) * 8 + wave) * 64;                                           \
    int ci = cb + lane;                                                       \
    int r = ci >> 3, cl = (ci & 7) ^ (r & 7);                                 \
    gload16(A + (size_t)(row0A + r) * lda + (size_t)(tile) * 64 + cl * 8,     \
            &As[(tile) & 1][cb * 8]);                                         \
  }
#define STG_B(tile, i)                                                        \
  {                                                                           \
    int cb = ((i) * 8 + wave) * 64;                                           \
    int ci = cb + lane;                                                       \
    int r = ci >> 3, cl = (ci & 7) ^ (r & 7);                                 \
    gload16(Bt + (size_t)(row0B + r) * ldb + (size_t)(tile) * 64 + cl * 8,    \
            &Bs[(tile) & 1][cb * 8]);                                         \
  }
#define AFRAG(d, mi, ks)                                                      \
  (*(const bf16x8*)((const char*)As[d] + (wm * 128 + (mi) * 16 + lr) * 128 +  \
                    ((((ks) * 4 + g) ^ (lr & 7)) * 16)))
#define BFRAG(d, ni, ks)                                                      \
  (*(const bf16x8*)((const char*)Bs[d] + (wn * 64 + (ni) * 16 + lr) * 128 +   \
                    ((((ks) * 4 + g) ^ (lr & 7)) * 16)))

  // prologue: tile 0 fully + tile 1 low-half of A; retire tile 0 (keep 2)
#pragma unroll
  for (int i = 0; i < 4; ++i) STG_A(0, i);
#pragma unroll
  for (int i = 0; i < 4; ++i) STG_B(0, i);
  STG_A(1, 0);
  STG_A(1, 1);
  asm volatile("s_waitcnt vmcnt(2)" ::: "memory");
  BARRIER;

  for (int tt = 0; tt < L; ++tt) {
    const int d = tt & 1;
    const bool s1 = (tt + 1) < L, s2 = (tt + 2) < L;
    bf16x8 aL[4][2], aH[4][2], bL[2][2], bH[2][2];

    // ---- phase 1: quadrant (mLow, nLow) ----
#pragma unroll
    for (int mi = 0; mi < 4; ++mi) {
      aL[mi][0] = AFRAG(d, mi, 0);
      aL[mi][1] = AFRAG(d, mi, 1);
    }
#pragma unroll
    for (int ni = 0; ni < 2; ++ni) {
      bL[ni][0] = BFRAG(d, ni, 0);
      bL[ni][1] = BFRAG(d, ni, 1);
    }
    if (s1) { STG_A(tt + 1, 2); STG_A(tt + 1, 3); }
    BARRIER;
    __builtin_amdgcn_s_setprio(1);
#pragma unroll
    for (int mi = 0; mi < 4; ++mi)
#pragma unroll
      for (int ni = 0; ni < 2; ++ni) {
        acc[mi][ni] = MFMA16(aL[mi][0], bL[ni][0], acc[mi][ni]);
        acc[mi][ni] = MFMA16(aL[mi][1], bL[ni][1], acc[mi][ni]);
      }
    __builtin_amdgcn_s_setprio(0);
    BARRIER;

    // ---- phase 2: quadrant (mLow, nHigh) ----
#pragma unroll
    for (int ni = 0; ni < 2; ++ni) {
      bH[ni][0] = BFRAG(d, ni + 2, 0);
      bH[ni][1] = BFRAG(d, ni + 2, 1);
    }
    if (s1) { STG_B(tt + 1, 0); STG_B(tt + 1, 1); }
    BARRIER;
    __builtin_amdgcn_s_setprio(1);
#pragma unroll
    for (int mi = 0; mi < 4; ++mi)
#pragma unroll
      for (int ni = 0; ni < 2; ++ni) {
        acc[mi][ni + 2] = MFMA16(aL[mi][0], bH[ni][0], acc[mi][ni + 2]);
        acc[mi][ni + 2] = MFMA16(aL[mi][1], bH[ni][1], acc[mi][ni + 2]);
      }
    __builtin_amdgcn_s_setprio(0);
    BARRIER;

    // ---- phase 3: quadrant (mHigh, nHigh) ----
#pragma unroll
    for (int mi = 0; mi < 4; ++mi) {
      aH[mi][0] = AFRAG(d, mi + 4, 0);
      aH[mi][1] = AFRAG(d, mi + 4, 1);
    }
    if (s1) { STG_B(tt + 1, 2); STG_B(tt + 1, 3); }
    BARRIER;
    __builtin_amdgcn_s_setprio(1);
#pragma unroll
    for (int mi = 0; mi < 4; ++mi)
#pragma unroll
      for (int ni = 0; ni < 2; ++ni) {
        acc[mi + 4][ni + 2] = MFMA16(aH[mi][0], bH[ni][0], acc[mi + 4][ni + 2]);
        acc[mi + 4][ni + 2] = MFMA16(aH[mi][1], bH[ni][1], acc[mi + 4][ni + 2]);
      }
    __builtin_amdgcn_s_setprio(0);
    BARRIER;

    // ---- phase 4: quadrant (mHigh, nLow) — register-only MFMA ----
    if (s2) { STG_A(tt + 2, 0); STG_A(tt + 2, 1); }
    __builtin_amdgcn_s_setprio(1);
#pragma unroll
    for (int mi = 0; mi < 4; ++mi)
#pragma unroll
      for (int ni = 0; ni < 2; ++ni) {
        acc[mi + 4][ni] = MFMA16(aH[mi][0], bL[ni][0], acc[mi + 4][ni]);
        acc[mi + 4][ni] = MFMA16(aH[mi][1], bL[ni][1], acc[mi + 4][ni]);
      }
    __builtin_amdgcn_s_setprio(0);
    if (s2)
      asm volatile("s_waitcnt vmcnt(2)" ::: "memory");
    else
      asm volatile("s_waitcnt vmcnt(0)" ::: "memory");
    BARRIER;
  }
#undef STG_A
#undef STG_B
#undef AFRAG
#undef BFRAG

  float bias_v[4];
#pragma unroll
  for (int ni = 0; ni < 4; ++ni) bias_v[ni] = bias[row0B + wn * 64 + ni * 16 + lr];
#pragma unroll
  for (int mi = 0; mi < 8; ++mi) {
    int grow_base = row0A + wm * 128 + mi * 16 + g * 4;
#pragma unroll
    for (int ni = 0; ni < 4; ++ni) {
      int gcol = row0B + wn * 64 + ni * 16 + lr;
#pragma unroll
      for (int j = 0; j < 4; ++j)
        C[(size_t)(grow_base + j) * ldc + gcol] = (OutT)(acc[mi][ni][j] + bias_v[ni]);
    }
  }
}

// ---------------------------------------------------------------------------
// RoPE + scatter (qkv column-permuted: [Q|K|V] each (token, h*64+hd)).
// q pre-scaled by 0.125*log2(e) so attn uses native exp2. v packed to
// (bh, hd, n) with kv-permutation matching the PV register fragment.
// ---------------------------------------------------------------------------
__global__ __launch_bounds__(256) void rope_scatter(
    const __bf16* __restrict__ qkv, const float* __restrict__ enc,
    __bf16* __restrict__ q, __bf16* __restrict__ kk, __bf16* __restrict__ vt) {
  int bh = blockIdx.y;
  int b = bh >> 4, h = bh & 15;
  int n0 = blockIdx.x * 64;
  int t = threadIdx.x;
  const float QSC = 0.125f * 1.44269504088896f;
#pragma unroll
  for (int i = 0; i < 2; ++i) {
    int id = t + i * 256;
    int nl = id >> 3, cc = id & 7;
    int n = n0 + nl;
    size_t row = (size_t)(b * 2048 + n) * 3072;
    bf16x8 qv = *(const bf16x8*)(qkv + row + h * 64 + cc * 8);
    bf16x8 kv = *(const bf16x8*)(qkv + row + 1024 + h * 64 + cc * 8);
    const float* e0 = enc + (size_t)n * 64 + cc * 8;
    const float* e1 = e0 + 131072;
    __bf16 qo[8], ko[8];
#pragma unroll
    for (int e = 0; e < 8; e += 2) {
      float q0 = (float)qv[e], q1 = (float)qv[e + 1];
      float k0 = (float)kv[e], k1 = (float)kv[e + 1];
      float f00 = e0[e], f01 = e0[e + 1], f10 = e1[e], f11 = e1[e + 1];
      qo[e] = (__bf16)((q0 * f00 - q1 * f10) * QSC);
      qo[e + 1] = (__bf16)((q1 * f01 + q0 * f11) * QSC);
      ko[e] = (__bf16)(k0 * f00 - k1 * f10);
      ko[e + 1] = (__bf16)(k1 * f01 + k0 * f11);
    }
    size_t qb = ((size_t)bh * 2048 + n) * 64 + cc * 8;
    *(uint4*)(q + qb) = *(uint4*)qo;
    *(uint4*)(kk + qb) = *(uint4*)ko;
  }
#pragma unroll
  for (int i = 0; i < 2; ++i) {
    int id = t + i * 256;
    int hd = id >> 3, c = id & 7;
    __bf16 tmp[8];
#pragma unroll
    for (int e = 0; e < 8; ++e) {
      int kv = (c >> 2) * 32 + (e >> 2) * 16 + (c & 3) * 4 + (e & 3);
      int n = n0 + kv;
      tmp[e] = qkv[(size_t)(b * 2048 + n) * 3072 + 2048 + h * 64 + hd];
    }
    *(uint4*)(vt + ((size_t)bh * 64 + hd) * 2048 + n0 + c * 8) = *(uint4*)tmp;
  }
}

// ---------------------------------------------------------------------------
// Flash attention, QBLK=32 per wave (2 q-groups share K/V fragments).
// Swapped QK^T (lane-local softmax), native exp2, row-sum via all-ones MFMA,
// P fed to PV from registers. Double-buffered gload_lds staging; setprio;
// XCD swizzle (8 heads/XCD -> KV L2-fit). Block covers 128 q rows.
// ctx written into h_in right half (ld 2048).
// ---------------------------------------------------------------------------
__global__ __launch_bounds__(256) void attn_kernel(
    const __bf16* __restrict__ q, const __bf16* __restrict__ k,
    const __bf16* __restrict__ vt, __bf16* __restrict__ ctx) {
  __shared__ __attribute__((aligned(16))) __bf16 Ks[2][64 * 64];
  __shared__ __attribute__((aligned(16))) __bf16 Vs[2][64 * 64];

  int nwg = gridDim.x * gridDim.y;  // 1024
  int bid0 = blockIdx.y * gridDim.x + blockIdx.x;
  int bid = (bid0 & 7) * (nwg >> 3) + (bid0 >> 3);
  const int bh = bid >> 4, qblk = bid & 15;
  const int b = bh >> 4, h = bh & 15;
  const int q0 = qblk * 128;
  const int t = threadIdx.x, wave = t >> 6, lane = t & 63;
  const int g = lane >> 4, lr = lane & 15;
  const int qrow0 = q0 + wave * 32;

  const __bf16* kbase = k + (size_t)bh * 2048 * 64;
  const __bf16* vbase = vt + (size_t)bh * 64 * 2048;

  bf16x8 qf[2][2];
#pragma unroll
  for (int u = 0; u < 2; ++u)
#pragma unroll
    for (int kc = 0; kc < 2; ++kc)
      qf[u][kc] = *(const bf16x8*)(q + ((size_t)bh * 2048 + qrow0 + u * 16 + lr) * 64 +
                                   kc * 32 + g * 8);

  bf16x8 ones;
#pragma unroll
  for (int e = 0; e < 8; ++e) ones[e] = (__bf16)1.0f;

  f32x4 o[2][4] = {};
  f32x4 lacc[2] = {};

#define STAGE_ATTN(buf, kv0)                                                    \
  {                                                                             \
    _Pragma("unroll") for (int p = 0; p < 2; ++p) {                             \
      int cbase = wave * 128 + p * 64;                                          \
      int ci = cbase + lane;                                                    \
      int r = ci >> 3, cp = ci & 7, cl = cp ^ (r & 7);                          \
      gload16(kbase + (size_t)((kv0) + r) * 64 + cl * 8, &Ks[buf][cbase * 8]);  \
      gload16(vbase + (size_t)r * 2048 + (kv0) + cl * 8, &Vs[buf][cbase * 8]);  \
    }                                                                           \
  }

  STAGE_ATTN(0, 0);
  __syncthreads();
  int buf = 0;

  for (int kv0 = 0; kv0 < 2048; kv0 += 64) {
    if (kv0 + 64 < 2048) STAGE_ATTN(buf ^ 1, kv0 + 64);

    f32x4 s[2][4];
    __builtin_amdgcn_s_setprio(1);
#pragma unroll
    for (int nt = 0; nt < 4; ++nt) {
      int r = nt * 16 + lr;
      bf16x8 kf0 = *(const bf16x8*)((char*)Ks[buf] + r * 128 + ((g ^ (r & 7)) * 16));
      bf16x8 kf1 = *(const bf16x8*)((char*)Ks[buf] + r * 128 + (((4 + g) ^ (r & 7)) * 16));
#pragma unroll
      for (int u = 0; u < 2; ++u) {
        f32x4 a = {};
        a = MFMA16(kf0, qf[u][0], a);
        a = MFMA16(kf1, qf[u][1], a);
        s[u][nt] = a;
      }
    }
    __builtin_amdgcn_s_setprio(0);

#pragma unroll
    for (int t2 = 0; t2 < 2; ++t2) {
      bf16x8 pf[2];
#pragma unroll
      for (int u = 0; u < 2; ++u) {
#pragma unroll
        for (int e = 0; e < 8; ++e)
          pf[u][e] = (__bf16)__builtin_amdgcn_exp2f(s[u][2 * t2 + (e >> 2)][e & 3]);
        lacc[u] = MFMA16(ones, pf[u], lacc[u]);
      }
      __builtin_amdgcn_s_setprio(1);
#pragma unroll
      for (int nt = 0; nt < 4; ++nt) {
        int r = nt * 16 + lr;
        bf16x8 vf = *(const bf16x8*)((char*)Vs[buf] + r * 128 + (((t2 * 4 + g) ^ (r & 7)) * 16));
#pragma unroll
        for (int u = 0; u < 2; ++u) o[u][nt] = MFMA16(vf, pf[u], o[u][nt]);
      }
      __builtin_amdgcn_s_setprio(0);
    }
    __syncthreads();
    buf ^= 1;
  }

#pragma unroll
  for (int u = 0; u < 2; ++u) {
    float inv = 1.f / lacc[u][0];
    size_t obase = ((size_t)(b * 2048 + qrow0 + u * 16 + lr)) * 2048 + 1024 + h * 64;
#pragma unroll
    for (int nt = 0; nt < 4; ++nt) {
      __bf16 w4[4];
#pragma unroll
      for (int j = 0; j < 4; ++j) w4[j] = (__bf16)(o[u][nt][j] * inv);
      *(uint2*)(ctx + obase + nt * 16 + g * 4) = *(uint2*)w4;
    }
  }
#undef STAGE_ATTN
}

// ---------------------------------------------------------------------------
// LayerNorm + exact GELU over rows of 2048
// ---------------------------------------------------------------------------
__global__ __launch_bounds__(256) void ln_gelu(const __bf16* __restrict__ hin,
                                               const float* __restrict__ lns,
                                               const float* __restrict__ lnb,
                                               __bf16* __restrict__ hout) {
  int row = blockIdx.x;
  const __bf16* rp = hin + (size_t)row * 2048;
  int t = threadIdx.x;
  __bf16 tmp[8];
  *(uint4*)tmp = *(const uint4*)(rp + t * 8);
  float vals[8], s = 0.f, s2 = 0.f;
#pragma unroll
  for (int e = 0; e < 8; ++e) {
    float x = (float)tmp[e];
    vals[e] = x;
    s += x;
    s2 += x * x;
  }
#pragma unroll
  for (int m = 1; m < 64; m <<= 1) {
    s += __shfl_xor(s, m, 64);
    s2 += __shfl_xor(s2, m, 64);
  }
  __shared__ float red[8];
  int wave = t >> 6, lane = t & 63;
  if (lane == 0) { red[wave] = s; red[4 + wave] = s2; }
  __syncthreads();
  s = red[0] + red[1] + red[2] + red[3];
  s2 = red[4] + red[5] + red[6] + red[7];
  float mu = s * (1.f / 2048.f);
  float var = s2 * (1.f / 2048.f) - mu * mu;
  float rstd = rsqrtf(var + 1e-5f);
  __bf16 outv[8];
#pragma unroll
  for (int e = 0; e < 8; ++e) {
    int c = t * 8 + e;
    float xh = (vals[e] - mu) * rstd * lns[c] + lnb[c];
    float gg = 0.5f * xh * (1.f + erff(xh * 0.70710678118f));
    outv[e] = (__bf16)gg;
  }
  *(uint4*)(hout + (size_t)row * 2048 + t * 8) = *(uint4*)outv;
}

// ---------------------------------------------------------------------------
// Launch
// ---------------------------------------------------------------------------
extern "C" void kernel_launch(void* const* d_in, const int* in_sizes, int n_in,
                              void* d_out, int out_size, void* d_ws, size_t ws_size,
                              hipStream_t stream) {
  const float* x = (const float*)d_in[0];
  const float* enc = (const float*)d_in[1];
  const float* wqkv = (const float*)d_in[2];
  const float* bqkv = (const float*)d_in[3];
  const float* wout = (const float*)d_in[4];
  const float* bout = (const float*)d_in[5];
  const float* wffn0 = (const float*)d_in[6];
  const float* bffn0 = (const float*)d_in[7];
  const float* lns = (const float*)d_in[8];
  const float* lnb = (const float*)d_in[9];
  const float* wffn3 = (const float*)d_in[10];
  const float* bffn3 = (const float*)d_in[11];
  float* out = (float*)d_out;
  char* ws = (char*)d_ws;

  __bf16* wT_qkv = (__bf16*)(ws + 0);              //  6291456
  __bf16* wT_ffn0 = (__bf16*)(ws + 6291456);       //  8388608
  __bf16* wT_ffn3 = (__bf16*)(ws + 14680064);      //  4194304
  __bf16* wout_bf = (__bf16*)(ws + 18874368);      //  2097152
  __bf16* w0bT = (__bf16*)(ws + 20971520);         //  4194304
  float* bias_part = (float*)(ws + 20971520);      //   131072 (after W'' gemm)
  float* bqkv_p = (float*)(ws + 25165824);         //    12288
  float* bffn0_f = (float*)(ws + 25178112);        //     8192
  __bf16* h_in = (__bf16*)(ws + 25186304);         // 33554432  [x | ctx]
  __bf16* qkv = (__bf16*)(ws + 58740736);          // 50331648
  __bf16* ffn0o = qkv;                             // alias (qkv dead after rope)
  __bf16* qb = (__bf16*)(ws + 109072384);          // 16777216
  __bf16* h2 = qb;                                 // alias (q dead after attn)
  __bf16* kb = (__bf16*)(ws + 125849600);          // 16777216
  __bf16* vtb = (__bf16*)(ws + 142626816);         // 16777216

  dim3 blk(256);
  // weight prep
  transpose_qkv_perm<<<dim3(96, 32), blk, 0, stream>>>(wqkv, wT_qkv);
  bias_perm<<<12, blk, 0, stream>>>(bqkv, bqkv_p);
  transpose_bf16<<<dim3(64, 32), blk, 0, stream>>>(wffn0, 2048, wT_ffn0, 2048);
  transpose_bf16<<<dim3(64, 32), blk, 0, stream>>>(wffn0 + (size_t)1024 * 2048, 2048,
                                                   w0bT, 1024);
  transpose_bf16<<<dim3(32, 64), blk, 0, stream>>>(wffn3, 1024, wT_ffn3, 2048);
  convert_plain<<<512, blk, 0, stream>>>(wout, wout_bf);
  gemm_kernel<__bf16, false, false><<<dim3(16, 8), blk, 0, stream>>>(
      w0bT, 1024, wout_bf, nullptr, wT_ffn0 + 1024, 2048, nullptr, 2048, 1024, 1024);
  fuse_bias_part<<<dim3(8, 16), blk, 0, stream>>>(bout, wffn0, bias_part);
  fuse_bias_red<<<8, blk, 0, stream>>>(bias_part, bffn0, bffn0_f);
  convert_x<<<4096, blk, 0, stream>>>(x, h_in);

  // QKV projection (4-phase 256^2): [8192,1024] x [1024,3072]
  gemm256p<__bf16><<<dim3(32, 12), dim3(512), 0, stream>>>(
      h_in, 2048, wT_qkv, 1024, bqkv_p, qkv, 3072, 1024);

  rope_scatter<<<dim3(32, 64), blk, 0, stream>>>(qkv, enc, qb, kb, vtb);
  attn_kernel<<<dim3(16, 64), blk, 0, stream>>>(qb, kb, vtb, h_in);

  // FFN0 (with fused out-proj, 4-phase 256^2): [8192,2048] x [2048,2048]
  gemm256p<__bf16><<<dim3(32, 8), dim3(512), 0, stream>>>(
      h_in, 2048, wT_ffn0, 2048, bffn0_f, ffn0o, 2048, 2048);

  ln_gelu<<<8192, blk, 0, stream>>>(ffn0o, lns, lnb, h2);

  // FFN3 + bias + residual -> out (fp32)
  gemm_kernel<float, true, true><<<dim3(64, 8), blk, 0, stream>>>(
      h2, 2048, wT_ffn3, bffn3, out, 1024, x, 8192, 1024, 2048);
}

// Round 8
// 372.452 us; speedup vs baseline: 1.2542x; 1.0572x over previous
//
#include <hip/hip_runtime.h>
#include <hip/hip_bf16.h>
#include <math.h>

typedef __bf16 bf16x8 __attribute__((ext_vector_type(8)));
typedef float f32x4 __attribute__((ext_vector_type(4)));

#define MFMA16(a, b, c) __builtin_amdgcn_mfma_f32_16x16x32_bf16((a), (b), (c), 0, 0, 0)

__device__ __forceinline__ void gload16(const void* g, void* l) {
  __builtin_amdgcn_global_load_lds((const __attribute__((address_space(1))) void*)g,
                                   (__attribute__((address_space(3))) void*)l, 16, 0, 0);
}

#define BARRIER asm volatile("s_barrier" ::: "memory")

// ---------------------------------------------------------------------------
// prep1: ALL independent weight-prep tasks in one launch (blockIdx ranges).
//   [0,3072)      transpose_qkv_perm (96 x, 32 y)
//   [3072,5120)   transpose W0 top  -> wT_ffn0 cols [0:1024)   (64 x, 32 y)
//   [5120,7168)   transpose W0 bot  -> w0bT                    (64 x, 32 y)
//   [7168,9216)   transpose Wffn3   -> wT_ffn3                 (32 x, 64 y)
//   [9216,9728)   convert wout -> bf16
//   [9728,9740)   bias_perm (qkv bias)
//   [9740,9868)   fuse_bias_part (8 x, 16 y)
//   [9868,13964)  convert_x -> h_in left half
// ---------------------------------------------------------------------------
__device__ __forceinline__ void tr_body(float (*tile)[33], const float* __restrict__ in,
                                        int ldin, __bf16* __restrict__ out, int ldo,
                                        int n0, int k0, int t) {
  int tx = t & 31, ty = t >> 5;
#pragma unroll
  for (int r = 0; r < 32; r += 8)
    tile[ty + r][tx] = in[(size_t)(k0 + ty + r) * ldin + n0 + tx];
  __syncthreads();
#pragma unroll
  for (int r = 0; r < 32; r += 8)
    out[(size_t)(n0 + ty + r) * ldo + k0 + tx] = (__bf16)tile[tx][ty + r];
}

__global__ __launch_bounds__(256) void prep1(
    const float* __restrict__ wqkv, __bf16* __restrict__ wT_qkv,
    const float* __restrict__ wffn0, __bf16* __restrict__ wT_ffn0,
    __bf16* __restrict__ w0bT,
    const float* __restrict__ wffn3, __bf16* __restrict__ wT_ffn3,
    const float* __restrict__ wout, __bf16* __restrict__ wout_bf,
    const float* __restrict__ bqkv, float* __restrict__ bqkv_p,
    const float* __restrict__ bout, float* __restrict__ bias_part,
    const float* __restrict__ x, __bf16* __restrict__ h_in) {
  __shared__ float tile[32][33];
  const int bid = blockIdx.x;
  const int t = threadIdx.x;

  if (bid < 3072) {
    // QKV transpose with output-column permutation
    int bx = bid % 96, by = bid / 96;
    int n0 = bx * 32, k0 = by * 32;
    int tx = t & 31, ty = t >> 5;
#pragma unroll
    for (int r = 0; r < 32; r += 8)
      tile[ty + r][tx] = wqkv[(size_t)(k0 + ty + r) * 3072 + n0 + tx];
    __syncthreads();
#pragma unroll
    for (int r = 0; r < 32; r += 8) {
      int n = n0 + ty + r;
      int h = n / 192, rem = n % 192, hd = rem / 3, which = rem % 3;
      int np = which * 1024 + h * 64 + hd;
      wT_qkv[(size_t)np * 1024 + k0 + tx] = (__bf16)tile[tx][ty + r];
    }
  } else if (bid < 5120) {
    int lb = bid - 3072, bx = lb % 64, by = lb / 64;
    tr_body(tile, wffn0, 2048, wT_ffn0, 2048, bx * 32, by * 32, t);
  } else if (bid < 7168) {
    int lb = bid - 5120, bx = lb % 64, by = lb / 64;
    tr_body(tile, wffn0 + (size_t)1024 * 2048, 2048, w0bT, 1024, bx * 32, by * 32, t);
  } else if (bid < 9216) {
    int lb = bid - 7168, bx = lb % 32, by = lb / 32;
    tr_body(tile, wffn3, 1024, wT_ffn3, 2048, bx * 32, by * 32, t);
  } else if (bid < 9728) {
    int id = (bid - 9216) * 256 + t;
    const float* src = wout + (size_t)id * 8;
    __bf16 tmp[8];
#pragma unroll
    for (int e = 0; e < 8; ++e) tmp[e] = (__bf16)src[e];
    *(uint4*)(wout_bf + (size_t)id * 8) = *(uint4*)tmp;
  } else if (bid < 9740) {
    int n = (bid - 9728) * 256 + t;
    if (n < 3072) {
      int h = n / 192, rem = n % 192, hd = rem / 3, which = rem % 3;
      bqkv_p[which * 1024 + h * 64 + hd] = bqkv[n];
    }
  } else if (bid < 9868) {
    int lb = bid - 9740;
    int n = (lb % 8) * 256 + t;
    int e0 = (lb / 8) * 64;
    float s = 0.f;
#pragma unroll 4
    for (int e = 0; e < 64; ++e)
      s += bout[e0 + e] * wffn0[(size_t)(1024 + e0 + e) * 2048 + n];
    bias_part[(size_t)(lb / 8) * 2048 + n] = s;
  } else {
    int id = (bid - 9868) * 256 + t;
    int row = id >> 7, cc = id & 127;
    const float* src = x + (size_t)row * 1024 + cc * 8;
    __bf16 tmp[8];
#pragma unroll
    for (int e = 0; e < 8; ++e) tmp[e] = (__bf16)src[e];
    *(uint4*)(h_in + (size_t)row * 2048 + cc * 8) = *(uint4*)tmp;
  }
}

// ---------------------------------------------------------------------------
// prep2: blocks [0,128): W''T = W0b^T * Wout^T -> wT_ffn0 cols [1024:2048)
//        blocks [128,136): fuse_bias_red
// ---------------------------------------------------------------------------
__global__ __launch_bounds__(256) void prep2(
    const __bf16* __restrict__ w0bT, const __bf16* __restrict__ wout_bf,
    __bf16* __restrict__ wT_ffn0,
    const float* __restrict__ bias_part, const float* __restrict__ bffn0,
    float* __restrict__ bffn0_f) {
  const int bid = blockIdx.x;
  const int t = threadIdx.x;
  if (bid >= 128) {
    int n = (bid - 128) * 256 + t;
    float s = bffn0[n];
#pragma unroll
    for (int y = 0; y < 16; ++y) s += bias_part[(size_t)y * 2048 + n];
    bffn0_f[n] = s;
    return;
  }
  __shared__ __attribute__((aligned(16))) __bf16 As[128 * 64];
  __shared__ __attribute__((aligned(16))) __bf16 Bs[128 * 64];
  const int row0A = (bid % 16) * 128;   // over M=2048 (w0bT rows)
  const int row0B = (bid / 16) * 128;   // over N=1024 (wout cols)
  const int wave = t >> 6, lane = t & 63;
  const int wm = wave >> 1, wn = wave & 1;
  const int g = lane >> 4, lr = lane & 15;
  f32x4 acc[4][4] = {};
  for (int k0 = 0; k0 < 1024; k0 += 64) {
#pragma unroll
    for (int p = 0; p < 4; ++p) {
      int cbase = (wave * 4 + p) * 64;
      int ci = cbase + lane;
      int r = ci >> 3, cp = ci & 7, cl = cp ^ (r & 7);
      gload16(w0bT + (size_t)(row0A + r) * 1024 + k0 + cl * 8, &As[cbase * 8]);
      gload16(wout_bf + (size_t)(row0B + r) * 1024 + k0 + cl * 8, &Bs[cbase * 8]);
    }
    __syncthreads();
#pragma unroll
    for (int kk = 0; kk < 2; ++kk) {
      bf16x8 af[4], bfr[4];
#pragma unroll
      for (int mt = 0; mt < 4; ++mt) {
        int r = wm * 64 + mt * 16 + lr, c = kk * 4 + g;
        af[mt] = *(const bf16x8*)((char*)As + r * 128 + ((c ^ (r & 7)) * 16));
      }
#pragma unroll
      for (int nt = 0; nt < 4; ++nt) {
        int r = wn * 64 + nt * 16 + lr, c = kk * 4 + g;
        bfr[nt] = *(const bf16x8*)((char*)Bs + r * 128 + ((c ^ (r & 7)) * 16));
      }
#pragma unroll
      for (int mt = 0; mt < 4; ++mt)
#pragma unroll
        for (int nt = 0; nt < 4; ++nt)
          acc[mt][nt] = MFMA16(af[mt], bfr[nt], acc[mt][nt]);
    }
    __syncthreads();
  }
#pragma unroll
  for (int mt = 0; mt < 4; ++mt) {
    int grow_base = row0A + wm * 64 + mt * 16 + g * 4;
#pragma unroll
    for (int nt = 0; nt < 4; ++nt) {
      int gcol = row0B + wn * 64 + nt * 16 + lr;
#pragma unroll
      for (int j = 0; j < 4; ++j)
        wT_ffn0[(size_t)(grow_base + j) * 2048 + 1024 + gcol] = (__bf16)acc[mt][nt][j];
    }
  }
}

// ---------------------------------------------------------------------------
// 128x128 GEMM (verified) — FFN3.
// ---------------------------------------------------------------------------
template <typename OutT, bool HAS_RES, bool HAS_BIAS>
__global__ __launch_bounds__(256) void gemm_kernel(
    const __bf16* __restrict__ A, int lda,
    const __bf16* __restrict__ Bt,
    const float* __restrict__ bias,
    OutT* __restrict__ C, int ldc,
    const float* __restrict__ res,
    int M, int Nn, int K) {
  __shared__ __attribute__((aligned(16))) __bf16 As[128 * 64];
  __shared__ __attribute__((aligned(16))) __bf16 Bs[128 * 64];

  const int t = threadIdx.x;
  const int row0A = blockIdx.x * 128;
  const int row0B = blockIdx.y * 128;
  const int wave = t >> 6, lane = t & 63;
  const int wm = wave >> 1, wn = wave & 1;
  const int g = lane >> 4, lr = lane & 15;

  f32x4 acc[4][4] = {};

  for (int k0 = 0; k0 < K; k0 += 64) {
#pragma unroll
    for (int p = 0; p < 4; ++p) {
      int cbase = (wave * 4 + p) * 64;
      int ci = cbase + lane;
      int r = ci >> 3, cp = ci & 7, cl = cp ^ (r & 7);
      gload16(A + (size_t)(row0A + r) * lda + k0 + cl * 8, &As[cbase * 8]);
      gload16(Bt + (size_t)(row0B + r) * K + k0 + cl * 8, &Bs[cbase * 8]);
    }
    __syncthreads();
#pragma unroll
    for (int kk = 0; kk < 2; ++kk) {
      bf16x8 af[4], bfr[4];
#pragma unroll
      for (int mt = 0; mt < 4; ++mt) {
        int r = wm * 64 + mt * 16 + lr, c = kk * 4 + g;
        af[mt] = *(const bf16x8*)((char*)As + r * 128 + ((c ^ (r & 7)) * 16));
      }
#pragma unroll
      for (int nt = 0; nt < 4; ++nt) {
        int r = wn * 64 + nt * 16 + lr, c = kk * 4 + g;
        bfr[nt] = *(const bf16x8*)((char*)Bs + r * 128 + ((c ^ (r & 7)) * 16));
      }
#pragma unroll
      for (int mt = 0; mt < 4; ++mt)
#pragma unroll
        for (int nt = 0; nt < 4; ++nt)
          acc[mt][nt] = MFMA16(af[mt], bfr[nt], acc[mt][nt]);
    }
    __syncthreads();
  }

  float bias_v[4];
#pragma unroll
  for (int nt = 0; nt < 4; ++nt)
    bias_v[nt] = HAS_BIAS ? bias[row0B + wn * 64 + nt * 16 + lr] : 0.f;
#pragma unroll
  for (int mt = 0; mt < 4; ++mt) {
    int grow_base = row0A + wm * 64 + mt * 16 + g * 4;
#pragma unroll
    for (int nt = 0; nt < 4; ++nt) {
      int gcol = row0B + wn * 64 + nt * 16 + lr;
#pragma unroll
      for (int j = 0; j < 4; ++j) {
        int grow = grow_base + j;
        float v = acc[mt][nt][j] + bias_v[nt];
        if (HAS_RES) v += res[(size_t)grow * ldc + gcol];
        C[(size_t)grow * ldc + gcol] = (OutT)v;
      }
    }
  }
}

// ---------------------------------------------------------------------------
// 256x256 4-phase counted-vmcnt GEMM (verified round 6).
// ---------------------------------------------------------------------------
template <typename OutT>
__global__ __launch_bounds__(512, 2) void gemm256p(
    const __bf16* __restrict__ A, int lda,
    const __bf16* __restrict__ Bt, int ldb,
    const float* __restrict__ bias,
    OutT* __restrict__ C, int ldc, int K) {
  __shared__ __attribute__((aligned(16))) __bf16 As[2][256 * 64];
  __shared__ __attribute__((aligned(16))) __bf16 Bs[2][256 * 64];

  const int t = threadIdx.x;
  const int wave = t >> 6, lane = t & 63;
  const int wm = wave >> 2, wn = wave & 3;
  const int g = lane >> 4, lr = lane & 15;
  const int row0A = blockIdx.x * 256, row0B = blockIdx.y * 256;
  const int L = K >> 6;

  f32x4 acc[8][4] = {};

#define STG_A(tile, i)                                                        \
  {                                                                           \
    int cb = ((i) * 8 + wave) * 64;                                           \
    int ci = cb + lane;                                                       \
    int r = ci >> 3, cl = (ci & 7) ^ (r & 7);                                 \
    gload16(A + (size_t)(row0A + r) * lda + (size_t)(tile) * 64 + cl * 8,     \
            &As[(tile) & 1][cb * 8]);                                         \
  }
#define STG_B(tile, i)                                                        \
  {                                                                           \
    int cb = ((i) * 8 + wave) * 64;                                           \
    int ci = cb + lane;                                                       \
    int r = ci >> 3, cl = (ci & 7) ^ (r & 7);                                 \
    gload16(Bt + (size_t)(row0B + r) * ldb + (size_t)(tile) * 64 + cl * 8,    \
            &Bs[(tile) & 1][cb * 8]);                                         \
  }
#define AFRAG(d, mi, ks)                                                      \
  (*(const bf16x8*)((const char*)As[d] + (wm * 128 + (mi) * 16 + lr) * 128 +  \
                    ((((ks) * 4 + g) ^ (lr & 7)) * 16)))
#define BFRAG(d, ni, ks)                                                      \
  (*(const bf16x8*)((const char*)Bs[d] + (wn * 64 + (ni) * 16 + lr) * 128 +   \
                    ((((ks) * 4 + g) ^ (lr & 7)) * 16)))

#pragma unroll
  for (int i = 0; i < 4; ++i) STG_A(0, i);
#pragma unroll
  for (int i = 0; i < 4; ++i) STG_B(0, i);
  STG_A(1, 0);
  STG_A(1, 1);
  asm volatile("s_waitcnt vmcnt(2)" ::: "memory");
  BARRIER;

  for (int tt = 0; tt < L; ++tt) {
    const int d = tt & 1;
    const bool s1 = (tt + 1) < L, s2 = (tt + 2) < L;
    bf16x8 aL[4][2], aH[4][2], bL[2][2], bH[2][2];

#pragma unroll
    for (int mi = 0; mi < 4; ++mi) {
      aL[mi][0] = AFRAG(d, mi, 0);
      aL[mi][1] = AFRAG(d, mi, 1);
    }
#pragma unroll
    for (int ni = 0; ni < 2; ++ni) {
      bL[ni][0] = BFRAG(d, ni, 0);
      bL[ni][1] = BFRAG(d, ni, 1);
    }
    if (s1) { STG_A(tt + 1, 2); STG_A(tt + 1, 3); }
    BARRIER;
    __builtin_amdgcn_s_setprio(1);
#pragma unroll
    for (int mi = 0; mi < 4; ++mi)
#pragma unroll
      for (int ni = 0; ni < 2; ++ni) {
        acc[mi][ni] = MFMA16(aL[mi][0], bL[ni][0], acc[mi][ni]);
        acc[mi][ni] = MFMA16(aL[mi][1], bL[ni][1], acc[mi][ni]);
      }
    __builtin_amdgcn_s_setprio(0);
    BARRIER;

#pragma unroll
    for (int ni = 0; ni < 2; ++ni) {
      bH[ni][0] = BFRAG(d, ni + 2, 0);
      bH[ni][1] = BFRAG(d, ni + 2, 1);
    }
    if (s1) { STG_B(tt + 1, 0); STG_B(tt + 1, 1); }
    BARRIER;
    __builtin_amdgcn_s_setprio(1);
#pragma unroll
    for (int mi = 0; mi < 4; ++mi)
#pragma unroll
      for (int ni = 0; ni < 2; ++ni) {
        acc[mi][ni + 2] = MFMA16(aL[mi][0], bH[ni][0], acc[mi][ni + 2]);
        acc[mi][ni + 2] = MFMA16(aL[mi][1], bH[ni][1], acc[mi][ni + 2]);
      }
    __builtin_amdgcn_s_setprio(0);
    BARRIER;

#pragma unroll
    for (int mi = 0; mi < 4; ++mi) {
      aH[mi][0] = AFRAG(d, mi + 4, 0);
      aH[mi][1] = AFRAG(d, mi + 4, 1);
    }
    if (s1) { STG_B(tt + 1, 2); STG_B(tt + 1, 3); }
    BARRIER;
    __builtin_amdgcn_s_setprio(1);
#pragma unroll
    for (int mi = 0; mi < 4; ++mi)
#pragma unroll
      for (int ni = 0; ni < 2; ++ni) {
        acc[mi + 4][ni + 2] = MFMA16(aH[mi][0], bH[ni][0], acc[mi + 4][ni + 2]);
        acc[mi + 4][ni + 2] = MFMA16(aH[mi][1], bH[ni][1], acc[mi + 4][ni + 2]);
      }
    __builtin_amdgcn_s_setprio(0);
    BARRIER;

    if (s2) { STG_A(tt + 2, 0); STG_A(tt + 2, 1); }
    __builtin_amdgcn_s_setprio(1);
#pragma unroll
    for (int mi = 0; mi < 4; ++mi)
#pragma unroll
      for (int ni = 0; ni < 2; ++ni) {
        acc[mi + 4][ni] = MFMA16(aH[mi][0], bL[ni][0], acc[mi + 4][ni]);
        acc[mi + 4][ni] = MFMA16(aH[mi][1], bL[ni][1], acc[mi + 4][ni]);
      }
    __builtin_amdgcn_s_setprio(0);
    if (s2)
      asm volatile("s_waitcnt vmcnt(2)" ::: "memory");
    else
      asm volatile("s_waitcnt vmcnt(0)" ::: "memory");
    BARRIER;
  }
#undef STG_A
#undef STG_B
#undef AFRAG
#undef BFRAG

  float bias_v[4];
#pragma unroll
  for (int ni = 0; ni < 4; ++ni) bias_v[ni] = bias[row0B + wn * 64 + ni * 16 + lr];
#pragma unroll
  for (int mi = 0; mi < 8; ++mi) {
    int grow_base = row0A + wm * 128 + mi * 16 + g * 4;
#pragma unroll
    for (int ni = 0; ni < 4; ++ni) {
      int gcol = row0B + wn * 64 + ni * 16 + lr;
#pragma unroll
      for (int j = 0; j < 4; ++j)
        C[(size_t)(grow_base + j) * ldc + gcol] = (OutT)(acc[mi][ni][j] + bias_v[ni]);
    }
  }
}

// ---------------------------------------------------------------------------
// RoPE + scatter (unchanged, verified).
// ---------------------------------------------------------------------------
__global__ __launch_bounds__(256) void rope_scatter(
    const __bf16* __restrict__ qkv, const float* __restrict__ enc,
    __bf16* __restrict__ q, __bf16* __restrict__ kk, __bf16* __restrict__ vt) {
  int bh = blockIdx.y;
  int b = bh >> 4, h = bh & 15;
  int n0 = blockIdx.x * 64;
  int t = threadIdx.x;
  const float QSC = 0.125f * 1.44269504088896f;
#pragma unroll
  for (int i = 0; i < 2; ++i) {
    int id = t + i * 256;
    int nl = id >> 3, cc = id & 7;
    int n = n0 + nl;
    size_t row = (size_t)(b * 2048 + n) * 3072;
    bf16x8 qv = *(const bf16x8*)(qkv + row + h * 64 + cc * 8);
    bf16x8 kv = *(const bf16x8*)(qkv + row + 1024 + h * 64 + cc * 8);
    const float* e0 = enc + (size_t)n * 64 + cc * 8;
    const float* e1 = e0 + 131072;
    __bf16 qo[8], ko[8];
#pragma unroll
    for (int e = 0; e < 8; e += 2) {
      float q0 = (float)qv[e], q1 = (float)qv[e + 1];
      float k0 = (float)kv[e], k1 = (float)kv[e + 1];
      float f00 = e0[e], f01 = e0[e + 1], f10 = e1[e], f11 = e1[e + 1];
      qo[e] = (__bf16)((q0 * f00 - q1 * f10) * QSC);
      qo[e + 1] = (__bf16)((q1 * f01 + q0 * f11) * QSC);
      ko[e] = (__bf16)(k0 * f00 - k1 * f10);
      ko[e + 1] = (__bf16)(k1 * f01 + k0 * f11);
    }
    size_t qb = ((size_t)bh * 2048 + n) * 64 + cc * 8;
    *(uint4*)(q + qb) = *(uint4*)qo;
    *(uint4*)(kk + qb) = *(uint4*)ko;
  }
#pragma unroll
  for (int i = 0; i < 2; ++i) {
    int id = t + i * 256;
    int hd = id >> 3, c = id & 7;
    __bf16 tmp[8];
#pragma unroll
    for (int e = 0; e < 8; ++e) {
      int kv = (c >> 2) * 32 + (e >> 2) * 16 + (c & 3) * 4 + (e & 3);
      int n = n0 + kv;
      tmp[e] = qkv[(size_t)(b * 2048 + n) * 3072 + 2048 + h * 64 + hd];
    }
    *(uint4*)(vt + ((size_t)bh * 64 + hd) * 2048 + n0 + c * 8) = *(uint4*)tmp;
  }
}

// ---------------------------------------------------------------------------
// Flash attention, QBLK=64 per wave (4 q-groups share K/V fragments).
// Block covers 256 q rows; grid 512. XCD swizzle: 8 heads/XCD (KV L2-fit).
// ---------------------------------------------------------------------------
__global__ __launch_bounds__(256) void attn_kernel(
    const __bf16* __restrict__ q, const __bf16* __restrict__ k,
    const __bf16* __restrict__ vt, __bf16* __restrict__ ctx) {
  __shared__ __attribute__((aligned(16))) __bf16 Ks[2][64 * 64];
  __shared__ __attribute__((aligned(16))) __bf16 Vs[2][64 * 64];

  int bid0 = blockIdx.y * gridDim.x + blockIdx.x;   // grid (8, 64) = 512
  int bid = (bid0 & 7) * 64 + (bid0 >> 3);
  const int bh = bid >> 3, qblk = bid & 7;
  const int b = bh >> 4, h = bh & 15;
  const int q0 = qblk * 256;
  const int t = threadIdx.x, wave = t >> 6, lane = t & 63;
  const int g = lane >> 4, lr = lane & 15;
  const int qrow0 = q0 + wave * 64;

  const __bf16* kbase = k + (size_t)bh * 2048 * 64;
  const __bf16* vbase = vt + (size_t)bh * 64 * 2048;

  bf16x8 qf[4][2];
#pragma unroll
  for (int u = 0; u < 4; ++u)
#pragma unroll
    for (int kc = 0; kc < 2; ++kc)
      qf[u][kc] = *(const bf16x8*)(q + ((size_t)bh * 2048 + qrow0 + u * 16 + lr) * 64 +
                                   kc * 32 + g * 8);

  bf16x8 ones;
#pragma unroll
  for (int e = 0; e < 8; ++e) ones[e] = (__bf16)1.0f;

  f32x4 o[4][4] = {};
  f32x4 lacc[4] = {};

#define STAGE_ATTN(buf, kv0)                                                    \
  {                                                                             \
    _Pragma("unroll") for (int p = 0; p < 2; ++p) {                             \
      int cbase = wave * 128 + p * 64;                                          \
      int ci = cbase + lane;                                                    \
      int r = ci >> 3, cp = ci & 7, cl = cp ^ (r & 7);                          \
      gload16(kbase + (size_t)((kv0) + r) * 64 + cl * 8, &Ks[buf][cbase * 8]);  \
      gload16(vbase + (size_t)r * 2048 + (kv0) + cl * 8, &Vs[buf][cbase * 8]);  \
    }                                                                           \
  }

  STAGE_ATTN(0, 0);
  __syncthreads();
  int buf = 0;

  for (int kv0 = 0; kv0 < 2048; kv0 += 64) {
    if (kv0 + 64 < 2048) STAGE_ATTN(buf ^ 1, kv0 + 64);

    // load K fragments once, reuse for all 4 q-groups
    bf16x8 kf[4][2];
#pragma unroll
    for (int nt = 0; nt < 4; ++nt) {
      int r = nt * 16 + lr;
      kf[nt][0] = *(const bf16x8*)((char*)Ks[buf] + r * 128 + ((g ^ (r & 7)) * 16));
      kf[nt][1] = *(const bf16x8*)((char*)Ks[buf] + r * 128 + (((4 + g) ^ (r & 7)) * 16));
    }

    bf16x8 pf[4][2];
#pragma unroll
    for (int u = 0; u < 4; ++u) {
      f32x4 s[4];
      __builtin_amdgcn_s_setprio(1);
#pragma unroll
      for (int nt = 0; nt < 4; ++nt) {
        f32x4 a = {};
        a = MFMA16(kf[nt][0], qf[u][0], a);
        a = MFMA16(kf[nt][1], qf[u][1], a);
        s[nt] = a;
      }
      __builtin_amdgcn_s_setprio(0);
#pragma unroll
      for (int t2 = 0; t2 < 2; ++t2)
#pragma unroll
        for (int e = 0; e < 8; ++e)
          pf[u][t2][e] = (__bf16)__builtin_amdgcn_exp2f(s[2 * t2 + (e >> 2)][e & 3]);
    }

    __builtin_amdgcn_s_setprio(1);
#pragma unroll
    for (int u = 0; u < 4; ++u) {
      lacc[u] = MFMA16(ones, pf[u][0], lacc[u]);
      lacc[u] = MFMA16(ones, pf[u][1], lacc[u]);
    }
#pragma unroll
    for (int t2 = 0; t2 < 2; ++t2)
#pragma unroll
      for (int nt = 0; nt < 4; ++nt) {
        int r = nt * 16 + lr;
        bf16x8 vf = *(const bf16x8*)((char*)Vs[buf] + r * 128 + (((t2 * 4 + g) ^ (r & 7)) * 16));
#pragma unroll
        for (int u = 0; u < 4; ++u) o[u][nt] = MFMA16(vf, pf[u][t2], o[u][nt]);
      }
    __builtin_amdgcn_s_setprio(0);
    __syncthreads();
    buf ^= 1;
  }

#pragma unroll
  for (int u = 0; u < 4; ++u) {
    float inv = 1.f / lacc[u][0];
    size_t obase = ((size_t)(b * 2048 + qrow0 + u * 16 + lr)) * 2048 + 1024 + h * 64;
#pragma unroll
    for (int nt = 0; nt < 4; ++nt) {
      __bf16 w4[4];
#pragma unroll
      for (int j = 0; j < 4; ++j) w4[j] = (__bf16)(o[u][nt][j] * inv);
      *(uint2*)(ctx + obase + nt * 16 + g * 4) = *(uint2*)w4;
    }
  }
#undef STAGE_ATTN
}

// ---------------------------------------------------------------------------
// LayerNorm + exact GELU over rows of 2048
// ---------------------------------------------------------------------------
__global__ __launch_bounds__(256) void ln_gelu(const __bf16* __restrict__ hin,
                                               const float* __restrict__ lns,
                                               const float* __restrict__ lnb,
                                               __bf16* __restrict__ hout) {
  int row = blockIdx.x;
  const __bf16* rp = hin + (size_t)row * 2048;
  int t = threadIdx.x;
  __bf16 tmp[8];
  *(uint4*)tmp = *(const uint4*)(rp + t * 8);
  float vals[8], s = 0.f, s2 = 0.f;
#pragma unroll
  for (int e = 0; e < 8; ++e) {
    float x = (float)tmp[e];
    vals[e] = x;
    s += x;
    s2 += x * x;
  }
#pragma unroll
  for (int m = 1; m < 64; m <<= 1) {
    s += __shfl_xor(s, m, 64);
    s2 += __shfl_xor(s2, m, 64);
  }
  __shared__ float red[8];
  int wave = t >> 6, lane = t & 63;
  if (lane == 0) { red[wave] = s; red[4 + wave] = s2; }
  __syncthreads();
  s = red[0] + red[1] + red[2] + red[3];
  s2 = red[4] + red[5] + red[6] + red[7];
  float mu = s * (1.f / 2048.f);
  float var = s2 * (1.f / 2048.f) - mu * mu;
  float rstd = rsqrtf(var + 1e-5f);
  __bf16 outv[8];
#pragma unroll
  for (int e = 0; e < 8; ++e) {
    int c = t * 8 + e;
    float xh = (vals[e] - mu) * rstd * lns[c] + lnb[c];
    float gg = 0.5f * xh * (1.f + erff(xh * 0.70710678118f));
    outv[e] = (__bf16)gg;
  }
  *(uint4*)(hout + (size_t)row * 2048 + t * 8) = *(uint4*)outv;
}

// ---------------------------------------------------------------------------
// Launch
// ---------------------------------------------------------------------------
extern "C" void kernel_launch(void* const* d_in, const int* in_sizes, int n_in,
                              void* d_out, int out_size, void* d_ws, size_t ws_size,
                              hipStream_t stream) {
  const float* x = (const float*)d_in[0];
  const float* enc = (const float*)d_in[1];
  const float* wqkv = (const float*)d_in[2];
  const float* bqkv = (const float*)d_in[3];
  const float* wout = (const float*)d_in[4];
  const float* bout = (const float*)d_in[5];
  const float* wffn0 = (const float*)d_in[6];
  const float* bffn0 = (const float*)d_in[7];
  const float* lns = (const float*)d_in[8];
  const float* lnb = (const float*)d_in[9];
  const float* wffn3 = (const float*)d_in[10];
  const float* bffn3 = (const float*)d_in[11];
  float* out = (float*)d_out;
  char* ws = (char*)d_ws;

  __bf16* wT_qkv = (__bf16*)(ws + 0);              //  6291456
  __bf16* wT_ffn0 = (__bf16*)(ws + 6291456);       //  8388608
  __bf16* wT_ffn3 = (__bf16*)(ws + 14680064);      //  4194304
  __bf16* wout_bf = (__bf16*)(ws + 18874368);      //  2097152
  __bf16* w0bT = (__bf16*)(ws + 20971520);         //  4194304
  float* bias_part = (float*)(ws + 25165824);      //   131072
  float* bqkv_p = (float*)(ws + 25296896);         //    12288
  float* bffn0_f = (float*)(ws + 25309184);        //     8192
  __bf16* h_in = (__bf16*)(ws + 25317376);         // 33554432  [x | ctx]
  __bf16* qkv = (__bf16*)(ws + 58871808);          // 50331648
  __bf16* ffn0o = qkv;                             // alias (qkv dead after rope)
  __bf16* qb = (__bf16*)(ws + 109203456);          // 16777216
  __bf16* h2 = qb;                                 // alias (q dead after attn)
  __bf16* kb = (__bf16*)(ws + 125980672);          // 16777216
  __bf16* vtb = (__bf16*)(ws + 142757888);         // 16777216

  dim3 blk(256);
  // weight/activation prep: 2 launches
  prep1<<<13964, blk, 0, stream>>>(wqkv, wT_qkv, wffn0, wT_ffn0, w0bT, wffn3, wT_ffn3,
                                   wout, wout_bf, bqkv, bqkv_p, bout, bias_part, x, h_in);
  prep2<<<136, blk, 0, stream>>>(w0bT, wout_bf, wT_ffn0, bias_part, bffn0, bffn0_f);

  // QKV projection (4-phase 256^2): [8192,1024] x [1024,3072]
  gemm256p<__bf16><<<dim3(32, 12), dim3(512), 0, stream>>>(
      h_in, 2048, wT_qkv, 1024, bqkv_p, qkv, 3072, 1024);

  rope_scatter<<<dim3(32, 64), blk, 0, stream>>>(qkv, enc, qb, kb, vtb);
  attn_kernel<<<dim3(8, 64), blk, 0, stream>>>(qb, kb, vtb, h_in);

  // FFN0 (with fused out-proj, 4-phase 256^2): [8192,2048] x [2048,2048]
  gemm256p<__bf16><<<dim3(32, 8), dim3(512), 0, stream>>>(
      h_in, 2048, wT_ffn0, 2048, bffn0_f, ffn0o, 2048, 2048);

  ln_gelu<<<8192, blk, 0, stream>>>(ffn0o, lns, lnb, h2);

  // FFN3 + bias + residual -> out (fp32)
  gemm_kernel<float, true, true><<<dim3(64, 8), blk, 0, stream>>>(
      h2, 2048, wT_ffn3, bffn3, out, 1024, x, 8192, 1024, 2048);
}

// Round 10
// 364.984 us; speedup vs baseline: 1.2798x; 1.0205x over previous
//
#include <hip/hip_runtime.h>
#include <hip/hip_bf16.h>
#include <math.h>

typedef __bf16 bf16x8 __attribute__((ext_vector_type(8)));
typedef float f32x4 __attribute__((ext_vector_type(4)));

#define MFMA16(a, b, c) __builtin_amdgcn_mfma_f32_16x16x32_bf16((a), (b), (c), 0, 0, 0)

__device__ __forceinline__ void gload16(const void* g, void* l) {
  __builtin_amdgcn_global_load_lds((const __attribute__((address_space(1))) void*)g,
                                   (__attribute__((address_space(3))) void*)l, 16, 0, 0);
}

#define BARRIER asm volatile("s_barrier" ::: "memory")

// ---------------------------------------------------------------------------
// prep1: ALL independent prep tasks in one launch (blockIdx ranges).
//   [0,3072)        transpose_qkv_perm
//   [3072,5120)     transpose W0 top  -> wT_ffn0 cols [0:1024)
//   [5120,7168)     transpose W0 bot  -> w0bT
//   [7168,9216)     transpose Wffn3   -> wT_ffn3
//   [9216,9728)     convert wout -> bf16
//   [9728,9740)     bias_perm (qkv bias)
//   [9740,9868)     fuse_bias_part
//   [9868,13964)    convert_x -> h_in left half
//   [13964,14220)   enc transpose fp32 -> encT[2][64][2048]
// ---------------------------------------------------------------------------
__device__ __forceinline__ void tr_body(float (*tile)[33], const float* __restrict__ in,
                                        int ldin, __bf16* __restrict__ out, int ldo,
                                        int n0, int k0, int t) {
  int tx = t & 31, ty = t >> 5;
#pragma unroll
  for (int r = 0; r < 32; r += 8)
    tile[ty + r][tx] = in[(size_t)(k0 + ty + r) * ldin + n0 + tx];
  __syncthreads();
#pragma unroll
  for (int r = 0; r < 32; r += 8)
    out[(size_t)(n0 + ty + r) * ldo + k0 + tx] = (__bf16)tile[tx][ty + r];
}

__global__ __launch_bounds__(256) void prep1(
    const float* __restrict__ wqkv, __bf16* __restrict__ wT_qkv,
    const float* __restrict__ wffn0, __bf16* __restrict__ wT_ffn0,
    __bf16* __restrict__ w0bT,
    const float* __restrict__ wffn3, __bf16* __restrict__ wT_ffn3,
    const float* __restrict__ wout, __bf16* __restrict__ wout_bf,
    const float* __restrict__ bqkv, float* __restrict__ bqkv_p,
    const float* __restrict__ bout, float* __restrict__ bias_part,
    const float* __restrict__ x, __bf16* __restrict__ h_in,
    const float* __restrict__ enc, float* __restrict__ encT) {
  __shared__ float tile[32][33];
  const int bid = blockIdx.x;
  const int t = threadIdx.x;

  if (bid < 3072) {
    int bx = bid % 96, by = bid / 96;
    int n0 = bx * 32, k0 = by * 32;
    int tx = t & 31, ty = t >> 5;
#pragma unroll
    for (int r = 0; r < 32; r += 8)
      tile[ty + r][tx] = wqkv[(size_t)(k0 + ty + r) * 3072 + n0 + tx];
    __syncthreads();
#pragma unroll
    for (int r = 0; r < 32; r += 8) {
      int n = n0 + ty + r;
      int h = n / 192, rem = n % 192, hd = rem / 3, which = rem % 3;
      int np = which * 1024 + h * 64 + hd;
      wT_qkv[(size_t)np * 1024 + k0 + tx] = (__bf16)tile[tx][ty + r];
    }
  } else if (bid < 5120) {
    int lb = bid - 3072, bx = lb % 64, by = lb / 64;
    tr_body(tile, wffn0, 2048, wT_ffn0, 2048, bx * 32, by * 32, t);
  } else if (bid < 7168) {
    int lb = bid - 5120, bx = lb % 64, by = lb / 64;
    tr_body(tile, wffn0 + (size_t)1024 * 2048, 2048, w0bT, 1024, bx * 32, by * 32, t);
  } else if (bid < 9216) {
    int lb = bid - 7168, bx = lb % 32, by = lb / 32;
    tr_body(tile, wffn3, 1024, wT_ffn3, 2048, bx * 32, by * 32, t);
  } else if (bid < 9728) {
    int id = (bid - 9216) * 256 + t;
    const float* src = wout + (size_t)id * 8;
    __bf16 tmp[8];
#pragma unroll
    for (int e = 0; e < 8; ++e) tmp[e] = (__bf16)src[e];
    *(uint4*)(wout_bf + (size_t)id * 8) = *(uint4*)tmp;
  } else if (bid < 9740) {
    int n = (bid - 9728) * 256 + t;
    if (n < 3072) {
      int h = n / 192, rem = n % 192, hd = rem / 3, which = rem % 3;
      bqkv_p[which * 1024 + h * 64 + hd] = bqkv[n];
    }
  } else if (bid < 9868) {
    int lb = bid - 9740;
    int n = (lb % 8) * 256 + t;
    int e0 = (lb / 8) * 64;
    float s = 0.f;
#pragma unroll 4
    for (int e = 0; e < 64; ++e)
      s += bout[e0 + e] * wffn0[(size_t)(1024 + e0 + e) * 2048 + n];
    bias_part[(size_t)(lb / 8) * 2048 + n] = s;
  } else if (bid < 13964) {
    int id = (bid - 9868) * 256 + t;
    int row = id >> 7, cc = id & 127;
    const float* src = x + (size_t)row * 1024 + cc * 8;
    __bf16 tmp[8];
#pragma unroll
    for (int e = 0; e < 8; ++e) tmp[e] = (__bf16)src[e];
    *(uint4*)(h_in + (size_t)row * 2048 + cc * 8) = *(uint4*)tmp;
  } else {
    // enc transpose: enc[tab][n][hd] -> encT[tab][hd][n] (fp32)
    int lb = bid - 13964;            // [0,256)
    int tab = lb >> 7, lb2 = lb & 127;
    int n0 = (lb2 & 1) * 32;         // hd-dim
    int k0 = (lb2 >> 1) * 32;        // n-dim
    int tx = t & 31, ty = t >> 5;
#pragma unroll
    for (int r = 0; r < 32; r += 8)
      tile[ty + r][tx] = enc[(size_t)tab * 131072 + (size_t)(k0 + ty + r) * 64 + n0 + tx];
    __syncthreads();
#pragma unroll
    for (int r = 0; r < 32; r += 8)
      encT[(size_t)tab * 131072 + (size_t)(n0 + ty + r) * 2048 + k0 + tx] = tile[tx][ty + r];
  }
}

// ---------------------------------------------------------------------------
// prep2: blocks [0,128): W''T = W0b^T * Wout^T -> wT_ffn0 cols [1024:2048)
//        blocks [128,136): fuse_bias_red
// ---------------------------------------------------------------------------
__global__ __launch_bounds__(256) void prep2(
    const __bf16* __restrict__ w0bT, const __bf16* __restrict__ wout_bf,
    __bf16* __restrict__ wT_ffn0,
    const float* __restrict__ bias_part, const float* __restrict__ bffn0,
    float* __restrict__ bffn0_f) {
  const int bid = blockIdx.x;
  const int t = threadIdx.x;
  if (bid >= 128) {
    int n = (bid - 128) * 256 + t;
    float s = bffn0[n];
#pragma unroll
    for (int y = 0; y < 16; ++y) s += bias_part[(size_t)y * 2048 + n];
    bffn0_f[n] = s;
    return;
  }
  __shared__ __attribute__((aligned(16))) __bf16 As[128 * 64];
  __shared__ __attribute__((aligned(16))) __bf16 Bs[128 * 64];
  const int row0A = (bid % 16) * 128;
  const int row0B = (bid / 16) * 128;
  const int wave = t >> 6, lane = t & 63;
  const int wm = wave >> 1, wn = wave & 1;
  const int g = lane >> 4, lr = lane & 15;
  f32x4 acc[4][4] = {};
  for (int k0 = 0; k0 < 1024; k0 += 64) {
#pragma unroll
    for (int p = 0; p < 4; ++p) {
      int cbase = (wave * 4 + p) * 64;
      int ci = cbase + lane;
      int r = ci >> 3, cp = ci & 7, cl = cp ^ (r & 7);
      gload16(w0bT + (size_t)(row0A + r) * 1024 + k0 + cl * 8, &As[cbase * 8]);
      gload16(wout_bf + (size_t)(row0B + r) * 1024 + k0 + cl * 8, &Bs[cbase * 8]);
    }
    __syncthreads();
#pragma unroll
    for (int kk = 0; kk < 2; ++kk) {
      bf16x8 af[4], bfr[4];
#pragma unroll
      for (int mt = 0; mt < 4; ++mt) {
        int r = wm * 64 + mt * 16 + lr, c = kk * 4 + g;
        af[mt] = *(const bf16x8*)((char*)As + r * 128 + ((c ^ (r & 7)) * 16));
      }
#pragma unroll
      for (int nt = 0; nt < 4; ++nt) {
        int r = wn * 64 + nt * 16 + lr, c = kk * 4 + g;
        bfr[nt] = *(const bf16x8*)((char*)Bs + r * 128 + ((c ^ (r & 7)) * 16));
      }
#pragma unroll
      for (int mt = 0; mt < 4; ++mt)
#pragma unroll
        for (int nt = 0; nt < 4; ++nt)
          acc[mt][nt] = MFMA16(af[mt], bfr[nt], acc[mt][nt]);
    }
    __syncthreads();
  }
#pragma unroll
  for (int mt = 0; mt < 4; ++mt) {
    int grow_base = row0A + wm * 64 + mt * 16 + g * 4;
#pragma unroll
    for (int nt = 0; nt < 4; ++nt) {
      int gcol = row0B + wn * 64 + nt * 16 + lr;
#pragma unroll
      for (int j = 0; j < 4; ++j)
        wT_ffn0[(size_t)(grow_base + j) * 2048 + 1024 + gcol] = (__bf16)acc[mt][nt][j];
    }
  }
}

// ---------------------------------------------------------------------------
// 128x128 GEMM (verified) — FFN3.
// ---------------------------------------------------------------------------
template <typename OutT, bool HAS_RES, bool HAS_BIAS>
__global__ __launch_bounds__(256) void gemm_kernel(
    const __bf16* __restrict__ A, int lda,
    const __bf16* __restrict__ Bt,
    const float* __restrict__ bias,
    OutT* __restrict__ C, int ldc,
    const float* __restrict__ res,
    int M, int Nn, int K) {
  __shared__ __attribute__((aligned(16))) __bf16 As[128 * 64];
  __shared__ __attribute__((aligned(16))) __bf16 Bs[128 * 64];

  const int t = threadIdx.x;
  const int row0A = blockIdx.x * 128;
  const int row0B = blockIdx.y * 128;
  const int wave = t >> 6, lane = t & 63;
  const int wm = wave >> 1, wn = wave & 1;
  const int g = lane >> 4, lr = lane & 15;

  f32x4 acc[4][4] = {};

  for (int k0 = 0; k0 < K; k0 += 64) {
#pragma unroll
    for (int p = 0; p < 4; ++p) {
      int cbase = (wave * 4 + p) * 64;
      int ci = cbase + lane;
      int r = ci >> 3, cp = ci & 7, cl = cp ^ (r & 7);
      gload16(A + (size_t)(row0A + r) * lda + k0 + cl * 8, &As[cbase * 8]);
      gload16(Bt + (size_t)(row0B + r) * K + k0 + cl * 8, &Bs[cbase * 8]);
    }
    __syncthreads();
#pragma unroll
    for (int kk = 0; kk < 2; ++kk) {
      bf16x8 af[4], bfr[4];
#pragma unroll
      for (int mt = 0; mt < 4; ++mt) {
        int r = wm * 64 + mt * 16 + lr, c = kk * 4 + g;
        af[mt] = *(const bf16x8*)((char*)As + r * 128 + ((c ^ (r & 7)) * 16));
      }
#pragma unroll
      for (int nt = 0; nt < 4; ++nt) {
        int r = wn * 64 + nt * 16 + lr, c = kk * 4 + g;
        bfr[nt] = *(const bf16x8*)((char*)Bs + r * 128 + ((c ^ (r & 7)) * 16));
      }
#pragma unroll
      for (int mt = 0; mt < 4; ++mt)
#pragma unroll
        for (int nt = 0; nt < 4; ++nt)
          acc[mt][nt] = MFMA16(af[mt], bfr[nt], acc[mt][nt]);
    }
    __syncthreads();
  }

  float bias_v[4];
#pragma unroll
  for (int nt = 0; nt < 4; ++nt)
    bias_v[nt] = HAS_BIAS ? bias[row0B + wn * 64 + nt * 16 + lr] : 0.f;
#pragma unroll
  for (int mt = 0; mt < 4; ++mt) {
    int grow_base = row0A + wm * 64 + mt * 16 + g * 4;
#pragma unroll
    for (int nt = 0; nt < 4; ++nt) {
      int gcol = row0B + wn * 64 + nt * 16 + lr;
#pragma unroll
      for (int j = 0; j < 4; ++j) {
        int grow = grow_base + j;
        float v = acc[mt][nt][j] + bias_v[nt];
        if (HAS_RES) v += res[(size_t)grow * ldc + gcol];
        C[(size_t)grow * ldc + gcol] = (OutT)v;
      }
    }
  }
}

// ---------------------------------------------------------------------------
// 256x256 4-phase counted-vmcnt GEMM (verified round 6).
// MODE 0: plain bias + C store (FFN0).
// MODE 1: QKV fused epilogue — RoPE (shuffle-pair) for Q/K written to qb/kb,
//         V bias + LDS-transpose + kv-perm written to vtb. No C write.
// ---------------------------------------------------------------------------
template <typename OutT, int MODE>
__global__ __launch_bounds__(512, 2) void gemm256p(
    const __bf16* __restrict__ A, int lda,
    const __bf16* __restrict__ Bt, int ldb,
    const float* __restrict__ bias,
    OutT* __restrict__ C, int ldc, int K,
    __bf16* __restrict__ qb, __bf16* __restrict__ kb,
    __bf16* __restrict__ vtb, const float* __restrict__ encT) {
  __shared__ __attribute__((aligned(16))) __bf16 As[2][256 * 64];
  __shared__ __attribute__((aligned(16))) __bf16 Bs[2][256 * 64];

  const int t = threadIdx.x;
  const int wave = t >> 6, lane = t & 63;
  const int wm = wave >> 2, wn = wave & 3;
  const int g = lane >> 4, lr = lane & 15;
  const int row0A = blockIdx.x * 256, row0B = blockIdx.y * 256;
  const int L = K >> 6;

  f32x4 acc[8][4] = {};

#define STG_A(tile, i)                                                        \
  {                                                                           \
    int cb = ((i) * 8 + wave) * 64;                                           \
    int ci = cb + lane;                                                       \
    int r = ci >> 3, cl = (ci & 7) ^ (r & 7);                                 \
    gload16(A + (size_t)(row0A + r) * lda + (size_t)(tile) * 64 + cl * 8,     \
            &As[(tile) & 1][cb * 8]);                                         \
  }
#define STG_B(tile, i)                                                        \
  {                                                                           \
    int cb = ((i) * 8 + wave) * 64;                                           \
    int ci = cb + lane;                                                       \
    int r = ci >> 3, cl = (ci & 7) ^ (r & 7);                                 \
    gload16(Bt + (size_t)(row0B + r) * ldb + (size_t)(tile) * 64 + cl * 8,    \
            &Bs[(tile) & 1][cb * 8]);                                         \
  }
#define AFRAG(d, mi, ks)                                                      \
  (*(const bf16x8*)((const char*)As[d] + (wm * 128 + (mi) * 16 + lr) * 128 +  \
                    ((((ks) * 4 + g) ^ (lr & 7)) * 16)))
#define BFRAG(d, ni, ks)                                                      \
  (*(const bf16x8*)((const char*)Bs[d] + (wn * 64 + (ni) * 16 + lr) * 128 +   \
                    ((((ks) * 4 + g) ^ (lr & 7)) * 16)))

#pragma unroll
  for (int i = 0; i < 4; ++i) STG_A(0, i);
#pragma unroll
  for (int i = 0; i < 4; ++i) STG_B(0, i);
  STG_A(1, 0);
  STG_A(1, 1);
  asm volatile("s_waitcnt vmcnt(2)" ::: "memory");
  BARRIER;

  for (int tt = 0; tt < L; ++tt) {
    const int d = tt & 1;
    const bool s1 = (tt + 1) < L, s2 = (tt + 2) < L;
    bf16x8 aL[4][2], aH[4][2], bL[2][2], bH[2][2];

#pragma unroll
    for (int mi = 0; mi < 4; ++mi) {
      aL[mi][0] = AFRAG(d, mi, 0);
      aL[mi][1] = AFRAG(d, mi, 1);
    }
#pragma unroll
    for (int ni = 0; ni < 2; ++ni) {
      bL[ni][0] = BFRAG(d, ni, 0);
      bL[ni][1] = BFRAG(d, ni, 1);
    }
    if (s1) { STG_A(tt + 1, 2); STG_A(tt + 1, 3); }
    BARRIER;
    __builtin_amdgcn_s_setprio(1);
#pragma unroll
    for (int mi = 0; mi < 4; ++mi)
#pragma unroll
      for (int ni = 0; ni < 2; ++ni) {
        acc[mi][ni] = MFMA16(aL[mi][0], bL[ni][0], acc[mi][ni]);
        acc[mi][ni] = MFMA16(aL[mi][1], bL[ni][1], acc[mi][ni]);
      }
    __builtin_amdgcn_s_setprio(0);
    BARRIER;

#pragma unroll
    for (int ni = 0; ni < 2; ++ni) {
      bH[ni][0] = BFRAG(d, ni + 2, 0);
      bH[ni][1] = BFRAG(d, ni + 2, 1);
    }
    if (s1) { STG_B(tt + 1, 0); STG_B(tt + 1, 1); }
    BARRIER;
    __builtin_amdgcn_s_setprio(1);
#pragma unroll
    for (int mi = 0; mi < 4; ++mi)
#pragma unroll
      for (int ni = 0; ni < 2; ++ni) {
        acc[mi][ni + 2] = MFMA16(aL[mi][0], bH[ni][0], acc[mi][ni + 2]);
        acc[mi][ni + 2] = MFMA16(aL[mi][1], bH[ni][1], acc[mi][ni + 2]);
      }
    __builtin_amdgcn_s_setprio(0);
    BARRIER;

#pragma unroll
    for (int mi = 0; mi < 4; ++mi) {
      aH[mi][0] = AFRAG(d, mi + 4, 0);
      aH[mi][1] = AFRAG(d, mi + 4, 1);
    }
    if (s1) { STG_B(tt + 1, 2); STG_B(tt + 1, 3); }
    BARRIER;
    __builtin_amdgcn_s_setprio(1);
#pragma unroll
    for (int mi = 0; mi < 4; ++mi)
#pragma unroll
      for (int ni = 0; ni < 2; ++ni) {
        acc[mi + 4][ni + 2] = MFMA16(aH[mi][0], bH[ni][0], acc[mi + 4][ni + 2]);
        acc[mi + 4][ni + 2] = MFMA16(aH[mi][1], bH[ni][1], acc[mi + 4][ni + 2]);
      }
    __builtin_amdgcn_s_setprio(0);
    BARRIER;

    if (s2) { STG_A(tt + 2, 0); STG_A(tt + 2, 1); }
    __builtin_amdgcn_s_setprio(1);
#pragma unroll
    for (int mi = 0; mi < 4; ++mi)
#pragma unroll
      for (int ni = 0; ni < 2; ++ni) {
        acc[mi + 4][ni] = MFMA16(aH[mi][0], bL[ni][0], acc[mi + 4][ni]);
        acc[mi + 4][ni] = MFMA16(aH[mi][1], bL[ni][1], acc[mi + 4][ni]);
      }
    __builtin_amdgcn_s_setprio(0);
    if (s2)
      asm volatile("s_waitcnt vmcnt(2)" ::: "memory");
    else
      asm volatile("s_waitcnt vmcnt(0)" ::: "memory");
    BARRIER;
  }
#undef STG_A
#undef STG_B
#undef AFRAG
#undef BFRAG

  float bias_v[4];
#pragma unroll
  for (int ni = 0; ni < 4; ++ni) bias_v[ni] = bias[row0B + wn * 64 + ni * 16 + lr];

  if (MODE == 0) {
#pragma unroll
    for (int mi = 0; mi < 8; ++mi) {
      int grow_base = row0A + wm * 128 + mi * 16 + g * 4;
#pragma unroll
      for (int ni = 0; ni < 4; ++ni) {
        int gcol = row0B + wn * 64 + ni * 16 + lr;
#pragma unroll
        for (int j = 0; j < 4; ++j)
          C[(size_t)(grow_base + j) * ldc + gcol] = (OutT)(acc[mi][ni][j] + bias_v[ni]);
      }
    }
  } else {
    // QKV-fused epilogue
    const int which = blockIdx.y >> 2;                 // 0=Q, 1=K, 2=V
    const int h = (blockIdx.y & 3) * 4 + wn;
    const int b = blockIdx.x >> 3;
    const int bh = b * 16 + h;
    const int ntop = (blockIdx.x & 7) * 256 + wm * 128;  // n within [0,2048)

    if (which < 2) {
      __bf16* dst = (which == 0) ? qb : kb;
      const float sc = (which == 0) ? 0.125f * 1.44269504088896f : 1.f;
      const float sgn = (lane & 1) ? 1.f : -1.f;
#pragma unroll
      for (int mi = 0; mi < 8; ++mi) {
#pragma unroll
        for (int ni = 0; ni < 4; ++ni) {
          int hd = ni * 16 + lr;
          const float* p0 = encT + (size_t)hd * 2048 + ntop + mi * 16 + g * 4;
          float4 f0 = *(const float4*)p0;
          float4 f1 = *(const float4*)(p0 + 131072);
#pragma unroll
          for (int j = 0; j < 4; ++j) {
            float v = acc[mi][ni][j] + bias_v[ni];
            float p = __shfl_xor(v, 1, 64);
            float e0 = ((const float*)&f0)[j], e1 = ((const float*)&f1)[j];
            float r = (v * e0 + sgn * p * e1) * sc;
            dst[((size_t)bh * 2048 + ntop + mi * 16 + g * 4 + j) * 64 + hd] = (__bf16)r;
          }
        }
      }
    } else {
      // V: bias -> swizzled LDS [hd][tok] per wave -> kv-perm coalesced writes
      char* lbuf = (char*)As;                 // 128 KB staging LDS (free now)
      const int wb2 = wave * 16384;           // 16 KB per wave (64hd x 128tok)
#pragma unroll
      for (int mi = 0; mi < 8; ++mi)
#pragma unroll
        for (int ni = 0; ni < 4; ++ni) {
          int hd = ni * 16 + lr;
          int tok = mi * 16 + g * 4;
          __bf16 w4[4];
#pragma unroll
          for (int j = 0; j < 4; ++j) w4[j] = (__bf16)(acc[mi][ni][j] + bias_v[ni]);
          int ab = wb2 + hd * 256 + ((tok * 2) ^ ((hd & 15) << 4));
          *(uint2*)(lbuf + ab) = *(uint2*)w4;
        }
      __syncthreads();
#pragma unroll
      for (int it = 0; it < 16; ++it) {
        int hd = (lane >> 3) + (it & 7) * 8;
        int slot = (lane & 7) + (it >> 3) * 8;   // 0..15 over 128 toks
        int grp = slot >> 3, c = slot & 7;
        int kv0 = grp * 64 + (c >> 2) * 32 + (c & 3) * 4;
        int a1 = wb2 + hd * 256 + ((kv0 * 2) ^ ((hd & 15) << 4));
        int a2 = wb2 + hd * 256 + (((kv0 + 16) * 2) ^ ((hd & 15) << 4));
        uint2 lo = *(uint2*)(lbuf + a1);
        uint2 hi = *(uint2*)(lbuf + a2);
        uint4 o4 = make_uint4(lo.x, lo.y, hi.x, hi.y);
        *(uint4*)(vtb + ((size_t)bh * 64 + hd) * 2048 + ntop + grp * 64 + c * 8) = o4;
      }
    }
  }
}

// ---------------------------------------------------------------------------
// Flash attention (round-7 verified: QBLK=32/wave, VGPR 64, grid (16,64)).
// ---------------------------------------------------------------------------
__global__ __launch_bounds__(256) void attn_kernel(
    const __bf16* __restrict__ q, const __bf16* __restrict__ k,
    const __bf16* __restrict__ vt, __bf16* __restrict__ ctx) {
  __shared__ __attribute__((aligned(16))) __bf16 Ks[2][64 * 64];
  __shared__ __attribute__((aligned(16))) __bf16 Vs[2][64 * 64];

  int nwg = gridDim.x * gridDim.y;  // 1024
  int bid0 = blockIdx.y * gridDim.x + blockIdx.x;
  int bid = (bid0 & 7) * (nwg >> 3) + (bid0 >> 3);
  const int bh = bid >> 4, qblk = bid & 15;
  const int b = bh >> 4, h = bh & 15;
  const int q0 = qblk * 128;
  const int t = threadIdx.x, wave = t >> 6, lane = t & 63;
  const int g = lane >> 4, lr = lane & 15;
  const int qrow0 = q0 + wave * 32;

  const __bf16* kbase = k + (size_t)bh * 2048 * 64;
  const __bf16* vbase = vt + (size_t)bh * 64 * 2048;

  bf16x8 qf[2][2];
#pragma unroll
  for (int u = 0; u < 2; ++u)
#pragma unroll
    for (int kc = 0; kc < 2; ++kc)
      qf[u][kc] = *(const bf16x8*)(q + ((size_t)bh * 2048 + qrow0 + u * 16 + lr) * 64 +
                                   kc * 32 + g * 8);

  bf16x8 ones;
#pragma unroll
  for (int e = 0; e < 8; ++e) ones[e] = (__bf16)1.0f;

  f32x4 o[2][4] = {};
  f32x4 lacc[2] = {};

#define STAGE_ATTN(buf, kv0)                                                    \
  {                                                                             \
    _Pragma("unroll") for (int p = 0; p < 2; ++p) {                             \
      int cbase = wave * 128 + p * 64;                                          \
      int ci = cbase + lane;                                                    \
      int r = ci >> 3, cp = ci & 7, cl = cp ^ (r & 7);                          \
      gload16(kbase + (size_t)((kv0) + r) * 64 + cl * 8, &Ks[buf][cbase * 8]);  \
      gload16(vbase + (size_t)r * 2048 + (kv0) + cl * 8, &Vs[buf][cbase * 8]);  \
    }                                                                           \
  }

  STAGE_ATTN(0, 0);
  __syncthreads();
  int buf = 0;

  for (int kv0 = 0; kv0 < 2048; kv0 += 64) {
    if (kv0 + 64 < 2048) STAGE_ATTN(buf ^ 1, kv0 + 64);

    f32x4 s[2][4];
    __builtin_amdgcn_s_setprio(1);
#pragma unroll
    for (int nt = 0; nt < 4; ++nt) {
      int r = nt * 16 + lr;
      bf16x8 kf0 = *(const bf16x8*)((char*)Ks[buf] + r * 128 + ((g ^ (r & 7)) * 16));
      bf16x8 kf1 = *(const bf16x8*)((char*)Ks[buf] + r * 128 + (((4 + g) ^ (r & 7)) * 16));
#pragma unroll
      for (int u = 0; u < 2; ++u) {
        f32x4 a = {};
        a = MFMA16(kf0, qf[u][0], a);
        a = MFMA16(kf1, qf[u][1], a);
        s[u][nt] = a;
      }
    }
    __builtin_amdgcn_s_setprio(0);

#pragma unroll
    for (int t2 = 0; t2 < 2; ++t2) {
      bf16x8 pf[2];
#pragma unroll
      for (int u = 0; u < 2; ++u) {
#pragma unroll
        for (int e = 0; e < 8; ++e)
          pf[u][e] = (__bf16)__builtin_amdgcn_exp2f(s[u][2 * t2 + (e >> 2)][e & 3]);
        lacc[u] = MFMA16(ones, pf[u], lacc[u]);
      }
      __builtin_amdgcn_s_setprio(1);
#pragma unroll
      for (int nt = 0; nt < 4; ++nt) {
        int r = nt * 16 + lr;
        bf16x8 vf = *(const bf16x8*)((char*)Vs[buf] + r * 128 + (((t2 * 4 + g) ^ (r & 7)) * 16));
#pragma unroll
        for (int u = 0; u < 2; ++u) o[u][nt] = MFMA16(vf, pf[u], o[u][nt]);
      }
      __builtin_amdgcn_s_setprio(0);
    }
    __syncthreads();
    buf ^= 1;
  }

#pragma unroll
  for (int u = 0; u < 2; ++u) {
    float inv = 1.f / lacc[u][0];
    size_t obase = ((size_t)(b * 2048 + qrow0 + u * 16 + lr)) * 2048 + 1024 + h * 64;
#pragma unroll
    for (int nt = 0; nt < 4; ++nt) {
      __bf16 w4[4];
#pragma unroll
      for (int j = 0; j < 4; ++j) w4[j] = (__bf16)(o[u][nt][j] * inv);
      *(uint2*)(ctx + obase + nt * 16 + g * 4) = *(uint2*)w4;
    }
  }
#undef STAGE_ATTN
}

// ---------------------------------------------------------------------------
// LayerNorm + exact GELU over rows of 2048
// ---------------------------------------------------------------------------
__global__ __launch_bounds__(256) void ln_gelu(const __bf16* __restrict__ hin,
                                               const float* __restrict__ lns,
                                               const float* __restrict__ lnb,
                                               __bf16* __restrict__ hout) {
  int row = blockIdx.x;
  const __bf16* rp = hin + (size_t)row * 2048;
  int t = threadIdx.x;
  __bf16 tmp[8];
  *(uint4*)tmp = *(const uint4*)(rp + t * 8);
  float vals[8], s = 0.f, s2 = 0.f;
#pragma unroll
  for (int e = 0; e < 8; ++e) {
    float x = (float)tmp[e];
    vals[e] = x;
    s += x;
    s2 += x * x;
  }
#pragma unroll
  for (int m = 1; m < 64; m <<= 1) {
    s += __shfl_xor(s, m, 64);
    s2 += __shfl_xor(s2, m, 64);
  }
  __shared__ float red[8];
  int wave = t >> 6, lane = t & 63;
  if (lane == 0) { red[wave] = s; red[4 + wave] = s2; }
  __syncthreads();
  s = red[0] + red[1] + red[2] + red[3];
  s2 = red[4] + red[5] + red[6] + red[7];
  float mu = s * (1.f / 2048.f);
  float var = s2 * (1.f / 2048.f) - mu * mu;
  float rstd = rsqrtf(var + 1e-5f);
  __bf16 outv[8];
#pragma unroll
  for (int e = 0; e < 8; ++e) {
    int c = t * 8 + e;
    float xh = (vals[e] - mu) * rstd * lns[c] + lnb[c];
    float gg = 0.5f * xh * (1.f + erff(xh * 0.70710678118f));
    outv[e] = (__bf16)gg;
  }
  *(uint4*)(hout + (size_t)row * 2048 + t * 8) = *(uint4*)outv;
}

// ---------------------------------------------------------------------------
// Launch
// ---------------------------------------------------------------------------
extern "C" void kernel_launch(void* const* d_in, const int* in_sizes, int n_in,
                              void* d_out, int out_size, void* d_ws, size_t ws_size,
                              hipStream_t stream) {
  const float* x = (const float*)d_in[0];
  const float* enc = (const float*)d_in[1];
  const float* wqkv = (const float*)d_in[2];
  const float* bqkv = (const float*)d_in[3];
  const float* wout = (const float*)d_in[4];
  const float* bout = (const float*)d_in[5];
  const float* wffn0 = (const float*)d_in[6];
  const float* bffn0 = (const float*)d_in[7];
  const float* lns = (const float*)d_in[8];
  const float* lnb = (const float*)d_in[9];
  const float* wffn3 = (const float*)d_in[10];
  const float* bffn3 = (const float*)d_in[11];
  float* out = (float*)d_out;
  char* ws = (char*)d_ws;

  __bf16* wT_qkv = (__bf16*)(ws + 0);              //  6291456
  __bf16* wT_ffn0 = (__bf16*)(ws + 6291456);       //  8388608
  __bf16* wT_ffn3 = (__bf16*)(ws + 14680064);      //  4194304
  __bf16* wout_bf = (__bf16*)(ws + 18874368);      //  2097152
  __bf16* w0bT = (__bf16*)(ws + 20971520);         //  4194304
  float* bias_part = (float*)(ws + 25165824);      //   131072
  float* bqkv_p = (float*)(ws + 25296896);         //    12288
  float* bffn0_f = (float*)(ws + 25309184);        //     8192
  __bf16* h_in = (__bf16*)(ws + 25317376);         // 33554432  [x | ctx]
  __bf16* ffn0o = (__bf16*)(ws + 58871808);        // 33554432
  __bf16* qb = (__bf16*)(ws + 109203456);          // 16777216
  __bf16* h2 = qb;                                 // alias (q dead after attn)
  __bf16* kb = (__bf16*)(ws + 125980672);          // 16777216
  __bf16* vtb = (__bf16*)(ws + 142757888);         // 16777216
  float* encT = (float*)(ws + 159535104);          //  1048576

  dim3 blk(256);
  prep1<<<14220, blk, 0, stream>>>(wqkv, wT_qkv, wffn0, wT_ffn0, w0bT, wffn3, wT_ffn3,
                                   wout, wout_bf, bqkv, bqkv_p, bout, bias_part, x, h_in,
                                   enc, encT);
  prep2<<<136, blk, 0, stream>>>(w0bT, wout_bf, wT_ffn0, bias_part, bffn0, bffn0_f);

  // QKV projection + fused RoPE/scatter: [8192,1024] x [1024,3072] -> qb,kb,vtb
  gemm256p<__bf16, 1><<<dim3(32, 12), dim3(512), 0, stream>>>(
      h_in, 2048, wT_qkv, 1024, bqkv_p, (__bf16*)nullptr, 0, 1024, qb, kb, vtb, encT);

  attn_kernel<<<dim3(16, 64), blk, 0, stream>>>(qb, kb, vtb, h_in);

  // FFN0 (with fused out-proj): [8192,2048] x [2048,2048]
  gemm256p<__bf16, 0><<<dim3(32, 8), dim3(512), 0, stream>>>(
      h_in, 2048, wT_ffn0, 2048, bffn0_f, ffn0o, 2048, 2048,
      nullptr, nullptr, nullptr, nullptr);

  ln_gelu<<<8192, blk, 0, stream>>>(ffn0o, lns, lnb, h2);

  // FFN3 + bias + residual -> out (fp32)
  gemm_kernel<float, true, true><<<dim3(64, 8), blk, 0, stream>>>(
      h2, 2048, wT_ffn3, bffn3, out, 1024, x, 8192, 1024, 2048);
}

// Round 11
// 363.798 us; speedup vs baseline: 1.2840x; 1.0033x over previous
//
#include <hip/hip_runtime.h>
#include <hip/hip_bf16.h>
#include <math.h>

typedef __bf16 bf16x8 __attribute__((ext_vector_type(8)));
typedef float f32x4 __attribute__((ext_vector_type(4)));

#define MFMA16(a, b, c) __builtin_amdgcn_mfma_f32_16x16x32_bf16((a), (b), (c), 0, 0, 0)

__device__ __forceinline__ void gload16(const void* g, void* l) {
  __builtin_amdgcn_global_load_lds((const __attribute__((address_space(1))) void*)g,
                                   (__attribute__((address_space(3))) void*)l, 16, 0, 0);
}

#define BARRIER asm volatile("s_barrier" ::: "memory")

// ---------------------------------------------------------------------------
// prep1: ALL independent prep tasks in one launch (blockIdx ranges).
// ---------------------------------------------------------------------------
__device__ __forceinline__ void tr_body(float (*tile)[33], const float* __restrict__ in,
                                        int ldin, __bf16* __restrict__ out, int ldo,
                                        int n0, int k0, int t) {
  int tx = t & 31, ty = t >> 5;
#pragma unroll
  for (int r = 0; r < 32; r += 8)
    tile[ty + r][tx] = in[(size_t)(k0 + ty + r) * ldin + n0 + tx];
  __syncthreads();
#pragma unroll
  for (int r = 0; r < 32; r += 8)
    out[(size_t)(n0 + ty + r) * ldo + k0 + tx] = (__bf16)tile[tx][ty + r];
}

__global__ __launch_bounds__(256) void prep1(
    const float* __restrict__ wqkv, __bf16* __restrict__ wT_qkv,
    const float* __restrict__ wffn0, __bf16* __restrict__ wT_ffn0,
    __bf16* __restrict__ w0bT,
    const float* __restrict__ wffn3, __bf16* __restrict__ wT_ffn3,
    const float* __restrict__ wout, __bf16* __restrict__ wout_bf,
    const float* __restrict__ bqkv, float* __restrict__ bqkv_p,
    const float* __restrict__ bout, float* __restrict__ bias_part,
    const float* __restrict__ x, __bf16* __restrict__ h_in,
    const float* __restrict__ enc, float* __restrict__ encT) {
  __shared__ float tile[32][33];
  const int bid = blockIdx.x;
  const int t = threadIdx.x;

  if (bid < 3072) {
    int bx = bid % 96, by = bid / 96;
    int n0 = bx * 32, k0 = by * 32;
    int tx = t & 31, ty = t >> 5;
#pragma unroll
    for (int r = 0; r < 32; r += 8)
      tile[ty + r][tx] = wqkv[(size_t)(k0 + ty + r) * 3072 + n0 + tx];
    __syncthreads();
#pragma unroll
    for (int r = 0; r < 32; r += 8) {
      int n = n0 + ty + r;
      int h = n / 192, rem = n % 192, hd = rem / 3, which = rem % 3;
      int np = which * 1024 + h * 64 + hd;
      wT_qkv[(size_t)np * 1024 + k0 + tx] = (__bf16)tile[tx][ty + r];
    }
  } else if (bid < 5120) {
    int lb = bid - 3072, bx = lb % 64, by = lb / 64;
    tr_body(tile, wffn0, 2048, wT_ffn0, 2048, bx * 32, by * 32, t);
  } else if (bid < 7168) {
    int lb = bid - 5120, bx = lb % 64, by = lb / 64;
    tr_body(tile, wffn0 + (size_t)1024 * 2048, 2048, w0bT, 1024, bx * 32, by * 32, t);
  } else if (bid < 9216) {
    int lb = bid - 7168, bx = lb % 32, by = lb / 32;
    tr_body(tile, wffn3, 1024, wT_ffn3, 2048, bx * 32, by * 32, t);
  } else if (bid < 9728) {
    int id = (bid - 9216) * 256 + t;
    const float* src = wout + (size_t)id * 8;
    __bf16 tmp[8];
#pragma unroll
    for (int e = 0; e < 8; ++e) tmp[e] = (__bf16)src[e];
    *(uint4*)(wout_bf + (size_t)id * 8) = *(uint4*)tmp;
  } else if (bid < 9740) {
    int n = (bid - 9728) * 256 + t;
    if (n < 3072) {
      int h = n / 192, rem = n % 192, hd = rem / 3, which = rem % 3;
      bqkv_p[which * 1024 + h * 64 + hd] = bqkv[n];
    }
  } else if (bid < 9868) {
    int lb = bid - 9740;
    int n = (lb % 8) * 256 + t;
    int e0 = (lb / 8) * 64;
    float s = 0.f;
#pragma unroll 4
    for (int e = 0; e < 64; ++e)
      s += bout[e0 + e] * wffn0[(size_t)(1024 + e0 + e) * 2048 + n];
    bias_part[(size_t)(lb / 8) * 2048 + n] = s;
  } else if (bid < 13964) {
    int id = (bid - 9868) * 256 + t;
    int row = id >> 7, cc = id & 127;
    const float* src = x + (size_t)row * 1024 + cc * 8;
    __bf16 tmp[8];
#pragma unroll
    for (int e = 0; e < 8; ++e) tmp[e] = (__bf16)src[e];
    *(uint4*)(h_in + (size_t)row * 2048 + cc * 8) = *(uint4*)tmp;
  } else {
    int lb = bid - 13964;            // [0,256)
    int tab = lb >> 7, lb2 = lb & 127;
    int n0 = (lb2 & 1) * 32;
    int k0 = (lb2 >> 1) * 32;
    int tx = t & 31, ty = t >> 5;
#pragma unroll
    for (int r = 0; r < 32; r += 8)
      tile[ty + r][tx] = enc[(size_t)tab * 131072 + (size_t)(k0 + ty + r) * 64 + n0 + tx];
    __syncthreads();
#pragma unroll
    for (int r = 0; r < 32; r += 8)
      encT[(size_t)tab * 131072 + (size_t)(n0 + ty + r) * 2048 + k0 + tx] = tile[tx][ty + r];
  }
}

// ---------------------------------------------------------------------------
// prep2: blocks [0,128): W''T = W0b^T * Wout^T -> wT_ffn0 cols [1024:2048)
//        blocks [128,136): fuse_bias_red
// ---------------------------------------------------------------------------
__global__ __launch_bounds__(256) void prep2(
    const __bf16* __restrict__ w0bT, const __bf16* __restrict__ wout_bf,
    __bf16* __restrict__ wT_ffn0,
    const float* __restrict__ bias_part, const float* __restrict__ bffn0,
    float* __restrict__ bffn0_f) {
  const int bid = blockIdx.x;
  const int t = threadIdx.x;
  if (bid >= 128) {
    int n = (bid - 128) * 256 + t;
    float s = bffn0[n];
#pragma unroll
    for (int y = 0; y < 16; ++y) s += bias_part[(size_t)y * 2048 + n];
    bffn0_f[n] = s;
    return;
  }
  __shared__ __attribute__((aligned(16))) __bf16 As[128 * 64];
  __shared__ __attribute__((aligned(16))) __bf16 Bs[128 * 64];
  const int row0A = (bid % 16) * 128;
  const int row0B = (bid / 16) * 128;
  const int wave = t >> 6, lane = t & 63;
  const int wm = wave >> 1, wn = wave & 1;
  const int g = lane >> 4, lr = lane & 15;
  f32x4 acc[4][4] = {};
  for (int k0 = 0; k0 < 1024; k0 += 64) {
#pragma unroll
    for (int p = 0; p < 4; ++p) {
      int cbase = (wave * 4 + p) * 64;
      int ci = cbase + lane;
      int r = ci >> 3, cp = ci & 7, cl = cp ^ (r & 7);
      gload16(w0bT + (size_t)(row0A + r) * 1024 + k0 + cl * 8, &As[cbase * 8]);
      gload16(wout_bf + (size_t)(row0B + r) * 1024 + k0 + cl * 8, &Bs[cbase * 8]);
    }
    __syncthreads();
#pragma unroll
    for (int kk = 0; kk < 2; ++kk) {
      bf16x8 af[4], bfr[4];
#pragma unroll
      for (int mt = 0; mt < 4; ++mt) {
        int r = wm * 64 + mt * 16 + lr, c = kk * 4 + g;
        af[mt] = *(const bf16x8*)((char*)As + r * 128 + ((c ^ (r & 7)) * 16));
      }
#pragma unroll
      for (int nt = 0; nt < 4; ++nt) {
        int r = wn * 64 + nt * 16 + lr, c = kk * 4 + g;
        bfr[nt] = *(const bf16x8*)((char*)Bs + r * 128 + ((c ^ (r & 7)) * 16));
      }
#pragma unroll
      for (int mt = 0; mt < 4; ++mt)
#pragma unroll
        for (int nt = 0; nt < 4; ++nt)
          acc[mt][nt] = MFMA16(af[mt], bfr[nt], acc[mt][nt]);
    }
    __syncthreads();
  }
#pragma unroll
  for (int mt = 0; mt < 4; ++mt) {
    int grow_base = row0A + wm * 64 + mt * 16 + g * 4;
#pragma unroll
    for (int nt = 0; nt < 4; ++nt) {
      int gcol = row0B + wn * 64 + nt * 16 + lr;
#pragma unroll
      for (int j = 0; j < 4; ++j)
        wT_ffn0[(size_t)(grow_base + j) * 2048 + 1024 + gcol] = (__bf16)acc[mt][nt][j];
    }
  }
}

// ---------------------------------------------------------------------------
// 128x128 GEMM (verified) — FFN3.
// ---------------------------------------------------------------------------
template <typename OutT, bool HAS_RES, bool HAS_BIAS>
__global__ __launch_bounds__(256) void gemm_kernel(
    const __bf16* __restrict__ A, int lda,
    const __bf16* __restrict__ Bt,
    const float* __restrict__ bias,
    OutT* __restrict__ C, int ldc,
    const float* __restrict__ res,
    int M, int Nn, int K) {
  __shared__ __attribute__((aligned(16))) __bf16 As[128 * 64];
  __shared__ __attribute__((aligned(16))) __bf16 Bs[128 * 64];

  const int t = threadIdx.x;
  const int row0A = blockIdx.x * 128;
  const int row0B = blockIdx.y * 128;
  const int wave = t >> 6, lane = t & 63;
  const int wm = wave >> 1, wn = wave & 1;
  const int g = lane >> 4, lr = lane & 15;

  f32x4 acc[4][4] = {};

  for (int k0 = 0; k0 < K; k0 += 64) {
#pragma unroll
    for (int p = 0; p < 4; ++p) {
      int cbase = (wave * 4 + p) * 64;
      int ci = cbase + lane;
      int r = ci >> 3, cp = ci & 7, cl = cp ^ (r & 7);
      gload16(A + (size_t)(row0A + r) * lda + k0 + cl * 8, &As[cbase * 8]);
      gload16(Bt + (size_t)(row0B + r) * K + k0 + cl * 8, &Bs[cbase * 8]);
    }
    __syncthreads();
#pragma unroll
    for (int kk = 0; kk < 2; ++kk) {
      bf16x8 af[4], bfr[4];
#pragma unroll
      for (int mt = 0; mt < 4; ++mt) {
        int r = wm * 64 + mt * 16 + lr, c = kk * 4 + g;
        af[mt] = *(const bf16x8*)((char*)As + r * 128 + ((c ^ (r & 7)) * 16));
      }
#pragma unroll
      for (int nt = 0; nt < 4; ++nt) {
        int r = wn * 64 + nt * 16 + lr, c = kk * 4 + g;
        bfr[nt] = *(const bf16x8*)((char*)Bs + r * 128 + ((c ^ (r & 7)) * 16));
      }
#pragma unroll
      for (int mt = 0; mt < 4; ++mt)
#pragma unroll
        for (int nt = 0; nt < 4; ++nt)
          acc[mt][nt] = MFMA16(af[mt], bfr[nt], acc[mt][nt]);
    }
    __syncthreads();
  }

  float bias_v[4];
#pragma unroll
  for (int nt = 0; nt < 4; ++nt)
    bias_v[nt] = HAS_BIAS ? bias[row0B + wn * 64 + nt * 16 + lr] : 0.f;
#pragma unroll
  for (int mt = 0; mt < 4; ++mt) {
    int grow_base = row0A + wm * 64 + mt * 16 + g * 4;
#pragma unroll
    for (int nt = 0; nt < 4; ++nt) {
      int gcol = row0B + wn * 64 + nt * 16 + lr;
#pragma unroll
      for (int j = 0; j < 4; ++j) {
        int grow = grow_base + j;
        float v = acc[mt][nt][j] + bias_v[nt];
        if (HAS_RES) v += res[(size_t)grow * ldc + gcol];
        C[(size_t)grow * ldc + gcol] = (OutT)v;
      }
    }
  }
}

// ---------------------------------------------------------------------------
// 256x256 4-phase counted-vmcnt GEMM (verified round 6).
// MODE 0: plain bias + C store (FFN0).
// MODE 1: QKV fused epilogue — Q: RoPE + qpack layout (coalesced uint2);
//         K: RoPE + LDS transpose -> row-major kb (coalesced uint4);
//         V: bias + LDS transpose + kv-perm -> vtb. No C write.
// ---------------------------------------------------------------------------
template <typename OutT, int MODE>
__global__ __launch_bounds__(512, 2) void gemm256p(
    const __bf16* __restrict__ A, int lda,
    const __bf16* __restrict__ Bt, int ldb,
    const float* __restrict__ bias,
    OutT* __restrict__ C, int ldc, int K,
    __bf16* __restrict__ qb, __bf16* __restrict__ kb,
    __bf16* __restrict__ vtb, const float* __restrict__ encT) {
  __shared__ __attribute__((aligned(16))) __bf16 As[2][256 * 64];
  __shared__ __attribute__((aligned(16))) __bf16 Bs[2][256 * 64];

  const int t = threadIdx.x;
  const int wave = t >> 6, lane = t & 63;
  const int wm = wave >> 2, wn = wave & 3;
  const int g = lane >> 4, lr = lane & 15;
  const int row0A = blockIdx.x * 256, row0B = blockIdx.y * 256;
  const int L = K >> 6;

  f32x4 acc[8][4] = {};

#define STG_A(tile, i)                                                        \
  {                                                                           \
    int cb = ((i) * 8 + wave) * 64;                                           \
    int ci = cb + lane;                                                       \
    int r = ci >> 3, cl = (ci & 7) ^ (r & 7);                                 \
    gload16(A + (size_t)(row0A + r) * lda + (size_t)(tile) * 64 + cl * 8,     \
            &As[(tile) & 1][cb * 8]);                                         \
  }
#define STG_B(tile, i)                                                        \
  {                                                                           \
    int cb = ((i) * 8 + wave) * 64;                                           \
    int ci = cb + lane;                                                       \
    int r = ci >> 3, cl = (ci & 7) ^ (r & 7);                                 \
    gload16(Bt + (size_t)(row0B + r) * ldb + (size_t)(tile) * 64 + cl * 8,    \
            &Bs[(tile) & 1][cb * 8]);                                         \
  }
#define AFRAG(d, mi, ks)                                                      \
  (*(const bf16x8*)((const char*)As[d] + (wm * 128 + (mi) * 16 + lr) * 128 +  \
                    ((((ks) * 4 + g) ^ (lr & 7)) * 16)))
#define BFRAG(d, ni, ks)                                                      \
  (*(const bf16x8*)((const char*)Bs[d] + (wn * 64 + (ni) * 16 + lr) * 128 +   \
                    ((((ks) * 4 + g) ^ (lr & 7)) * 16)))

#pragma unroll
  for (int i = 0; i < 4; ++i) STG_A(0, i);
#pragma unroll
  for (int i = 0; i < 4; ++i) STG_B(0, i);
  STG_A(1, 0);
  STG_A(1, 1);
  asm volatile("s_waitcnt vmcnt(2)" ::: "memory");
  BARRIER;

  for (int tt = 0; tt < L; ++tt) {
    const int d = tt & 1;
    const bool s1 = (tt + 1) < L, s2 = (tt + 2) < L;
    bf16x8 aL[4][2], aH[4][2], bL[2][2], bH[2][2];

#pragma unroll
    for (int mi = 0; mi < 4; ++mi) {
      aL[mi][0] = AFRAG(d, mi, 0);
      aL[mi][1] = AFRAG(d, mi, 1);
    }
#pragma unroll
    for (int ni = 0; ni < 2; ++ni) {
      bL[ni][0] = BFRAG(d, ni, 0);
      bL[ni][1] = BFRAG(d, ni, 1);
    }
    if (s1) { STG_A(tt + 1, 2); STG_A(tt + 1, 3); }
    BARRIER;
    __builtin_amdgcn_s_setprio(1);
#pragma unroll
    for (int mi = 0; mi < 4; ++mi)
#pragma unroll
      for (int ni = 0; ni < 2; ++ni) {
        acc[mi][ni] = MFMA16(aL[mi][0], bL[ni][0], acc[mi][ni]);
        acc[mi][ni] = MFMA16(aL[mi][1], bL[ni][1], acc[mi][ni]);
      }
    __builtin_amdgcn_s_setprio(0);
    BARRIER;

#pragma unroll
    for (int ni = 0; ni < 2; ++ni) {
      bH[ni][0] = BFRAG(d, ni + 2, 0);
      bH[ni][1] = BFRAG(d, ni + 2, 1);
    }
    if (s1) { STG_B(tt + 1, 0); STG_B(tt + 1, 1); }
    BARRIER;
    __builtin_amdgcn_s_setprio(1);
#pragma unroll
    for (int mi = 0; mi < 4; ++mi)
#pragma unroll
      for (int ni = 0; ni < 2; ++ni) {
        acc[mi][ni + 2] = MFMA16(aL[mi][0], bH[ni][0], acc[mi][ni + 2]);
        acc[mi][ni + 2] = MFMA16(aL[mi][1], bH[ni][1], acc[mi][ni + 2]);
      }
    __builtin_amdgcn_s_setprio(0);
    BARRIER;

#pragma unroll
    for (int mi = 0; mi < 4; ++mi) {
      aH[mi][0] = AFRAG(d, mi + 4, 0);
      aH[mi][1] = AFRAG(d, mi + 4, 1);
    }
    if (s1) { STG_B(tt + 1, 2); STG_B(tt + 1, 3); }
    BARRIER;
    __builtin_amdgcn_s_setprio(1);
#pragma unroll
    for (int mi = 0; mi < 4; ++mi)
#pragma unroll
      for (int ni = 0; ni < 2; ++ni) {
        acc[mi + 4][ni + 2] = MFMA16(aH[mi][0], bH[ni][0], acc[mi + 4][ni + 2]);
        acc[mi + 4][ni + 2] = MFMA16(aH[mi][1], bH[ni][1], acc[mi + 4][ni + 2]);
      }
    __builtin_amdgcn_s_setprio(0);
    BARRIER;

    if (s2) { STG_A(tt + 2, 0); STG_A(tt + 2, 1); }
    __builtin_amdgcn_s_setprio(1);
#pragma unroll
    for (int mi = 0; mi < 4; ++mi)
#pragma unroll
      for (int ni = 0; ni < 2; ++ni) {
        acc[mi + 4][ni] = MFMA16(aH[mi][0], bL[ni][0], acc[mi + 4][ni]);
        acc[mi + 4][ni] = MFMA16(aH[mi][1], bL[ni][1], acc[mi + 4][ni]);
      }
    __builtin_amdgcn_s_setprio(0);
    if (s2)
      asm volatile("s_waitcnt vmcnt(2)" ::: "memory");
    else
      asm volatile("s_waitcnt vmcnt(0)" ::: "memory");
    BARRIER;
  }
#undef STG_A
#undef STG_B
#undef AFRAG
#undef BFRAG

  float bias_v[4];
#pragma unroll
  for (int ni = 0; ni < 4; ++ni) bias_v[ni] = bias[row0B + wn * 64 + ni * 16 + lr];

  if (MODE == 0) {
#pragma unroll
    for (int mi = 0; mi < 8; ++mi) {
      int grow_base = row0A + wm * 128 + mi * 16 + g * 4;
#pragma unroll
      for (int ni = 0; ni < 4; ++ni) {
        int gcol = row0B + wn * 64 + ni * 16 + lr;
#pragma unroll
        for (int j = 0; j < 4; ++j)
          C[(size_t)(grow_base + j) * ldc + gcol] = (OutT)(acc[mi][ni][j] + bias_v[ni]);
      }
    }
  } else {
    // QKV-fused epilogue
    const int which = blockIdx.y >> 2;                 // 0=Q, 1=K, 2=V
    const int h = (blockIdx.y & 3) * 4 + wn;
    const int b = blockIdx.x >> 3;
    const int bh = b * 16 + h;
    const int ntop = (blockIdx.x & 7) * 256 + wm * 128;  // n within [0,2048)

    if (which == 0) {
      // Q: RoPE + qpack layout [bh][tok>>2][hd][tok&3], coalesced uint2 stores
      const float sc = 0.125f * 1.44269504088896f;
      const float sgn = (lane & 1) ? 1.f : -1.f;
      const size_t qbase = (size_t)bh * 131072;
#pragma unroll
      for (int mi = 0; mi < 8; ++mi) {
        int tb0 = ((ntop + mi * 16) >> 2) + g;
#pragma unroll
        for (int ni = 0; ni < 4; ++ni) {
          int hd = ni * 16 + lr;
          const float* p0 = encT + (size_t)hd * 2048 + ntop + mi * 16 + g * 4;
          float4 f0 = *(const float4*)p0;
          float4 f1 = *(const float4*)(p0 + 131072);
          __bf16 w4[4];
#pragma unroll
          for (int j = 0; j < 4; ++j) {
            float v = acc[mi][ni][j] + bias_v[ni];
            float p = __shfl_xor(v, 1, 64);
            float e0 = ((const float*)&f0)[j], e1 = ((const float*)&f1)[j];
            w4[j] = (__bf16)((v * e0 + sgn * p * e1) * sc);
          }
          *(uint2*)(qb + qbase + (size_t)tb0 * 256 + hd * 4) = *(uint2*)w4;
        }
      }
    } else if (which == 1) {
      // K: RoPE -> LDS [tok][hd] XOR-swizzled -> coalesced row-major kb
      char* lbuf = (char*)As;
      const int wb = wave * 16384;            // 16 KB per wave (128 tok x 64 hd)
      const float sgn = (lane & 1) ? 1.f : -1.f;
#pragma unroll
      for (int mi = 0; mi < 8; ++mi) {
#pragma unroll
        for (int ni = 0; ni < 4; ++ni) {
          int hd = ni * 16 + lr;
          const float* p0 = encT + (size_t)hd * 2048 + ntop + mi * 16 + g * 4;
          float4 f0 = *(const float4*)p0;
          float4 f1 = *(const float4*)(p0 + 131072);
#pragma unroll
          for (int j = 0; j < 4; ++j) {
            float v = acc[mi][ni][j] + bias_v[ni];
            float p = __shfl_xor(v, 1, 64);
            float e0 = ((const float*)&f0)[j], e1 = ((const float*)&f1)[j];
            __bf16 r = (__bf16)(v * e0 + sgn * p * e1);
            int ltok = mi * 16 + g * 4 + j;
            *(__bf16*)(lbuf + wb + ltok * 128 + ((hd * 2) ^ ((ltok & 7) << 4))) = r;
          }
        }
      }
      __syncthreads();
#pragma unroll
      for (int it = 0; it < 16; ++it) {
        int ltok = (lane >> 3) + (it & 7) * 8 + (it >> 3) * 64;
        int o = lane & 7;
        uint4 val = *(uint4*)(lbuf + wb + ltok * 128 + ((o ^ (ltok & 7)) << 4));
        *(uint4*)(kb + ((size_t)bh * 2048 + ntop + ltok) * 64 + o * 8) = val;
      }
    } else {
      // V: bias -> swizzled LDS [hd][tok] per wave -> kv-perm coalesced writes
      char* lbuf = (char*)As;
      const int wb2 = wave * 16384;
#pragma unroll
      for (int mi = 0; mi < 8; ++mi)
#pragma unroll
        for (int ni = 0; ni < 4; ++ni) {
          int hd = ni * 16 + lr;
          int tok = mi * 16 + g * 4;
          __bf16 w4[4];
#pragma unroll
          for (int j = 0; j < 4; ++j) w4[j] = (__bf16)(acc[mi][ni][j] + bias_v[ni]);
          int ab = wb2 + hd * 256 + ((tok * 2) ^ ((hd & 15) << 4));
          *(uint2*)(lbuf + ab) = *(uint2*)w4;
        }
      __syncthreads();
#pragma unroll
      for (int it = 0; it < 16; ++it) {
        int hd = (lane >> 3) + (it & 7) * 8;
        int slot = (lane & 7) + (it >> 3) * 8;
        int grp = slot >> 3, c = slot & 7;
        int kv0 = grp * 64 + (c >> 2) * 32 + (c & 3) * 4;
        int a1 = wb2 + hd * 256 + ((kv0 * 2) ^ ((hd & 15) << 4));
        int a2 = wb2 + hd * 256 + (((kv0 + 16) * 2) ^ ((hd & 15) << 4));
        uint2 lo = *(uint2*)(lbuf + a1);
        uint2 hi = *(uint2*)(lbuf + a2);
        uint4 o4 = make_uint4(lo.x, lo.y, hi.x, hi.y);
        *(uint4*)(vtb + ((size_t)bh * 64 + hd) * 2048 + ntop + grp * 64 + c * 8) = o4;
      }
    }
  }
}

// ---------------------------------------------------------------------------
// Flash attention (QBLK=32/wave). Q read from qpack layout (one-time gather).
// ---------------------------------------------------------------------------
__global__ __launch_bounds__(256) void attn_kernel(
    const __bf16* __restrict__ q, const __bf16* __restrict__ k,
    const __bf16* __restrict__ vt, __bf16* __restrict__ ctx) {
  __shared__ __attribute__((aligned(16))) __bf16 Ks[2][64 * 64];
  __shared__ __attribute__((aligned(16))) __bf16 Vs[2][64 * 64];

  int nwg = gridDim.x * gridDim.y;  // 1024
  int bid0 = blockIdx.y * gridDim.x + blockIdx.x;
  int bid = (bid0 & 7) * (nwg >> 3) + (bid0 >> 3);
  const int bh = bid >> 4, qblk = bid & 15;
  const int b = bh >> 4, h = bh & 15;
  const int q0 = qblk * 128;
  const int t = threadIdx.x, wave = t >> 6, lane = t & 63;
  const int g = lane >> 4, lr = lane & 15;
  const int qrow0 = q0 + wave * 32;

  const __bf16* kbase = k + (size_t)bh * 2048 * 64;
  const __bf16* vbase = vt + (size_t)bh * 64 * 2048;

  // Q from qpack: elem (tok, hd) at bh*131072 + (tok>>2)*256 + hd*4 + (tok&3)
  bf16x8 qf[2][2];
#pragma unroll
  for (int u = 0; u < 2; ++u) {
    int tok = qrow0 + u * 16 + lr;
    const __bf16* qp = q + (size_t)bh * 131072 + (size_t)(tok >> 2) * 256 + (tok & 3);
#pragma unroll
    for (int kc = 0; kc < 2; ++kc) {
      bf16x8 v;
#pragma unroll
      for (int e = 0; e < 8; ++e) v[e] = qp[(kc * 32 + g * 8 + e) * 4];
      qf[u][kc] = v;
    }
  }

  bf16x8 ones;
#pragma unroll
  for (int e = 0; e < 8; ++e) ones[e] = (__bf16)1.0f;

  f32x4 o[2][4] = {};
  f32x4 lacc[2] = {};

#define STAGE_ATTN(buf, kv0)                                                    \
  {                                                                             \
    _Pragma("unroll") for (int p = 0; p < 2; ++p) {                             \
      int cbase = wave * 128 + p * 64;                                          \
      int ci = cbase + lane;                                                    \
      int r = ci >> 3, cp = ci & 7, cl = cp ^ (r & 7);                          \
      gload16(kbase + (size_t)((kv0) + r) * 64 + cl * 8, &Ks[buf][cbase * 8]);  \
      gload16(vbase + (size_t)r * 2048 + (kv0) + cl * 8, &Vs[buf][cbase * 8]);  \
    }                                                                           \
  }

  STAGE_ATTN(0, 0);
  __syncthreads();
  int buf = 0;

  for (int kv0 = 0; kv0 < 2048; kv0 += 64) {
    if (kv0 + 64 < 2048) STAGE_ATTN(buf ^ 1, kv0 + 64);

    f32x4 s[2][4];
    __builtin_amdgcn_s_setprio(1);
#pragma unroll
    for (int nt = 0; nt < 4; ++nt) {
      int r = nt * 16 + lr;
      bf16x8 kf0 = *(const bf16x8*)((char*)Ks[buf] + r * 128 + ((g ^ (r & 7)) * 16));
      bf16x8 kf1 = *(const bf16x8*)((char*)Ks[buf] + r * 128 + (((4 + g) ^ (r & 7)) * 16));
#pragma unroll
      for (int u = 0; u < 2; ++u) {
        f32x4 a = {};
        a = MFMA16(kf0, qf[u][0], a);
        a = MFMA16(kf1, qf[u][1], a);
        s[u][nt] = a;
      }
    }
    __builtin_amdgcn_s_setprio(0);

#pragma unroll
    for (int t2 = 0; t2 < 2; ++t2) {
      bf16x8 pf[2];
#pragma unroll
      for (int u = 0; u < 2; ++u) {
#pragma unroll
        for (int e = 0; e < 8; ++e)
          pf[u][e] = (__bf16)__builtin_amdgcn_exp2f(s[u][2 * t2 + (e >> 2)][e & 3]);
        lacc[u] = MFMA16(ones, pf[u], lacc[u]);
      }
      __builtin_amdgcn_s_setprio(1);
#pragma unroll
      for (int nt = 0; nt < 4; ++nt) {
        int r = nt * 16 + lr;
        bf16x8 vf = *(const bf16x8*)((char*)Vs[buf] + r * 128 + (((t2 * 4 + g) ^ (r & 7)) * 16));
#pragma unroll
        for (int u = 0; u < 2; ++u) o[u][nt] = MFMA16(vf, pf[u], o[u][nt]);
      }
      __builtin_amdgcn_s_setprio(0);
    }
    __syncthreads();
    buf ^= 1;
  }

#pragma unroll
  for (int u = 0; u < 2; ++u) {
    float inv = 1.f / lacc[u][0];
    size_t obase = ((size_t)(b * 2048 + qrow0 + u * 16 + lr)) * 2048 + 1024 + h * 64;
#pragma unroll
    for (int nt = 0; nt < 4; ++nt) {
      __bf16 w4[4];
#pragma unroll
      for (int j = 0; j < 4; ++j) w4[j] = (__bf16)(o[u][nt][j] * inv);
      *(uint2*)(ctx + obase + nt * 16 + g * 4) = *(uint2*)w4;
    }
  }
#undef STAGE_ATTN
}

// ---------------------------------------------------------------------------
// LayerNorm + exact GELU over rows of 2048
// ---------------------------------------------------------------------------
__global__ __launch_bounds__(256) void ln_gelu(const __bf16* __restrict__ hin,
                                               const float* __restrict__ lns,
                                               const float* __restrict__ lnb,
                                               __bf16* __restrict__ hout) {
  int row = blockIdx.x;
  const __bf16* rp = hin + (size_t)row * 2048;
  int t = threadIdx.x;
  __bf16 tmp[8];
  *(uint4*)tmp = *(const uint4*)(rp + t * 8);
  float vals[8], s = 0.f, s2 = 0.f;
#pragma unroll
  for (int e = 0; e < 8; ++e) {
    float x = (float)tmp[e];
    vals[e] = x;
    s += x;
    s2 += x * x;
  }
#pragma unroll
  for (int m = 1; m < 64; m <<= 1) {
    s += __shfl_xor(s, m, 64);
    s2 += __shfl_xor(s2, m, 64);
  }
  __shared__ float red[8];
  int wave = t >> 6, lane = t & 63;
  if (lane == 0) { red[wave] = s; red[4 + wave] = s2; }
  __syncthreads();
  s = red[0] + red[1] + red[2] + red[3];
  s2 = red[4] + red[5] + red[6] + red[7];
  float mu = s * (1.f / 2048.f);
  float var = s2 * (1.f / 2048.f) - mu * mu;
  float rstd = rsqrtf(var + 1e-5f);
  __bf16 outv[8];
#pragma unroll
  for (int e = 0; e < 8; ++e) {
    int c = t * 8 + e;
    float xh = (vals[e] - mu) * rstd * lns[c] + lnb[c];
    float gg = 0.5f * xh * (1.f + erff(xh * 0.70710678118f));
    outv[e] = (__bf16)gg;
  }
  *(uint4*)(hout + (size_t)row * 2048 + t * 8) = *(uint4*)outv;
}

// ---------------------------------------------------------------------------
// Launch
// ---------------------------------------------------------------------------
extern "C" void kernel_launch(void* const* d_in, const int* in_sizes, int n_in,
                              void* d_out, int out_size, void* d_ws, size_t ws_size,
                              hipStream_t stream) {
  const float* x = (const float*)d_in[0];
  const float* enc = (const float*)d_in[1];
  const float* wqkv = (const float*)d_in[2];
  const float* bqkv = (const float*)d_in[3];
  const float* wout = (const float*)d_in[4];
  const float* bout = (const float*)d_in[5];
  const float* wffn0 = (const float*)d_in[6];
  const float* bffn0 = (const float*)d_in[7];
  const float* lns = (const float*)d_in[8];
  const float* lnb = (const float*)d_in[9];
  const float* wffn3 = (const float*)d_in[10];
  const float* bffn3 = (const float*)d_in[11];
  float* out = (float*)d_out;
  char* ws = (char*)d_ws;

  __bf16* wT_qkv = (__bf16*)(ws + 0);              //  6291456
  __bf16* wT_ffn0 = (__bf16*)(ws + 6291456);       //  8388608
  __bf16* wT_ffn3 = (__bf16*)(ws + 14680064);      //  4194304
  __bf16* wout_bf = (__bf16*)(ws + 18874368);      //  2097152
  __bf16* w0bT = (__bf16*)(ws + 20971520);         //  4194304
  float* bias_part = (float*)(ws + 25165824);      //   131072
  float* bqkv_p = (float*)(ws + 25296896);         //    12288
  float* bffn0_f = (float*)(ws + 25309184);        //     8192
  __bf16* h_in = (__bf16*)(ws + 25317376);         // 33554432  [x | ctx]
  __bf16* ffn0o = (__bf16*)(ws + 58871808);        // 33554432
  __bf16* qb = (__bf16*)(ws + 109203456);          // 16777216 (qpack)
  __bf16* h2 = qb;                                 // alias (q dead after attn)
  __bf16* kb = (__bf16*)(ws + 125980672);          // 16777216
  __bf16* vtb = (__bf16*)(ws + 142757888);         // 16777216
  float* encT = (float*)(ws + 159535104);          //  1048576

  dim3 blk(256);
  prep1<<<14220, blk, 0, stream>>>(wqkv, wT_qkv, wffn0, wT_ffn0, w0bT, wffn3, wT_ffn3,
                                   wout, wout_bf, bqkv, bqkv_p, bout, bias_part, x, h_in,
                                   enc, encT);
  prep2<<<136, blk, 0, stream>>>(w0bT, wout_bf, wT_ffn0, bias_part, bffn0, bffn0_f);

  // QKV projection + fused RoPE/scatter: [8192,1024] x [1024,3072] -> qb,kb,vtb
  gemm256p<__bf16, 1><<<dim3(32, 12), dim3(512), 0, stream>>>(
      h_in, 2048, wT_qkv, 1024, bqkv_p, (__bf16*)nullptr, 0, 1024, qb, kb, vtb, encT);

  attn_kernel<<<dim3(16, 64), blk, 0, stream>>>(qb, kb, vtb, h_in);

  // FFN0 (with fused out-proj): [8192,2048] x [2048,2048]
  gemm256p<__bf16, 0><<<dim3(32, 8), dim3(512), 0, stream>>>(
      h_in, 2048, wT_ffn0, 2048, bffn0_f, ffn0o, 2048, 2048,
      nullptr, nullptr, nullptr, nullptr);

  ln_gelu<<<8192, blk, 0, stream>>>(ffn0o, lns, lnb, h2);

  // FFN3 + bias + residual -> out (fp32)
  gemm_kernel<float, true, true><<<dim3(64, 8), blk, 0, stream>>>(
      h2, 2048, wT_ffn3, bffn3, out, 1024, x, 8192, 1024, 2048);
}